// Round 15
// baseline (300.323 us; speedup 1.0000x reference)
//
#include <hip/hip_runtime.h>

// ============================================================================
// Model_22016002360008 — synth forward pass.
//  GEMM: bf16 MFMA 16x16x32, LDS-free, barrier-free; K split x2; prefetch x4;
//        256-thread blocks, grid (512,2) -> 4 waves/SIMD.
//  FFT: complex four-step, N = N1*256, digit-permuted spectrum
//       addr = k2*N1 + k1, true bin k = k2 + 256*k1.
//  ALL complex spectra + GEMM partials stored PACKED BF16; fr1/fr2 packed as
//  one uint (FRP), fn bf16; finU fp32 (feeds dry output). FFT arithmetic fp32.
//  Length-256 transforms: REGISTER 16x16 FFT. 32K mid: radix-4 LDS Stockham.
//  Fusions: scalars folded into packA; conv-inverse+finU+SS+reverb-forward in
//  one kernel; fscale deferred to final pass; Ds+P+IRS forwards one dispatch.
//  !! mid's input must be STRIDED-ONLY (half-transformed) data — never run
//  !! a contig FFT before a mid kernel (round-2 bug, reverb path).
// ============================================================================

typedef __attribute__((ext_vector_type(8))) short bf16x8;
typedef __attribute__((ext_vector_type(4))) float f32x4;

constexpr int SC_OM0   = 0;
constexpr int SC_OM1   = 64;
constexpr int SC_NFMU  = 128;
constexpr int SC_NFSD  = 192;
constexpr int SC_RF1SD = 256;
constexpr int SC_RF2SD = 320;
constexpr int SC_ENVMU = 384;
constexpr int SC_ENVSD = 448;
constexpr int SC_AMPS  = 512;
constexpr int SC_MIXV  = 576;
constexpr int SC_ROOM  = 832;
constexpr int SC_PSS   = 1024;   // 64 x 16 partial sum-of-squares
constexpr int SC_DTAB  = 4096;
constexpr int SC_FTAB  = 12288;

// ---------------- workspace layout (float offsets; bf16 buffers use less) ---
constexpr size_t OFF_SCAL = 0;
constexpr size_t OFF_CT   = 65536;
constexpr size_t OFF_P    = 327680;       // P half-transformed (bf16 packed)
constexpr size_t OFF_DS   = 8716288;      // Ds (bf16); rp (bf16) aliases
constexpr size_t OFF_RP   = OFF_DS;
constexpr size_t OFF_W64  = 17104896;     // conv/rev work; early: NSs + W2
constexpr size_t OFF_NSS  = OFF_W64;
constexpr size_t OFF_W2   = OFF_W64 + 4194304;
constexpr size_t OFF_RSS  = 25493504;     // RSs -> finU
constexpr size_t OFF_FINU = OFF_RSS;
constexpr size_t OFF_W1   = 29687808;
constexpr size_t OFF_FN   = 38076416;     // fn bf16 (shorts)
constexpr size_t OFF_FRP  = 40173568;     // fr1+i*fr2 packed (uints)
constexpr size_t OFF_IRS  = 44367872;
constexpr size_t WS_FLOATS= 45416448;

__device__ __forceinline__ float2 cmul(float2 a, float2 b) {
  return make_float2(a.x*b.x - a.y*b.y, a.x*b.y + a.y*b.x);
}

__device__ __forceinline__ short f2bf(float x) {
  unsigned u = __float_as_uint(x);
  u = (u + 0x7FFFu + ((u >> 16) & 1u)) >> 16;
  return (short)u;
}
__device__ __forceinline__ float bf2f(short s) {
  return __uint_as_float((unsigned)(unsigned short)s << 16);
}
__device__ __forceinline__ unsigned pk2(float2 v) {
  return (unsigned)(unsigned short)f2bf(v.x)
       | ((unsigned)(unsigned short)f2bf(v.y) << 16);
}
__device__ __forceinline__ float2 upk2(unsigned u) {
  return make_float2(__uint_as_float(u << 16),
                     __uint_as_float(u & 0xFFFF0000u));
}

// ---------------- 16-point DFT in registers (natural order in/out) ---------
__device__ __forceinline__ void dft16(float2 d[16], float ei)
{
  const float CA[4] = {1.0f, 0.92387953251128674f, 0.70710678118654752f, 0.38268343236508977f};
  const float SA[4] = {0.0f, 0.38268343236508977f, 0.70710678118654752f, 0.92387953251128674f};
  const float CB[4] = {1.0f, 0.70710678118654752f, 0.0f, -0.70710678118654752f};
  const float SB[4] = {0.0f, 0.70710678118654752f, 1.0f, 0.70710678118654752f};
  float2 e[16];
  #pragma unroll
  for (int q = 0; q < 4; ++q) {
    float2 x0 = d[q], x1 = d[q+4], x2 = d[q+8], x3 = d[q+12];
    float ca = CA[q], sa = ei*SA[q], cb = CB[q], sb = ei*SB[q];
    float2 sum1 = make_float2(x0.x+x2.x, x0.y+x2.y);
    float2 d1   = make_float2(x0.x-x2.x, x0.y-x2.y);
    float2 dif1 = make_float2(d1.x*ca - d1.y*sa, d1.x*sa + d1.y*ca);
    float2 sum2 = make_float2(x1.x+x3.x, x1.y+x3.y);
    float2 d2   = make_float2(x1.x-x3.x, x1.y-x3.y);
    float2 dt   = make_float2(d2.x*ca - d2.y*sa, d2.x*sa + d2.y*ca);
    float2 dif2 = make_float2(-ei*dt.y, ei*dt.x);
    float2 Dm   = make_float2(sum1.x-sum2.x, sum1.y-sum2.y);
    float2 Dm2  = make_float2(dif1.x-dif2.x, dif1.y-dif2.y);
    e[4*q+0] = make_float2(sum1.x+sum2.x, sum1.y+sum2.y);
    e[4*q+1] = make_float2(dif1.x+dif2.x, dif1.y+dif2.y);
    e[4*q+2] = make_float2(Dm.x*cb - Dm.y*sb, Dm.x*sb + Dm.y*cb);
    e[4*q+3] = make_float2(Dm2.x*cb - Dm2.y*sb, Dm2.x*sb + Dm2.y*cb);
  }
  #pragma unroll
  for (int q = 0; q < 4; ++q) {
    float2 x0 = e[q], x1 = e[q+4], x2 = e[q+8], x3 = e[q+12];
    float2 sum1 = make_float2(x0.x+x2.x, x0.y+x2.y);
    float2 dif1 = make_float2(x0.x-x2.x, x0.y-x2.y);
    float2 sum2 = make_float2(x1.x+x3.x, x1.y+x3.y);
    float2 d2   = make_float2(x1.x-x3.x, x1.y-x3.y);
    float2 dif2 = make_float2(-ei*d2.y, ei*d2.x);
    d[q]    = make_float2(sum1.x+sum2.x, sum1.y+sum2.y);
    d[q+4]  = make_float2(dif1.x+dif2.x, dif1.y+dif2.y);
    d[q+8]  = make_float2(sum1.x-sum2.x, sum1.y-sum2.y);
    d[q+12] = make_float2(dif1.x-dif2.x, dif1.y-dif2.y);
  }
}

__device__ __forceinline__ void twiddleB(float2 d[16], int u, float dir2pi)
{
  float sn1, cs1;
  __sincosf(dir2pi * ((float)u * (1.0f/256.0f)), &sn1, &cs1);
  float2 w1 = make_float2(cs1, sn1);
  float2 tw = w1;
  #pragma unroll
  for (int k = 1; k < 16; ++k) { d[k] = cmul(d[k], tw); tw = cmul(tw, w1); }
}

// ---------------- in-LDS RADIX-4 Stockham (LEN=128, 32K mid only) ----------
template<int LEN>
__device__ float2* lds_fft(float2* src, float2* dst,
                           const float2* __restrict__ T256,
                           float dsign, float ei)
{
  constexpr int QB  = LEN >> 2;
  constexpr int FPT = (16 * QB) >> 8;
  constexpr int NST = (LEN == 256) ? 4 : 3;
  int n = LEN, s = 1, ls = 0;
  int sh = (LEN == 256) ? 0 : 1;

  if (LEN == 128) {
    constexpr int HB = LEN >> 1;
    constexpr int BPT = (16 * HB) >> 8;
    __syncthreads();
    #pragma unroll
    for (int b = 0; b < BPT; ++b) {
      int g = threadIdx.x + (b << 8);
      int row = g / HB;
      int beta = g & (HB - 1);
      float2 tj = T256[beta << 1];
      float cs = tj.x, sn = dsign * tj.y;
      float2 av = src[row*LEN + (beta ^ row)];
      float2 bv = src[row*LEN + ((beta + HB) ^ row)];
      float2 sum = make_float2(av.x + bv.x, av.y + bv.y);
      float2 dif = make_float2(av.x - bv.x, av.y - bv.y);
      float2 tw  = make_float2(dif.x*cs - dif.y*sn, dif.x*sn + dif.y*cs);
      dst[row*LEN + ((2*beta)     ^ row)] = sum;
      dst[row*LEN + ((2*beta + 1) ^ row)] = tw;
    }
    float2* t = src; src = dst; dst = t;
    n = 64; s = 2; ls = 1; sh = 2;
  }

  for (int st = 0; st < NST; ++st) {
    __syncthreads();
    #pragma unroll
    for (int b = 0; b < FPT; ++b) {
      int g   = threadIdx.x + (b << 8);
      int row = g / QB;
      int q   = g & (QB - 1);
      int p1  = q >> ls;
      int blo = q & (s - 1);
      int base = row * LEN;
      float2 x0 = src[base + ( q         ^ row)];
      float2 x1 = src[base + ((q +   QB) ^ row)];
      float2 x2 = src[base + ((q + 2*QB) ^ row)];
      float2 x3 = src[base + ((q + 3*QB) ^ row)];
      float2 tA = T256[p1 << sh];
      float caA = tA.x, saA = dsign * tA.y;
      float2 tB = T256[p1 << (sh + 1)];
      float caB = tB.x, saB = dsign * tB.y;
      float2 sum1 = make_float2(x0.x + x2.x, x0.y + x2.y);
      float2 d1   = make_float2(x0.x - x2.x, x0.y - x2.y);
      float2 dif1 = make_float2(d1.x*caA - d1.y*saA, d1.x*saA + d1.y*caA);
      float2 sum2 = make_float2(x1.x + x3.x, x1.y + x3.y);
      float2 d2   = make_float2(x1.x - x3.x, x1.y - x3.y);
      float2 dt   = make_float2(d2.x*caA - d2.y*saA, d2.x*saA + d2.y*caA);
      float2 dif2 = make_float2(-ei * dt.y, ei * dt.x);
      float2 S  = make_float2(sum1.x + sum2.x, sum1.y + sum2.y);
      float2 Dm = make_float2(sum1.x - sum2.x, sum1.y - sum2.y);
      float2 D  = make_float2(Dm.x*caB - Dm.y*saB, Dm.x*saB + Dm.y*caB);
      float2 S2 = make_float2(dif1.x + dif2.x, dif1.y + dif2.y);
      float2 Dm2= make_float2(dif1.x - dif2.x, dif1.y - dif2.y);
      float2 D2 = make_float2(Dm2.x*caB - Dm2.y*saB, Dm2.x*saB + Dm2.y*caB);
      int w0 = (p1 << (ls + 2)) | blo;
      dst[base + ( w0          ^ row)] = S;
      dst[base + ((w0 +     s) ^ row)] = S2;
      dst[base + ((w0 + 2 * s) ^ row)] = D;
      dst[base + ((w0 + 3 * s) ^ row)] = D2;
    }
    float2* t = src; src = dst; dst = t;
    n >>= 2; s <<= 2; ls += 2; sh += 2;
  }
  __syncthreads();
  return src;
}

// ---------------- merged Ds + P + IRS forward strided (64K) ----------------
// y<64: Ds = fwd_half(pad((fr1 + i*fr2) * decay)) from packed FRP, atom y
// 64<=y<128: P = fwd_half(pad(fn_bf16 * gauss_env)), atom y-64
// y>=128: IRS = fwd_half(pad(rirs)), room y-128
__global__ __launch_bounds__(256) void k_fft_s256_DsPI(
    unsigned* __restrict__ Ds, unsigned* __restrict__ P,
    unsigned* __restrict__ IRS,
    const unsigned* __restrict__ FRP, const short* __restrict__ fnb,
    const float* __restrict__ rirs, const float* __restrict__ scal)
{
  constexpr int N = 65536, NH = 32768;
  constexpr float FWD = -6.283185307179586f;
  __shared__ float2 X[16*16*17];
  __shared__ float2 T256[256];
  __shared__ float2 TN[256];
  const int mode = (blockIdx.y < 64) ? 0 : ((blockIdx.y < 128) ? 1 : 2);
  const int a = (mode == 0) ? blockIdx.y : ((mode == 1) ? blockIdx.y - 64 : blockIdx.y - 128);
  const int n1base = blockIdx.x << 4;
  const int r = threadIdx.x & 15;
  const int u = threadIdx.x >> 4;

  {
    float ang = FWD * ((float)threadIdx.x * (1.0f/256.0f));
    float sn, cs; __sincosf(ang, &sn, &cs);
    T256[threadIdx.x] = make_float2(cs, sn);
    float ang2 = FWD * ((float)threadIdx.x * (1.0f/(float)N));
    float sn2, cs2; __sincosf(ang2, &sn2, &cs2);
    TN[threadIdx.x] = make_float2(cs2, sn2);
  }

  float emu = 0.f, esd = 1.f, egp = 0.f;
  if (mode == 1) {
    emu = scal[SC_ENVMU + a];
    esd = scal[SC_ENVSD + a];
    egp = 0.3989422804014327f / esd;
  }

  float2 d[16];
  #pragma unroll
  for (int m = 0; m < 16; ++m) {
    int j = u + (m << 4);
    int n = n1base + r + 256 * j;
    float2 v = make_float2(0.0f, 0.0f);
    if (n < NH) {
      if (mode == 0) {
        float pos = ((float)n + 0.5f) * (1.0f/256.0f) - 0.5f;
        pos = fminf(fmaxf(pos, 0.0f), 127.0f);
        int i0 = (int)pos;
        float w = pos - (float)i0;
        int i1 = (i0 + 1 < 127) ? i0 + 1 : 127;
        const float* dt = scal + SC_DTAB + a*128;
        float de = dt[i0]*(1.0f-w) + dt[i1]*w;
        float2 fr = upk2(FRP[(size_t)a * NH + n]);
        v = make_float2(fr.x * de, fr.y * de);
      } else if (mode == 1) {
        float uu = (float)n * (1.0f / 32767.0f);
        float te = (uu - emu) / esd;
        float envv = __expf(-0.5f * te * te) * egp;
        v = make_float2(bf2f(fnb[(size_t)a * NH + n]) * envv, 0.0f);
      } else {
        v = make_float2(rirs[(size_t)a * NH + n], 0.0f);
      }
    }
    d[m] = v;
  }

  dft16(d, -1.0f);
  twiddleB(d, u, FWD);
  #pragma unroll
  for (int k = 0; k < 16; ++k) X[(u*16 + k)*17 + r] = d[k];
  __syncthreads();
  #pragma unroll
  for (int m = 0; m < 16; ++m) d[m] = X[(m*16 + u)*17 + r];
  dft16(d, -1.0f);

  unsigned* outp = (mode == 0) ? Ds : ((mode == 1) ? P : IRS);
  #pragma unroll
  for (int k1 = 0; k1 < 16; ++k1) {
    int j = u + (k1 << 4);
    int n = n1base + r + 256 * j;
    int aa = (n1base + r) * j;
    float2 tw = cmul(T256[(aa >> 8) & 255], TN[aa & 255]);
    outp[(size_t)a * N + n] = pk2(cmul(d[k1], tw));
  }
}

// ---------------- merged first strided (32K): RS (y<64) + NS (y>=64) -------
__global__ __launch_bounds__(256) void k_fft_s128_first(
    unsigned* __restrict__ RSs, unsigned* __restrict__ NSs,
    const short* __restrict__ rez, const float* __restrict__ noise)
{
  constexpr int N1 = 128, N = 32768;
  constexpr float FWD = -6.283185307179586f;
  __shared__ float2 X[16*16*17];
  __shared__ float2 T256[256];
  __shared__ float2 TN[128];
  const bool isRS = blockIdx.y < 64;
  const int a = isRS ? blockIdx.y : blockIdx.y - 64;
  const int n1base = blockIdx.x << 4;
  const int r = threadIdx.x & 15;
  const int u = threadIdx.x >> 4;

  {
    float ang = FWD * ((float)threadIdx.x * (1.0f/256.0f));
    float sn, cs; __sincosf(ang, &sn, &cs);
    T256[threadIdx.x] = make_float2(cs, sn);
    if (threadIdx.x < 128) {
      float ang2 = FWD * ((float)threadIdx.x * (1.0f/(float)N));
      float sn2, cs2; __sincosf(ang2, &sn2, &cs2);
      TN[threadIdx.x] = make_float2(cs2, sn2);
    }
  }

  float2 d[16];
  #pragma unroll
  for (int m = 0; m < 16; ++m) {
    int j = u + (m << 4);
    int n = n1base + r + N1 * j;
    float x = isRS ? (bf2f(rez[(size_t)a * N + n]) +
                      bf2f(rez[(size_t)(64 + a) * N + n]))
                   : noise[(size_t)a * N + n];
    d[m] = make_float2(x, 0.0f);
  }

  dft16(d, -1.0f);
  twiddleB(d, u, FWD);
  #pragma unroll
  for (int k = 0; k < 16; ++k) X[(u*16 + k)*17 + r] = d[k];
  __syncthreads();
  #pragma unroll
  for (int m = 0; m < 16; ++m) d[m] = X[(m*16 + u)*17 + r];
  dft16(d, -1.0f);

  unsigned* outp = isRS ? RSs : NSs;
  #pragma unroll
  for (int k1 = 0; k1 < 16; ++k1) {
    int j = u + (k1 << 4);
    int n = n1base + r + N1 * j;
    int aa = (n1base + r) * j;
    float2 tw = cmul(T256[(aa >> 7) & 255], TN[aa & 127]);
    outp[(size_t)a * N + n] = pk2(cmul(d[k1], tw));
  }
}

// ---------------- merged 32K mid: RS complex filter (y<64) / NS gauss ------
__global__ __launch_bounds__(256) void k_fft_m128_both(
    const unsigned* __restrict__ RSs, const unsigned* __restrict__ NSs,
    unsigned* __restrict__ W1, unsigned* __restrict__ W2,
    const float* __restrict__ scal)
{
  constexpr int N1 = 128;
  constexpr int N = N1 * 256;
  constexpr int ITERS = (16 * N1) >> 8;
  constexpr int LOG2N1 = 7;
  constexpr float FWD = -6.283185307179586f;
  constexpr float IVD = +6.283185307179586f;
  __shared__ float2 A[16 * N1];
  __shared__ float2 B[16 * N1];
  __shared__ float2 T256[256];
  __shared__ float2 TN[N1];
  const bool isRS = blockIdx.y < 64;
  const int a = isRS ? blockIdx.y : blockIdx.y - 64;
  const int colbase = blockIdx.x << 4;

  {
    float ang = FWD * ((float)threadIdx.x * (1.0f/256.0f));
    float sn, cs; __sincosf(ang, &sn, &cs);
    T256[threadIdx.x] = make_float2(cs, sn);
    if (threadIdx.x < N1) {
      float ang2 = IVD * ((float)threadIdx.x * (1.0f/(float)N));
      float sn2, cs2; __sincosf(ang2, &sn2, &cs2);
      TN[threadIdx.x] = make_float2(cs2, sn2);
    }
  }

  float mu = 0.f, isd1 = 0.f, g1 = 0.f, isd2 = 0.f, g2 = 0.f;
  if (isRS) {
    float s1 = scal[SC_RF1SD + a], s2 = scal[SC_RF2SD + a];
    isd1 = 1.0f/s1; g1 = 0.3989422804014327f/s1;
    isd2 = 1.0f/s2; g2 = 0.3989422804014327f/s2;
  } else {
    float sd = scal[SC_NFSD + a]; mu = scal[SC_NFMU + a];
    isd1 = 1.0f/sd; g1 = 0.3989422804014327f/sd;
  }
  const unsigned* zin = (isRS ? RSs : NSs) + (size_t)a * N;
  unsigned* out = (isRS ? W1 : W2) + (size_t)a * N;

  #pragma unroll
  for (int it = 0; it < ITERS; ++it) {
    int flat = threadIdx.x + (it << 8);
    int c = flat / N1, j = flat & (N1 - 1);
    A[c*N1 + (j ^ c)] = upk2(zin[(size_t)(colbase + c) * N1 + j]);
  }
  float2* cur = lds_fft<N1>(A, B, T256, 1.0f, -1.0f);
  float2* alt = (cur == A) ? B : A;

  #pragma unroll
  for (int it = 0; it < ITERS; ++it) {
    int flat = threadIdx.x + (it << 8);
    int c = flat / N1, j = flat & (N1 - 1);
    int idx = c*N1 + (j ^ c);
    float2 v = cur[idx];
    int k  = (colbase + c) + (j << 8);          // true bin
    int kk = (k <= N - k) ? k : N - k;          // hermitian mirror
    if (isRS) {
      float fr = (float)kk * (2.0f/(float)N);
      float t1 = fr * isd1, t2 = fr * isd2;
      float ga = __expf(-0.5f * t1 * t1) * g1;   // G1 (real)
      float gb = __expf(-0.5f * t2 * t2) * g2;   // G2 (imag)
      v = make_float2(v.x*ga - v.y*gb, v.x*gb + v.y*ga);
    } else {
      float t = ((float)kk * (2.0f/(float)N) - mu) * isd1;
      float g = __expf(-0.5f * t * t) * g1;
      v.x *= g; v.y *= g;
    }
    cur[idx] = v;
  }

  float2* r2 = lds_fft<N1>(cur, alt, T256, -1.0f, 1.0f);

  #pragma unroll
  for (int it = 0; it < ITERS; ++it) {
    int flat = threadIdx.x + (it << 8);
    int c = flat / N1, j = flat & (N1 - 1);
    float2 v = r2[c*N1 + (j ^ c)];
    int aa = j * (colbase + c);
    float2 t1 = T256[(aa >> LOG2N1) & 255];
    t1.y = -t1.y;
    float2 tw = cmul(t1, TN[aa & (N1 - 1)]);
    out[(size_t)(colbase + c) * N1 + j] = pk2(cmul(v, tw));
  }
}

// ---------------- merged final strided (32K inverse) -----------------------
// y<64: W1 -> FRP (fr1=re, fr2=im packed).  y>=64: W2 -> fn bf16 (re).
__global__ __launch_bounds__(256) void k_fft_s128_last(
    const unsigned* __restrict__ W1, const unsigned* __restrict__ W2,
    unsigned* __restrict__ FRP, short* __restrict__ fnb)
{
  constexpr int N1 = 128, N = 32768;
  constexpr float IVD = +6.283185307179586f;
  constexpr float S32 = 1.0f / 32768.0f;
  __shared__ float2 X[16*16*17];
  const bool isRS = blockIdx.y < 64;
  const int a = isRS ? blockIdx.y : blockIdx.y - 64;
  const int n1base = blockIdx.x << 4;
  const int r = threadIdx.x & 15;
  const int u = threadIdx.x >> 4;

  const unsigned* cb = (isRS ? W1 : W2) + (size_t)a * N;
  float2 d[16];
  #pragma unroll
  for (int m = 0; m < 16; ++m) {
    int j = u + (m << 4);
    d[m] = upk2(cb[n1base + r + N1 * j]);
  }
  dft16(d, 1.0f);
  twiddleB(d, u, IVD);
  #pragma unroll
  for (int k = 0; k < 16; ++k) X[(u*16 + k)*17 + r] = d[k];
  __syncthreads();
  #pragma unroll
  for (int m = 0; m < 16; ++m) d[m] = X[(m*16 + u)*17 + r];
  dft16(d, 1.0f);

  #pragma unroll
  for (int k1 = 0; k1 < 16; ++k1) {
    int j = u + (k1 << 4);
    int n = n1base + r + N1 * j;
    if (isRS) {
      FRP[(size_t)a * N + n] = pk2(make_float2(d[k1].x * S32, d[k1].y * S32));
    } else {
      fnb[(size_t)a * N + n] = f2bf(d[k1].x * S32);
    }
  }
}

// ---------------- fused middle, 64K (register FFT, dual-operand) -----------
// zin STRIDED-ONLY; zin2half also HALF-TRANSFORMED (its contig FFT runs here
// in-register). roomArr == nullptr -> batch index a; else room[a] (IRS).
__global__ __launch_bounds__(256) void k_fft_mid256dual(
    const unsigned* __restrict__ zin, const unsigned* __restrict__ zin2half,
    unsigned* __restrict__ out1, const int* __restrict__ roomArr)
{
  constexpr int N = 65536;
  constexpr float FWD = -6.283185307179586f;
  constexpr float IVD = +6.283185307179586f;
  __shared__ float2 X[16*16*17];
  __shared__ float2 T256[256];
  __shared__ float2 TN[256];
  const int a = blockIdx.y;
  const int colbase = blockIdx.x << 4;
  const int u  = threadIdx.x & 15;
  const int rc = threadIdx.x >> 4;

  {
    float ang = FWD * ((float)threadIdx.x * (1.0f/256.0f));
    float sn, cs; __sincosf(ang, &sn, &cs);
    T256[threadIdx.x] = make_float2(cs, sn);
    float ang2 = IVD * ((float)threadIdx.x * (1.0f/(float)N));
    float sn2, cs2; __sincosf(ang2, &sn2, &cs2);
    TN[threadIdx.x] = make_float2(cs2, sn2);
  }
  __syncthreads();

  const unsigned* z2 = zin2half + (size_t)(roomArr ? roomArr[a] : a) * N;
  const size_t rowG = (size_t)a * N + (size_t)(colbase + rc) * 256;
  const size_t rowZ2 = (size_t)(colbase + rc) * 256;

  float2 d[16];
  #pragma unroll
  for (int m = 0; m < 16; ++m) d[m] = upk2(zin[rowG + u + (m << 4)]);
  dft16(d, -1.0f);
  twiddleB(d, u, FWD);
  #pragma unroll
  for (int k = 0; k < 16; ++k) X[(rc*16 + k)*17 + u] = d[k];
  #pragma unroll
  for (int m = 0; m < 16; ++m) d[m] = X[(rc*16 + u)*17 + m];
  dft16(d, -1.0f);

  float2 stash[16];
  #pragma unroll
  for (int k = 0; k < 16; ++k) stash[k] = d[k];
  #pragma unroll
  for (int m = 0; m < 16; ++m) d[m] = upk2(z2[rowZ2 + u + (m << 4)]);
  dft16(d, -1.0f);
  twiddleB(d, u, FWD);
  #pragma unroll
  for (int k = 0; k < 16; ++k) X[(rc*16 + k)*17 + u] = d[k];
  #pragma unroll
  for (int m = 0; m < 16; ++m) d[m] = X[(rc*16 + u)*17 + m];
  dft16(d, -1.0f);
  #pragma unroll
  for (int k = 0; k < 16; ++k) d[k] = cmul(stash[k], d[k]);

  dft16(d, 1.0f);
  twiddleB(d, u, IVD);
  #pragma unroll
  for (int k = 0; k < 16; ++k) X[(rc*16 + k)*17 + u] = d[k];
  #pragma unroll
  for (int m = 0; m < 16; ++m) d[m] = X[(rc*16 + u)*17 + m];
  dft16(d, 1.0f);

  #pragma unroll
  for (int k1 = 0; k1 < 16; ++k1) {
    int j = u + (k1 << 4);
    int aa = j * (colbase + rc);
    float2 t1 = T256[(aa >> 8) & 255];
    t1.y = -t1.y;
    float2 tw = cmul(t1, TN[aa & 255]);
    out1[rowG + j] = pk2(cmul(d[k1], tw));
  }
}

// ---------------- FUSED: conv inverse -> finU + SS -> reverb forward -------
__global__ __launch_bounds__(256) void k_fft_out6fwd(
    const unsigned* __restrict__ W64in, const short* __restrict__ fnb,
    float* __restrict__ finU, float* __restrict__ scal,
    unsigned* __restrict__ DsOut)
{
  constexpr int N = 65536, NH = 32768;
  constexpr float FWD = -6.283185307179586f;
  constexpr float IVD = +6.283185307179586f;
  constexpr float S64 = 1.0f / 65536.0f;
  __shared__ float2 X[16*16*17];
  __shared__ float2 T256[256];   // FWD (for output twiddle)
  __shared__ float2 TN[256];     // FWD
  __shared__ float red[256];
  const int a = blockIdx.y;
  const int n1base = blockIdx.x << 4;
  const int r = threadIdx.x & 15;
  const int u = threadIdx.x >> 4;

  {
    float ang = FWD * ((float)threadIdx.x * (1.0f/256.0f));
    float sn, cs; __sincosf(ang, &sn, &cs);
    T256[threadIdx.x] = make_float2(cs, sn);
    float ang2 = FWD * ((float)threadIdx.x * (1.0f/(float)N));
    float sn2, cs2; __sincosf(ang2, &sn2, &cs2);
    TN[threadIdx.x] = make_float2(cs2, sn2);
  }

  const float emu = scal[SC_ENVMU + a];
  const float esd = scal[SC_ENVSD + a];
  const float egp = 0.3989422804014327f / esd;
  const float om0 = scal[SC_OM0 + a], om1 = scal[SC_OM1 + a];
  const float* ft = scal + SC_FTAB + a*128;

  // ---- inverse strided of conv spectrum ----
  float2 d[16];
  #pragma unroll
  for (int m = 0; m < 16; ++m) {
    int j = u + (m << 4);
    d[m] = upk2(W64in[(size_t)a * N + n1base + r + 256 * j]);
  }
  dft16(d, 1.0f);
  twiddleB(d, u, IVD);
  #pragma unroll
  for (int k = 0; k < 16; ++k) X[(u*16 + k)*17 + r] = d[k];
  __syncthreads();
  #pragma unroll
  for (int m = 0; m < 16; ++m) d[m] = X[(m*16 + u)*17 + r];
  dft16(d, 1.0f);

  // ---- finU (n < NH <=> k1 < 8) + partial sum of squares ----
  float fv[8];
  float ss = 0.0f;
  #pragma unroll
  for (int k1 = 0; k1 < 8; ++k1) {
    int n = n1base + r + 256 * (u + (k1 << 4));
    float resv  = d[k1].x * S64;
    float res2v = d[k1].y * S64;
    float uu = (float)n * (1.0f / 32767.0f);
    float te = (uu - emu) / esd;
    float envv = __expf(-0.5f * te * te) * egp;
    float pnv = bf2f(fnb[(size_t)a * NH + n]) * envv;
    float pos = ((float)n + 0.5f) * (1.0f/256.0f) - 0.5f;
    pos = fminf(fmaxf(pos, 0.0f), 127.0f);
    int i0 = (int)pos;
    float w = pos - (float)i0;
    int i1 = (i0 + 1 < 127) ? i0 + 1 : 127;
    float fc = ft[i0]*(1.0f-w) + ft[i1]*w;
    float f = pnv*om0 + (fc*resv + (1.0f-fc)*res2v)*om1;
    finU[(size_t)a * NH + n] = f;
    fv[k1] = f;
    ss += f * f;
  }
  red[threadIdx.x] = ss;
  __syncthreads();           // also guarantees all X reads above are done
  for (int s = 128; s > 0; s >>= 1) {
    if (threadIdx.x < s) red[threadIdx.x] += red[threadIdx.x + s];
    __syncthreads();
  }
  if (threadIdx.x == 0) scal[SC_PSS + a*16 + blockIdx.x] = red[0];

  // ---- forward strided of padded finU (same layout) ----
  #pragma unroll
  for (int m = 0; m < 16; ++m)
    d[m] = (m < 8) ? make_float2(fv[m], 0.0f) : make_float2(0.0f, 0.0f);
  dft16(d, -1.0f);
  twiddleB(d, u, FWD);
  #pragma unroll
  for (int k = 0; k < 16; ++k) X[(u*16 + k)*17 + r] = d[k];
  __syncthreads();
  #pragma unroll
  for (int m = 0; m < 16; ++m) d[m] = X[(m*16 + u)*17 + r];
  dft16(d, -1.0f);

  #pragma unroll
  for (int k1 = 0; k1 < 16; ++k1) {
    int j = u + (k1 << 4);
    int n = n1base + r + 256 * j;
    int aa = (n1base + r) * j;
    float2 tw = cmul(T256[(aa >> 8) & 255], TN[aa & 255]);
    DsOut[(size_t)a * N + n] = pk2(cmul(d[k1], tw));
  }
}

// ---------------- final inverse strided + inline norm + dry/wet mix --------
__global__ __launch_bounds__(256) void k_fft_s256_out3(
    const unsigned* __restrict__ W64in, const float* __restrict__ finU,
    const float* __restrict__ scal, float* __restrict__ out)
{
  constexpr int N = 65536, NH = 32768;
  constexpr float IVD = +6.283185307179586f;
  constexpr float S64 = 1.0f / 65536.0f;
  __shared__ float2 X[16*16*17];
  const int a = blockIdx.y;
  const int n1base = blockIdx.x << 4;
  const int r = threadIdx.x & 15;
  const int u = threadIdx.x >> 4;

  float ss = 0.0f;
  #pragma unroll
  for (int i = 0; i < 16; ++i) ss += scal[SC_PSS + a*16 + i];
  float fscale = scal[SC_AMPS + a] / (sqrtf(ss) + 1e-8f);
  float mixv = scal[SC_MIXV + a];
  float w1 = fscale * (1.0f - mixv);
  float w0 = fscale * mixv;

  float2 d[16];
  #pragma unroll
  for (int m = 0; m < 16; ++m) {
    int j = u + (m << 4);
    d[m] = upk2(W64in[(size_t)a * N + n1base + r + 256 * j]);
  }
  dft16(d, 1.0f);
  twiddleB(d, u, IVD);
  #pragma unroll
  for (int k = 0; k < 16; ++k) X[(u*16 + k)*17 + r] = d[k];
  __syncthreads();
  #pragma unroll
  for (int m = 0; m < 16; ++m) d[m] = X[(m*16 + u)*17 + r];
  dft16(d, 1.0f);

  #pragma unroll
  for (int k1 = 0; k1 < 8; ++k1) {
    int n = n1base + r + 256 * (u + (k1 << 4));
    out[(size_t)a * NH + n] =
        d[k1].x * S64 * w1 + finU[(size_t)a * NH + n] * w0;
  }
}

// ---------------- A repack + per-atom scalars (block 0) ---------------------
__global__ void k_packA(const float* __restrict__ rc, short* __restrict__ ctb,
    const float* __restrict__ mix, const float* __restrict__ decays,
    const float* __restrict__ fdec, const float* __restrict__ nf,
    const float* __restrict__ rf1, const float* __restrict__ rf2,
    const float* __restrict__ env, const float* __restrict__ amplitudes,
    const float* __restrict__ verb, const float* __restrict__ ln_w,
    const float* __restrict__ ln_b, const float* __restrict__ mw1,
    const float* __restrict__ mw2, const float* __restrict__ rw1,
    const float* __restrict__ rw2, float* __restrict__ scal,
    float* __restrict__ dout)
{
  int o = blockIdx.x * 256 + threadIdx.x;   // o = m*4096 + k
  {
    int m = o >> 12, k = o & 4095;
    int s = k >> 2, f = k & 3;
    float v = fmaxf(rc[m*4096 + f*1024 + s], 0.0f);
    ctb[o] = f2bf(v);
  }
  if (blockIdx.x != 0 || threadIdx.x >= 64) return;
  int a = threadIdx.x;
  float m0 = mix[a*2+0], m1 = mix[a*2+1];
  float mx = fmaxf(m0, m1);
  float e0 = expf(m0 - mx), e1 = expf(m1 - mx);
  float inv = 1.0f / (e0 + e1);
  scal[SC_OM0+a] = e0 * inv;
  scal[SC_OM1+a] = e1 * inv;
  scal[SC_NFMU+a] = nf[a*2+0];
  scal[SC_NFSD+a] = fabsf(nf[a*2+1]) + 1e-12f;
  scal[SC_RF1SD+a] = fabsf(rf1[a*2+1]) + 1e-12f;
  scal[SC_RF2SD+a] = fabsf(rf2[a*2+1]) + 1e-12f;
  scal[SC_ENVMU+a] = env[a*2+0];
  scal[SC_ENVSD+a] = fabsf(env[a*2+1] + 1e-12f) * 0.1f;
  float amp = fabsf(amplitudes[a]);
  scal[SC_AMPS+a] = amp;
  dout[2097152 + a] = amp;                       // output 1: amps
  float d  = 0.02f + (1.0f/(1.0f+expf(-decays[a]))) * (0.98f * 0.95f);
  float fd = 0.02f + (1.0f/(1.0f+expf(-fdec[a])))   * (0.98f * 0.95f);
  float pd = 1.0f, pf = 1.0f;
  for (int f = 0; f < 128; ++f) {
    pd *= d; pf *= fd;
    scal[SC_DTAB + a*128 + f] = pd;
    scal[SC_FTAB + a*128 + f] = pf;
  }
  float x0 = verb[a*4+0], x1 = verb[a*4+1], x2 = verb[a*4+2], x3 = verb[a*4+3];
  float mean = (x0+x1+x2+x3) * 0.25f;
  float d0 = x0-mean, d1 = x1-mean, d2 = x2-mean, d3 = x3-mean;
  float var = (d0*d0 + d1*d1 + d2*d2 + d3*d3) * 0.25f;
  float rs = 1.0f / sqrtf(var + 1e-5f);
  float h[4] = { d0*rs*ln_w[0]+ln_b[0], d1*rs*ln_w[1]+ln_b[1],
                 d2*rs*ln_w[2]+ln_b[2], d3*rs*ln_w[3]+ln_b[3] };
  float t[4], u[4];
  for (int j = 0; j < 4; ++j) {
    float s1 = 0.f, s2 = 0.f;
    for (int i2 = 0; i2 < 4; ++i2) {
      s1 += h[i2] * mw1[i2*4 + j];
      s2 += h[i2] * rw1[i2*4 + j];
    }
    t[j] = (s1 > 0.f) ? s1 : 0.01f*s1;
    u[j] = (s2 > 0.f) ? s2 : 0.01f*s2;
  }
  float ml = 0.f;
  for (int j = 0; j < 4; ++j) ml += t[j] * mw2[j];
  scal[SC_MIXV+a] = 1.0f / (1.0f + expf(-ml));
  float best = -1e30f; int bi = 0;
  for (int rr = 0; rr < 8; ++rr) {
    float lg = 0.f;
    for (int j = 0; j < 4; ++j) lg += u[j] * rw2[j*8 + rr];
    if (lg > best) { best = lg; bi = rr; }
  }
  ((int*)scal)[SC_ROOM + a] = bi;
}

// ---------------- resonances GEMM via MFMA: LDS-free, barrier-free ---------
// grid (512, 2) x 256 threads (4 waves; 4 blocks/CU -> 4 waves/SIMD);
// K half per blockIdx.y; prefetch x4. Partials rp[part*64+m][col] BF16.
__global__ __launch_bounds__(256) void k_gemm_mfma(
    const float* __restrict__ waves, const short* __restrict__ ctb,
    short* __restrict__ rp)
{
  const int t = threadIdx.x;
  const int w = t >> 6, lane = t & 63;
  const int ml = lane & 15, q = lane >> 4;
  const int col = blockIdx.x * 64 + w * 16 + ml;
  const int part = blockIdx.y;
  const int kb0 = part * 64;

  f32x4 acc[4] = {};

  const float* ws0 = waves + (size_t)(kb0*8 + 2*q) * 32768 + col;          // sine
  const float* ws1 = waves + (size_t)(1024 + kb0*8 + 2*q) * 32768 + col;   // saw
  const short* abase = ctb + (size_t)ml * 4096 + (size_t)kb0 * 32 + q * 8;

  #define LOADW(v, kbl) { size_t o = (size_t)(kbl) * (8*32768); \
    v[0] = ws0[o]; v[1] = ws0[o + 32768]; v[2] = ws1[o]; v[3] = ws1[o + 32768]; }

  #define DOKB(v, kbl) { \
    float sq0 = (v[0] > 0.f) ? 1.f : ((v[0] < 0.f) ? -1.f : v[0]); \
    float sq1 = (v[1] > 0.f) ? 1.f : ((v[1] < 0.f) ? -1.f : v[1]); \
    float tr0 = 2.f * fabsf(v[2]) - 1.f; \
    float tr1 = 2.f * fabsf(v[3]) - 1.f; \
    bf16x8 b; \
    b[0] = f2bf(v[0]); b[1] = f2bf(v[2]); b[2] = f2bf(sq0); b[3] = f2bf(tr0); \
    b[4] = f2bf(v[1]); b[5] = f2bf(v[3]); b[6] = f2bf(sq1); b[7] = f2bf(tr1); \
    const short* ap = abase + (size_t)(kbl) * 32; \
    acc[0] = __builtin_amdgcn_mfma_f32_16x16x32_bf16(*(const bf16x8*)(ap),                   b, acc[0], 0,0,0); \
    acc[1] = __builtin_amdgcn_mfma_f32_16x16x32_bf16(*(const bf16x8*)(ap + (size_t)16*4096), b, acc[1], 0,0,0); \
    acc[2] = __builtin_amdgcn_mfma_f32_16x16x32_bf16(*(const bf16x8*)(ap + (size_t)32*4096), b, acc[2], 0,0,0); \
    acc[3] = __builtin_amdgcn_mfma_f32_16x16x32_bf16(*(const bf16x8*)(ap + (size_t)48*4096), b, acc[3], 0,0,0); }

  float vA[4], vB[4], vC[4], vD[4];
  LOADW(vA, 0);
  LOADW(vB, 1);
  LOADW(vC, 2);
  LOADW(vD, 3);
  for (int kbl = 0; kbl < 64; kbl += 4) {
    DOKB(vA, kbl);
    if (kbl + 4 < 64) LOADW(vA, kbl + 4);
    DOKB(vB, kbl + 1);
    if (kbl + 5 < 64) LOADW(vB, kbl + 5);
    DOKB(vC, kbl + 2);
    if (kbl + 6 < 64) LOADW(vC, kbl + 6);
    DOKB(vD, kbl + 3);
    if (kbl + 7 < 64) LOADW(vD, kbl + 7);
  }
  #undef LOADW
  #undef DOKB

  #pragma unroll
  for (int mt = 0; mt < 4; ++mt) {
    #pragma unroll
    for (int rr = 0; rr < 4; ++rr) {
      rp[(size_t)(part*64 + mt*16 + q*4 + rr) * 32768 + col] = f2bf(acc[mt][rr]);
    }
  }
}

// ============================================================================
extern "C" void kernel_launch(void* const* d_in, const int* in_sizes, int n_in,
                              void* d_out, int out_size, void* d_ws, size_t ws_size,
                              hipStream_t stream)
{
  const float* mix   = (const float*)d_in[1];
  const float* dec   = (const float*)d_in[2];
  const float* fdec  = (const float*)d_in[3];
  const float* rc    = (const float*)d_in[4];
  const float* nf    = (const float*)d_in[5];
  const float* rf1   = (const float*)d_in[6];
  const float* rf2   = (const float*)d_in[7];
  const float* env   = (const float*)d_in[8];
  const float* amps  = (const float*)d_in[9];
  const float* verb  = (const float*)d_in[10];
  const float* noise = (const float*)d_in[11];
  const float* waves = (const float*)d_in[12];
  const float* lnw   = (const float*)d_in[13];
  const float* lnb   = (const float*)d_in[14];
  const float* mw1   = (const float*)d_in[15];
  const float* mw2   = (const float*)d_in[16];
  const float* rw1   = (const float*)d_in[17];
  const float* rw2   = (const float*)d_in[18];
  const float* rirs  = (const float*)d_in[19];
  float* out = (float*)d_out;
  float* w   = (float*)d_ws;

  if (ws_size < WS_FLOATS * 4ULL) return;

  float*    scal = w + OFF_SCAL;
  short*    ctb  = (short*)(w + OFF_CT);
  short*    rp   = (short*)(w + OFF_RP);     // bf16, dead before Ds
  unsigned* P    = (unsigned*)(w + OFF_P);   // bf16-packed, half-transformed
  unsigned* Ds   = (unsigned*)(w + OFF_DS);
  unsigned* W64  = (unsigned*)(w + OFF_W64);
  unsigned* RSs  = (unsigned*)(w + OFF_RSS);
  unsigned* NSs  = (unsigned*)(w + OFF_NSS); // in W64 region (early)
  unsigned* W2   = (unsigned*)(w + OFF_W2);  // in W64 region (early)
  float*    finU = w + OFF_FINU;
  unsigned* W1   = (unsigned*)(w + OFF_W1);
  short*    fnb  = (short*)(w + OFF_FN);     // fn bf16
  unsigned* FRP  = (unsigned*)(w + OFF_FRP); // fr1+i*fr2 packed
  unsigned* IRS  = (unsigned*)(w + OFF_IRS); // bf16-packed, half-transformed
  const int* room = ((const int*)(w + OFF_SCAL)) + SC_ROOM;

  // A repack + per-atom scalars (block 0)
  k_packA<<<1024, 256, 0, stream>>>(rc, ctb, mix, dec, fdec, nf, rf1, rf2, env,
                                    amps, verb, lnw, lnb, mw1, mw2, rw1, rw2,
                                    scal, out);
  k_gemm_mfma<<<dim3(512, 2), 256, 0, stream>>>(waves, ctb, rp);

  // merged RS (sum 2 bf16 GEMM partials) + NS chains: 3 dispatches
  k_fft_s128_first<<<dim3(8,128),256,0,stream>>>(RSs, NSs, rp, noise);
  k_fft_m128_both<<<dim3(16,128),256,0,stream>>>(RSs, NSs, W1, W2, scal);
  k_fft_s128_last<<<dim3(8,128),256,0,stream>>>(W1, W2, FRP, fnb);

  // merged Ds + P + IRS forward strided (all half-transformed, bf16)
  k_fft_s256_DsPI<<<dim3(16,136),256,0,stream>>>(Ds, P, IRS, FRP, fnb, rirs, scal);

  // conv mid: fft(Ds)*fft(P) -> inverse-contig -> W64
  k_fft_mid256dual<<<dim3(16,64),256,0,stream>>>(Ds, P, W64, nullptr);

  // FUSED: conv inverse -> finU + SS partials -> reverb forward -> Ds
  k_fft_out6fwd<<<dim3(16,64),256,0,stream>>>(W64, fnb, finU, scal, Ds);

  // reverb mid: fft(Ds half) * fft(IRS half[room]) -> inverse-contig -> W64
  // *** NO contig FFT between strided and mid (round-2 bug) ***
  k_fft_mid256dual<<<dim3(16,64),256,0,stream>>>(Ds, IRS, W64, room);

  // final inverse + inline norm (from PSS partials) + dry/wet mix
  k_fft_s256_out3<<<dim3(16,64),256,0,stream>>>(W64, finU, scal, out);
}

// Round 16
// 290.830 us; speedup vs baseline: 1.0326x; 1.0326x over previous
//
#include <hip/hip_runtime.h>

// ============================================================================
// Model_22016002360008 — synth forward pass.
//  GEMM: bf16 MFMA 16x16x32, LDS-free, barrier-free; K split x2; prefetch x4;
//        512-thread blocks, grid (256,2) [R15's 256-thr split reverted].
//  FFT: complex four-step, N = N1*256, digit-permuted spectrum
//       addr = k2*N1 + k1, true bin k = k2 + 256*k1.
//  ALL complex spectra + GEMM partials stored PACKED BF16; fr1/fr2 packed as
//  one uint (FRP), fn bf16; finU fp32 (feeds dry output). FFT arithmetic fp32.
//  Length-256 transforms: REGISTER 16x16 FFT. 32K mid: radix-4 LDS Stockham.
//  Fusions: scalars folded into packA; conv-inverse+finU+SS+reverb-forward in
//  one kernel; fscale deferred to final pass; Ds+P+IRS forwards one dispatch.
//  !! mid's input must be STRIDED-ONLY (half-transformed) data — never run
//  !! a contig FFT before a mid kernel (round-2 bug, reverb path).
// ============================================================================

typedef __attribute__((ext_vector_type(8))) short bf16x8;
typedef __attribute__((ext_vector_type(4))) float f32x4;

constexpr int SC_OM0   = 0;
constexpr int SC_OM1   = 64;
constexpr int SC_NFMU  = 128;
constexpr int SC_NFSD  = 192;
constexpr int SC_RF1SD = 256;
constexpr int SC_RF2SD = 320;
constexpr int SC_ENVMU = 384;
constexpr int SC_ENVSD = 448;
constexpr int SC_AMPS  = 512;
constexpr int SC_MIXV  = 576;
constexpr int SC_ROOM  = 832;
constexpr int SC_PSS   = 1024;   // 64 x 16 partial sum-of-squares
constexpr int SC_DTAB  = 4096;
constexpr int SC_FTAB  = 12288;

// ---------------- workspace layout (float offsets; bf16 buffers use less) ---
constexpr size_t OFF_SCAL = 0;
constexpr size_t OFF_CT   = 65536;
constexpr size_t OFF_P    = 327680;       // P half-transformed (bf16 packed)
constexpr size_t OFF_DS   = 8716288;      // Ds (bf16); rp (bf16) aliases
constexpr size_t OFF_RP   = OFF_DS;
constexpr size_t OFF_W64  = 17104896;     // conv/rev work; early: NSs + W2
constexpr size_t OFF_NSS  = OFF_W64;
constexpr size_t OFF_W2   = OFF_W64 + 4194304;
constexpr size_t OFF_RSS  = 25493504;     // RSs -> finU
constexpr size_t OFF_FINU = OFF_RSS;
constexpr size_t OFF_W1   = 29687808;
constexpr size_t OFF_FN   = 38076416;     // fn bf16 (shorts)
constexpr size_t OFF_FRP  = 40173568;     // fr1+i*fr2 packed (uints)
constexpr size_t OFF_IRS  = 44367872;
constexpr size_t WS_FLOATS= 45416448;

__device__ __forceinline__ float2 cmul(float2 a, float2 b) {
  return make_float2(a.x*b.x - a.y*b.y, a.x*b.y + a.y*b.x);
}

__device__ __forceinline__ short f2bf(float x) {
  unsigned u = __float_as_uint(x);
  u = (u + 0x7FFFu + ((u >> 16) & 1u)) >> 16;
  return (short)u;
}
__device__ __forceinline__ float bf2f(short s) {
  return __uint_as_float((unsigned)(unsigned short)s << 16);
}
__device__ __forceinline__ unsigned pk2(float2 v) {
  return (unsigned)(unsigned short)f2bf(v.x)
       | ((unsigned)(unsigned short)f2bf(v.y) << 16);
}
__device__ __forceinline__ float2 upk2(unsigned u) {
  return make_float2(__uint_as_float(u << 16),
                     __uint_as_float(u & 0xFFFF0000u));
}

// ---------------- 16-point DFT in registers (natural order in/out) ---------
__device__ __forceinline__ void dft16(float2 d[16], float ei)
{
  const float CA[4] = {1.0f, 0.92387953251128674f, 0.70710678118654752f, 0.38268343236508977f};
  const float SA[4] = {0.0f, 0.38268343236508977f, 0.70710678118654752f, 0.92387953251128674f};
  const float CB[4] = {1.0f, 0.70710678118654752f, 0.0f, -0.70710678118654752f};
  const float SB[4] = {0.0f, 0.70710678118654752f, 1.0f, 0.70710678118654752f};
  float2 e[16];
  #pragma unroll
  for (int q = 0; q < 4; ++q) {
    float2 x0 = d[q], x1 = d[q+4], x2 = d[q+8], x3 = d[q+12];
    float ca = CA[q], sa = ei*SA[q], cb = CB[q], sb = ei*SB[q];
    float2 sum1 = make_float2(x0.x+x2.x, x0.y+x2.y);
    float2 d1   = make_float2(x0.x-x2.x, x0.y-x2.y);
    float2 dif1 = make_float2(d1.x*ca - d1.y*sa, d1.x*sa + d1.y*ca);
    float2 sum2 = make_float2(x1.x+x3.x, x1.y+x3.y);
    float2 d2   = make_float2(x1.x-x3.x, x1.y-x3.y);
    float2 dt   = make_float2(d2.x*ca - d2.y*sa, d2.x*sa + d2.y*ca);
    float2 dif2 = make_float2(-ei*dt.y, ei*dt.x);
    float2 Dm   = make_float2(sum1.x-sum2.x, sum1.y-sum2.y);
    float2 Dm2  = make_float2(dif1.x-dif2.x, dif1.y-dif2.y);
    e[4*q+0] = make_float2(sum1.x+sum2.x, sum1.y+sum2.y);
    e[4*q+1] = make_float2(dif1.x+dif2.x, dif1.y+dif2.y);
    e[4*q+2] = make_float2(Dm.x*cb - Dm.y*sb, Dm.x*sb + Dm.y*cb);
    e[4*q+3] = make_float2(Dm2.x*cb - Dm2.y*sb, Dm2.x*sb + Dm2.y*cb);
  }
  #pragma unroll
  for (int q = 0; q < 4; ++q) {
    float2 x0 = e[q], x1 = e[q+4], x2 = e[q+8], x3 = e[q+12];
    float2 sum1 = make_float2(x0.x+x2.x, x0.y+x2.y);
    float2 dif1 = make_float2(x0.x-x2.x, x0.y-x2.y);
    float2 sum2 = make_float2(x1.x+x3.x, x1.y+x3.y);
    float2 d2   = make_float2(x1.x-x3.x, x1.y-x3.y);
    float2 dif2 = make_float2(-ei*d2.y, ei*d2.x);
    d[q]    = make_float2(sum1.x+sum2.x, sum1.y+sum2.y);
    d[q+4]  = make_float2(dif1.x+dif2.x, dif1.y+dif2.y);
    d[q+8]  = make_float2(sum1.x-sum2.x, sum1.y-sum2.y);
    d[q+12] = make_float2(dif1.x-dif2.x, dif1.y-dif2.y);
  }
}

__device__ __forceinline__ void twiddleB(float2 d[16], int u, float dir2pi)
{
  float sn1, cs1;
  __sincosf(dir2pi * ((float)u * (1.0f/256.0f)), &sn1, &cs1);
  float2 w1 = make_float2(cs1, sn1);
  float2 tw = w1;
  #pragma unroll
  for (int k = 1; k < 16; ++k) { d[k] = cmul(d[k], tw); tw = cmul(tw, w1); }
}

// ---------------- in-LDS RADIX-4 Stockham (LEN=128, 32K mid only) ----------
template<int LEN>
__device__ float2* lds_fft(float2* src, float2* dst,
                           const float2* __restrict__ T256,
                           float dsign, float ei)
{
  constexpr int QB  = LEN >> 2;
  constexpr int FPT = (16 * QB) >> 8;
  constexpr int NST = (LEN == 256) ? 4 : 3;
  int n = LEN, s = 1, ls = 0;
  int sh = (LEN == 256) ? 0 : 1;

  if (LEN == 128) {
    constexpr int HB = LEN >> 1;
    constexpr int BPT = (16 * HB) >> 8;
    __syncthreads();
    #pragma unroll
    for (int b = 0; b < BPT; ++b) {
      int g = threadIdx.x + (b << 8);
      int row = g / HB;
      int beta = g & (HB - 1);
      float2 tj = T256[beta << 1];
      float cs = tj.x, sn = dsign * tj.y;
      float2 av = src[row*LEN + (beta ^ row)];
      float2 bv = src[row*LEN + ((beta + HB) ^ row)];
      float2 sum = make_float2(av.x + bv.x, av.y + bv.y);
      float2 dif = make_float2(av.x - bv.x, av.y - bv.y);
      float2 tw  = make_float2(dif.x*cs - dif.y*sn, dif.x*sn + dif.y*cs);
      dst[row*LEN + ((2*beta)     ^ row)] = sum;
      dst[row*LEN + ((2*beta + 1) ^ row)] = tw;
    }
    float2* t = src; src = dst; dst = t;
    n = 64; s = 2; ls = 1; sh = 2;
  }

  for (int st = 0; st < NST; ++st) {
    __syncthreads();
    #pragma unroll
    for (int b = 0; b < FPT; ++b) {
      int g   = threadIdx.x + (b << 8);
      int row = g / QB;
      int q   = g & (QB - 1);
      int p1  = q >> ls;
      int blo = q & (s - 1);
      int base = row * LEN;
      float2 x0 = src[base + ( q         ^ row)];
      float2 x1 = src[base + ((q +   QB) ^ row)];
      float2 x2 = src[base + ((q + 2*QB) ^ row)];
      float2 x3 = src[base + ((q + 3*QB) ^ row)];
      float2 tA = T256[p1 << sh];
      float caA = tA.x, saA = dsign * tA.y;
      float2 tB = T256[p1 << (sh + 1)];
      float caB = tB.x, saB = dsign * tB.y;
      float2 sum1 = make_float2(x0.x + x2.x, x0.y + x2.y);
      float2 d1   = make_float2(x0.x - x2.x, x0.y - x2.y);
      float2 dif1 = make_float2(d1.x*caA - d1.y*saA, d1.x*saA + d1.y*caA);
      float2 sum2 = make_float2(x1.x + x3.x, x1.y + x3.y);
      float2 d2   = make_float2(x1.x - x3.x, x1.y - x3.y);
      float2 dt   = make_float2(d2.x*caA - d2.y*saA, d2.x*saA + d2.y*caA);
      float2 dif2 = make_float2(-ei * dt.y, ei * dt.x);
      float2 S  = make_float2(sum1.x + sum2.x, sum1.y + sum2.y);
      float2 Dm = make_float2(sum1.x - sum2.x, sum1.y - sum2.y);
      float2 D  = make_float2(Dm.x*caB - Dm.y*saB, Dm.x*saB + Dm.y*caB);
      float2 S2 = make_float2(dif1.x + dif2.x, dif1.y + dif2.y);
      float2 Dm2= make_float2(dif1.x - dif2.x, dif1.y - dif2.y);
      float2 D2 = make_float2(Dm2.x*caB - Dm2.y*saB, Dm2.x*saB + Dm2.y*caB);
      int w0 = (p1 << (ls + 2)) | blo;
      dst[base + ( w0          ^ row)] = S;
      dst[base + ((w0 +     s) ^ row)] = S2;
      dst[base + ((w0 + 2 * s) ^ row)] = D;
      dst[base + ((w0 + 3 * s) ^ row)] = D2;
    }
    float2* t = src; src = dst; dst = t;
    n >>= 2; s <<= 2; ls += 2; sh += 2;
  }
  __syncthreads();
  return src;
}

// ---------------- merged Ds + P + IRS forward strided (64K) ----------------
// y<64: Ds = fwd_half(pad((fr1 + i*fr2) * decay)) from packed FRP, atom y
// 64<=y<128: P = fwd_half(pad(fn_bf16 * gauss_env)), atom y-64
// y>=128: IRS = fwd_half(pad(rirs)), room y-128
__global__ __launch_bounds__(256) void k_fft_s256_DsPI(
    unsigned* __restrict__ Ds, unsigned* __restrict__ P,
    unsigned* __restrict__ IRS,
    const unsigned* __restrict__ FRP, const short* __restrict__ fnb,
    const float* __restrict__ rirs, const float* __restrict__ scal)
{
  constexpr int N = 65536, NH = 32768;
  constexpr float FWD = -6.283185307179586f;
  __shared__ float2 X[16*16*17];
  __shared__ float2 T256[256];
  __shared__ float2 TN[256];
  const int mode = (blockIdx.y < 64) ? 0 : ((blockIdx.y < 128) ? 1 : 2);
  const int a = (mode == 0) ? blockIdx.y : ((mode == 1) ? blockIdx.y - 64 : blockIdx.y - 128);
  const int n1base = blockIdx.x << 4;
  const int r = threadIdx.x & 15;
  const int u = threadIdx.x >> 4;

  {
    float ang = FWD * ((float)threadIdx.x * (1.0f/256.0f));
    float sn, cs; __sincosf(ang, &sn, &cs);
    T256[threadIdx.x] = make_float2(cs, sn);
    float ang2 = FWD * ((float)threadIdx.x * (1.0f/(float)N));
    float sn2, cs2; __sincosf(ang2, &sn2, &cs2);
    TN[threadIdx.x] = make_float2(cs2, sn2);
  }

  float emu = 0.f, esd = 1.f, egp = 0.f;
  if (mode == 1) {
    emu = scal[SC_ENVMU + a];
    esd = scal[SC_ENVSD + a];
    egp = 0.3989422804014327f / esd;
  }

  float2 d[16];
  #pragma unroll
  for (int m = 0; m < 16; ++m) {
    int j = u + (m << 4);
    int n = n1base + r + 256 * j;
    float2 v = make_float2(0.0f, 0.0f);
    if (n < NH) {
      if (mode == 0) {
        float pos = ((float)n + 0.5f) * (1.0f/256.0f) - 0.5f;
        pos = fminf(fmaxf(pos, 0.0f), 127.0f);
        int i0 = (int)pos;
        float w = pos - (float)i0;
        int i1 = (i0 + 1 < 127) ? i0 + 1 : 127;
        const float* dt = scal + SC_DTAB + a*128;
        float de = dt[i0]*(1.0f-w) + dt[i1]*w;
        float2 fr = upk2(FRP[(size_t)a * NH + n]);
        v = make_float2(fr.x * de, fr.y * de);
      } else if (mode == 1) {
        float uu = (float)n * (1.0f / 32767.0f);
        float te = (uu - emu) / esd;
        float envv = __expf(-0.5f * te * te) * egp;
        v = make_float2(bf2f(fnb[(size_t)a * NH + n]) * envv, 0.0f);
      } else {
        v = make_float2(rirs[(size_t)a * NH + n], 0.0f);
      }
    }
    d[m] = v;
  }

  dft16(d, -1.0f);
  twiddleB(d, u, FWD);
  #pragma unroll
  for (int k = 0; k < 16; ++k) X[(u*16 + k)*17 + r] = d[k];
  __syncthreads();
  #pragma unroll
  for (int m = 0; m < 16; ++m) d[m] = X[(m*16 + u)*17 + r];
  dft16(d, -1.0f);

  unsigned* outp = (mode == 0) ? Ds : ((mode == 1) ? P : IRS);
  #pragma unroll
  for (int k1 = 0; k1 < 16; ++k1) {
    int j = u + (k1 << 4);
    int n = n1base + r + 256 * j;
    int aa = (n1base + r) * j;
    float2 tw = cmul(T256[(aa >> 8) & 255], TN[aa & 255]);
    outp[(size_t)a * N + n] = pk2(cmul(d[k1], tw));
  }
}

// ---------------- merged first strided (32K): RS (y<64) + NS (y>=64) -------
__global__ __launch_bounds__(256) void k_fft_s128_first(
    unsigned* __restrict__ RSs, unsigned* __restrict__ NSs,
    const short* __restrict__ rez, const float* __restrict__ noise)
{
  constexpr int N1 = 128, N = 32768;
  constexpr float FWD = -6.283185307179586f;
  __shared__ float2 X[16*16*17];
  __shared__ float2 T256[256];
  __shared__ float2 TN[128];
  const bool isRS = blockIdx.y < 64;
  const int a = isRS ? blockIdx.y : blockIdx.y - 64;
  const int n1base = blockIdx.x << 4;
  const int r = threadIdx.x & 15;
  const int u = threadIdx.x >> 4;

  {
    float ang = FWD * ((float)threadIdx.x * (1.0f/256.0f));
    float sn, cs; __sincosf(ang, &sn, &cs);
    T256[threadIdx.x] = make_float2(cs, sn);
    if (threadIdx.x < 128) {
      float ang2 = FWD * ((float)threadIdx.x * (1.0f/(float)N));
      float sn2, cs2; __sincosf(ang2, &sn2, &cs2);
      TN[threadIdx.x] = make_float2(cs2, sn2);
    }
  }

  float2 d[16];
  #pragma unroll
  for (int m = 0; m < 16; ++m) {
    int j = u + (m << 4);
    int n = n1base + r + N1 * j;
    float x = isRS ? (bf2f(rez[(size_t)a * N + n]) +
                      bf2f(rez[(size_t)(64 + a) * N + n]))
                   : noise[(size_t)a * N + n];
    d[m] = make_float2(x, 0.0f);
  }

  dft16(d, -1.0f);
  twiddleB(d, u, FWD);
  #pragma unroll
  for (int k = 0; k < 16; ++k) X[(u*16 + k)*17 + r] = d[k];
  __syncthreads();
  #pragma unroll
  for (int m = 0; m < 16; ++m) d[m] = X[(m*16 + u)*17 + r];
  dft16(d, -1.0f);

  unsigned* outp = isRS ? RSs : NSs;
  #pragma unroll
  for (int k1 = 0; k1 < 16; ++k1) {
    int j = u + (k1 << 4);
    int n = n1base + r + N1 * j;
    int aa = (n1base + r) * j;
    float2 tw = cmul(T256[(aa >> 7) & 255], TN[aa & 127]);
    outp[(size_t)a * N + n] = pk2(cmul(d[k1], tw));
  }
}

// ---------------- merged 32K mid: RS complex filter (y<64) / NS gauss ------
__global__ __launch_bounds__(256) void k_fft_m128_both(
    const unsigned* __restrict__ RSs, const unsigned* __restrict__ NSs,
    unsigned* __restrict__ W1, unsigned* __restrict__ W2,
    const float* __restrict__ scal)
{
  constexpr int N1 = 128;
  constexpr int N = N1 * 256;
  constexpr int ITERS = (16 * N1) >> 8;
  constexpr int LOG2N1 = 7;
  constexpr float FWD = -6.283185307179586f;
  constexpr float IVD = +6.283185307179586f;
  __shared__ float2 A[16 * N1];
  __shared__ float2 B[16 * N1];
  __shared__ float2 T256[256];
  __shared__ float2 TN[N1];
  const bool isRS = blockIdx.y < 64;
  const int a = isRS ? blockIdx.y : blockIdx.y - 64;
  const int colbase = blockIdx.x << 4;

  {
    float ang = FWD * ((float)threadIdx.x * (1.0f/256.0f));
    float sn, cs; __sincosf(ang, &sn, &cs);
    T256[threadIdx.x] = make_float2(cs, sn);
    if (threadIdx.x < N1) {
      float ang2 = IVD * ((float)threadIdx.x * (1.0f/(float)N));
      float sn2, cs2; __sincosf(ang2, &sn2, &cs2);
      TN[threadIdx.x] = make_float2(cs2, sn2);
    }
  }

  float mu = 0.f, isd1 = 0.f, g1 = 0.f, isd2 = 0.f, g2 = 0.f;
  if (isRS) {
    float s1 = scal[SC_RF1SD + a], s2 = scal[SC_RF2SD + a];
    isd1 = 1.0f/s1; g1 = 0.3989422804014327f/s1;
    isd2 = 1.0f/s2; g2 = 0.3989422804014327f/s2;
  } else {
    float sd = scal[SC_NFSD + a]; mu = scal[SC_NFMU + a];
    isd1 = 1.0f/sd; g1 = 0.3989422804014327f/sd;
  }
  const unsigned* zin = (isRS ? RSs : NSs) + (size_t)a * N;
  unsigned* out = (isRS ? W1 : W2) + (size_t)a * N;

  #pragma unroll
  for (int it = 0; it < ITERS; ++it) {
    int flat = threadIdx.x + (it << 8);
    int c = flat / N1, j = flat & (N1 - 1);
    A[c*N1 + (j ^ c)] = upk2(zin[(size_t)(colbase + c) * N1 + j]);
  }
  float2* cur = lds_fft<N1>(A, B, T256, 1.0f, -1.0f);
  float2* alt = (cur == A) ? B : A;

  #pragma unroll
  for (int it = 0; it < ITERS; ++it) {
    int flat = threadIdx.x + (it << 8);
    int c = flat / N1, j = flat & (N1 - 1);
    int idx = c*N1 + (j ^ c);
    float2 v = cur[idx];
    int k  = (colbase + c) + (j << 8);          // true bin
    int kk = (k <= N - k) ? k : N - k;          // hermitian mirror
    if (isRS) {
      float fr = (float)kk * (2.0f/(float)N);
      float t1 = fr * isd1, t2 = fr * isd2;
      float ga = __expf(-0.5f * t1 * t1) * g1;   // G1 (real)
      float gb = __expf(-0.5f * t2 * t2) * g2;   // G2 (imag)
      v = make_float2(v.x*ga - v.y*gb, v.x*gb + v.y*ga);
    } else {
      float t = ((float)kk * (2.0f/(float)N) - mu) * isd1;
      float g = __expf(-0.5f * t * t) * g1;
      v.x *= g; v.y *= g;
    }
    cur[idx] = v;
  }

  float2* r2 = lds_fft<N1>(cur, alt, T256, -1.0f, 1.0f);

  #pragma unroll
  for (int it = 0; it < ITERS; ++it) {
    int flat = threadIdx.x + (it << 8);
    int c = flat / N1, j = flat & (N1 - 1);
    float2 v = r2[c*N1 + (j ^ c)];
    int aa = j * (colbase + c);
    float2 t1 = T256[(aa >> LOG2N1) & 255];
    t1.y = -t1.y;
    float2 tw = cmul(t1, TN[aa & (N1 - 1)]);
    out[(size_t)(colbase + c) * N1 + j] = pk2(cmul(v, tw));
  }
}

// ---------------- merged final strided (32K inverse) -----------------------
// y<64: W1 -> FRP (fr1=re, fr2=im packed).  y>=64: W2 -> fn bf16 (re).
__global__ __launch_bounds__(256) void k_fft_s128_last(
    const unsigned* __restrict__ W1, const unsigned* __restrict__ W2,
    unsigned* __restrict__ FRP, short* __restrict__ fnb)
{
  constexpr int N1 = 128, N = 32768;
  constexpr float IVD = +6.283185307179586f;
  constexpr float S32 = 1.0f / 32768.0f;
  __shared__ float2 X[16*16*17];
  const bool isRS = blockIdx.y < 64;
  const int a = isRS ? blockIdx.y : blockIdx.y - 64;
  const int n1base = blockIdx.x << 4;
  const int r = threadIdx.x & 15;
  const int u = threadIdx.x >> 4;

  const unsigned* cb = (isRS ? W1 : W2) + (size_t)a * N;
  float2 d[16];
  #pragma unroll
  for (int m = 0; m < 16; ++m) {
    int j = u + (m << 4);
    d[m] = upk2(cb[n1base + r + N1 * j]);
  }
  dft16(d, 1.0f);
  twiddleB(d, u, IVD);
  #pragma unroll
  for (int k = 0; k < 16; ++k) X[(u*16 + k)*17 + r] = d[k];
  __syncthreads();
  #pragma unroll
  for (int m = 0; m < 16; ++m) d[m] = X[(m*16 + u)*17 + r];
  dft16(d, 1.0f);

  #pragma unroll
  for (int k1 = 0; k1 < 16; ++k1) {
    int j = u + (k1 << 4);
    int n = n1base + r + N1 * j;
    if (isRS) {
      FRP[(size_t)a * N + n] = pk2(make_float2(d[k1].x * S32, d[k1].y * S32));
    } else {
      fnb[(size_t)a * N + n] = f2bf(d[k1].x * S32);
    }
  }
}

// ---------------- fused middle, 64K (register FFT, dual-operand) -----------
// zin STRIDED-ONLY; zin2half also HALF-TRANSFORMED (its contig FFT runs here
// in-register). roomArr == nullptr -> batch index a; else room[a] (IRS).
__global__ __launch_bounds__(256) void k_fft_mid256dual(
    const unsigned* __restrict__ zin, const unsigned* __restrict__ zin2half,
    unsigned* __restrict__ out1, const int* __restrict__ roomArr)
{
  constexpr int N = 65536;
  constexpr float FWD = -6.283185307179586f;
  constexpr float IVD = +6.283185307179586f;
  __shared__ float2 X[16*16*17];
  __shared__ float2 T256[256];
  __shared__ float2 TN[256];
  const int a = blockIdx.y;
  const int colbase = blockIdx.x << 4;
  const int u  = threadIdx.x & 15;
  const int rc = threadIdx.x >> 4;

  {
    float ang = FWD * ((float)threadIdx.x * (1.0f/256.0f));
    float sn, cs; __sincosf(ang, &sn, &cs);
    T256[threadIdx.x] = make_float2(cs, sn);
    float ang2 = IVD * ((float)threadIdx.x * (1.0f/(float)N));
    float sn2, cs2; __sincosf(ang2, &sn2, &cs2);
    TN[threadIdx.x] = make_float2(cs2, sn2);
  }
  __syncthreads();

  const unsigned* z2 = zin2half + (size_t)(roomArr ? roomArr[a] : a) * N;
  const size_t rowG = (size_t)a * N + (size_t)(colbase + rc) * 256;
  const size_t rowZ2 = (size_t)(colbase + rc) * 256;

  float2 d[16];
  #pragma unroll
  for (int m = 0; m < 16; ++m) d[m] = upk2(zin[rowG + u + (m << 4)]);
  dft16(d, -1.0f);
  twiddleB(d, u, FWD);
  #pragma unroll
  for (int k = 0; k < 16; ++k) X[(rc*16 + k)*17 + u] = d[k];
  #pragma unroll
  for (int m = 0; m < 16; ++m) d[m] = X[(rc*16 + u)*17 + m];
  dft16(d, -1.0f);

  float2 stash[16];
  #pragma unroll
  for (int k = 0; k < 16; ++k) stash[k] = d[k];
  #pragma unroll
  for (int m = 0; m < 16; ++m) d[m] = upk2(z2[rowZ2 + u + (m << 4)]);
  dft16(d, -1.0f);
  twiddleB(d, u, FWD);
  #pragma unroll
  for (int k = 0; k < 16; ++k) X[(rc*16 + k)*17 + u] = d[k];
  #pragma unroll
  for (int m = 0; m < 16; ++m) d[m] = X[(rc*16 + u)*17 + m];
  dft16(d, -1.0f);
  #pragma unroll
  for (int k = 0; k < 16; ++k) d[k] = cmul(stash[k], d[k]);

  dft16(d, 1.0f);
  twiddleB(d, u, IVD);
  #pragma unroll
  for (int k = 0; k < 16; ++k) X[(rc*16 + k)*17 + u] = d[k];
  #pragma unroll
  for (int m = 0; m < 16; ++m) d[m] = X[(rc*16 + u)*17 + m];
  dft16(d, 1.0f);

  #pragma unroll
  for (int k1 = 0; k1 < 16; ++k1) {
    int j = u + (k1 << 4);
    int aa = j * (colbase + rc);
    float2 t1 = T256[(aa >> 8) & 255];
    t1.y = -t1.y;
    float2 tw = cmul(t1, TN[aa & 255]);
    out1[rowG + j] = pk2(cmul(d[k1], tw));
  }
}

// ---------------- FUSED: conv inverse -> finU + SS -> reverb forward -------
__global__ __launch_bounds__(256) void k_fft_out6fwd(
    const unsigned* __restrict__ W64in, const short* __restrict__ fnb,
    float* __restrict__ finU, float* __restrict__ scal,
    unsigned* __restrict__ DsOut)
{
  constexpr int N = 65536, NH = 32768;
  constexpr float FWD = -6.283185307179586f;
  constexpr float IVD = +6.283185307179586f;
  constexpr float S64 = 1.0f / 65536.0f;
  __shared__ float2 X[16*16*17];
  __shared__ float2 T256[256];   // FWD (for output twiddle)
  __shared__ float2 TN[256];     // FWD
  __shared__ float red[256];
  const int a = blockIdx.y;
  const int n1base = blockIdx.x << 4;
  const int r = threadIdx.x & 15;
  const int u = threadIdx.x >> 4;

  {
    float ang = FWD * ((float)threadIdx.x * (1.0f/256.0f));
    float sn, cs; __sincosf(ang, &sn, &cs);
    T256[threadIdx.x] = make_float2(cs, sn);
    float ang2 = FWD * ((float)threadIdx.x * (1.0f/(float)N));
    float sn2, cs2; __sincosf(ang2, &sn2, &cs2);
    TN[threadIdx.x] = make_float2(cs2, sn2);
  }

  const float emu = scal[SC_ENVMU + a];
  const float esd = scal[SC_ENVSD + a];
  const float egp = 0.3989422804014327f / esd;
  const float om0 = scal[SC_OM0 + a], om1 = scal[SC_OM1 + a];
  const float* ft = scal + SC_FTAB + a*128;

  // ---- inverse strided of conv spectrum ----
  float2 d[16];
  #pragma unroll
  for (int m = 0; m < 16; ++m) {
    int j = u + (m << 4);
    d[m] = upk2(W64in[(size_t)a * N + n1base + r + 256 * j]);
  }
  dft16(d, 1.0f);
  twiddleB(d, u, IVD);
  #pragma unroll
  for (int k = 0; k < 16; ++k) X[(u*16 + k)*17 + r] = d[k];
  __syncthreads();
  #pragma unroll
  for (int m = 0; m < 16; ++m) d[m] = X[(m*16 + u)*17 + r];
  dft16(d, 1.0f);

  // ---- finU (n < NH <=> k1 < 8) + partial sum of squares ----
  float fv[8];
  float ss = 0.0f;
  #pragma unroll
  for (int k1 = 0; k1 < 8; ++k1) {
    int n = n1base + r + 256 * (u + (k1 << 4));
    float resv  = d[k1].x * S64;
    float res2v = d[k1].y * S64;
    float uu = (float)n * (1.0f / 32767.0f);
    float te = (uu - emu) / esd;
    float envv = __expf(-0.5f * te * te) * egp;
    float pnv = bf2f(fnb[(size_t)a * NH + n]) * envv;
    float pos = ((float)n + 0.5f) * (1.0f/256.0f) - 0.5f;
    pos = fminf(fmaxf(pos, 0.0f), 127.0f);
    int i0 = (int)pos;
    float w = pos - (float)i0;
    int i1 = (i0 + 1 < 127) ? i0 + 1 : 127;
    float fc = ft[i0]*(1.0f-w) + ft[i1]*w;
    float f = pnv*om0 + (fc*resv + (1.0f-fc)*res2v)*om1;
    finU[(size_t)a * NH + n] = f;
    fv[k1] = f;
    ss += f * f;
  }
  red[threadIdx.x] = ss;
  __syncthreads();           // also guarantees all X reads above are done
  for (int s = 128; s > 0; s >>= 1) {
    if (threadIdx.x < s) red[threadIdx.x] += red[threadIdx.x + s];
    __syncthreads();
  }
  if (threadIdx.x == 0) scal[SC_PSS + a*16 + blockIdx.x] = red[0];

  // ---- forward strided of padded finU (same layout) ----
  #pragma unroll
  for (int m = 0; m < 16; ++m)
    d[m] = (m < 8) ? make_float2(fv[m], 0.0f) : make_float2(0.0f, 0.0f);
  dft16(d, -1.0f);
  twiddleB(d, u, FWD);
  #pragma unroll
  for (int k = 0; k < 16; ++k) X[(u*16 + k)*17 + r] = d[k];
  __syncthreads();
  #pragma unroll
  for (int m = 0; m < 16; ++m) d[m] = X[(m*16 + u)*17 + r];
  dft16(d, -1.0f);

  #pragma unroll
  for (int k1 = 0; k1 < 16; ++k1) {
    int j = u + (k1 << 4);
    int n = n1base + r + 256 * j;
    int aa = (n1base + r) * j;
    float2 tw = cmul(T256[(aa >> 8) & 255], TN[aa & 255]);
    DsOut[(size_t)a * N + n] = pk2(cmul(d[k1], tw));
  }
}

// ---------------- final inverse strided + inline norm + dry/wet mix --------
__global__ __launch_bounds__(256) void k_fft_s256_out3(
    const unsigned* __restrict__ W64in, const float* __restrict__ finU,
    const float* __restrict__ scal, float* __restrict__ out)
{
  constexpr int N = 65536, NH = 32768;
  constexpr float IVD = +6.283185307179586f;
  constexpr float S64 = 1.0f / 65536.0f;
  __shared__ float2 X[16*16*17];
  const int a = blockIdx.y;
  const int n1base = blockIdx.x << 4;
  const int r = threadIdx.x & 15;
  const int u = threadIdx.x >> 4;

  float ss = 0.0f;
  #pragma unroll
  for (int i = 0; i < 16; ++i) ss += scal[SC_PSS + a*16 + i];
  float fscale = scal[SC_AMPS + a] / (sqrtf(ss) + 1e-8f);
  float mixv = scal[SC_MIXV + a];
  float w1 = fscale * (1.0f - mixv);
  float w0 = fscale * mixv;

  float2 d[16];
  #pragma unroll
  for (int m = 0; m < 16; ++m) {
    int j = u + (m << 4);
    d[m] = upk2(W64in[(size_t)a * N + n1base + r + 256 * j]);
  }
  dft16(d, 1.0f);
  twiddleB(d, u, IVD);
  #pragma unroll
  for (int k = 0; k < 16; ++k) X[(u*16 + k)*17 + r] = d[k];
  __syncthreads();
  #pragma unroll
  for (int m = 0; m < 16; ++m) d[m] = X[(m*16 + u)*17 + r];
  dft16(d, 1.0f);

  #pragma unroll
  for (int k1 = 0; k1 < 8; ++k1) {
    int n = n1base + r + 256 * (u + (k1 << 4));
    out[(size_t)a * NH + n] =
        d[k1].x * S64 * w1 + finU[(size_t)a * NH + n] * w0;
  }
}

// ---------------- A repack + per-atom scalars (block 0) ---------------------
__global__ void k_packA(const float* __restrict__ rc, short* __restrict__ ctb,
    const float* __restrict__ mix, const float* __restrict__ decays,
    const float* __restrict__ fdec, const float* __restrict__ nf,
    const float* __restrict__ rf1, const float* __restrict__ rf2,
    const float* __restrict__ env, const float* __restrict__ amplitudes,
    const float* __restrict__ verb, const float* __restrict__ ln_w,
    const float* __restrict__ ln_b, const float* __restrict__ mw1,
    const float* __restrict__ mw2, const float* __restrict__ rw1,
    const float* __restrict__ rw2, float* __restrict__ scal,
    float* __restrict__ dout)
{
  int o = blockIdx.x * 256 + threadIdx.x;   // o = m*4096 + k
  {
    int m = o >> 12, k = o & 4095;
    int s = k >> 2, f = k & 3;
    float v = fmaxf(rc[m*4096 + f*1024 + s], 0.0f);
    ctb[o] = f2bf(v);
  }
  if (blockIdx.x != 0 || threadIdx.x >= 64) return;
  int a = threadIdx.x;
  float m0 = mix[a*2+0], m1 = mix[a*2+1];
  float mx = fmaxf(m0, m1);
  float e0 = expf(m0 - mx), e1 = expf(m1 - mx);
  float inv = 1.0f / (e0 + e1);
  scal[SC_OM0+a] = e0 * inv;
  scal[SC_OM1+a] = e1 * inv;
  scal[SC_NFMU+a] = nf[a*2+0];
  scal[SC_NFSD+a] = fabsf(nf[a*2+1]) + 1e-12f;
  scal[SC_RF1SD+a] = fabsf(rf1[a*2+1]) + 1e-12f;
  scal[SC_RF2SD+a] = fabsf(rf2[a*2+1]) + 1e-12f;
  scal[SC_ENVMU+a] = env[a*2+0];
  scal[SC_ENVSD+a] = fabsf(env[a*2+1] + 1e-12f) * 0.1f;
  float amp = fabsf(amplitudes[a]);
  scal[SC_AMPS+a] = amp;
  dout[2097152 + a] = amp;                       // output 1: amps
  float d  = 0.02f + (1.0f/(1.0f+expf(-decays[a]))) * (0.98f * 0.95f);
  float fd = 0.02f + (1.0f/(1.0f+expf(-fdec[a])))   * (0.98f * 0.95f);
  float pd = 1.0f, pf = 1.0f;
  for (int f = 0; f < 128; ++f) {
    pd *= d; pf *= fd;
    scal[SC_DTAB + a*128 + f] = pd;
    scal[SC_FTAB + a*128 + f] = pf;
  }
  float x0 = verb[a*4+0], x1 = verb[a*4+1], x2 = verb[a*4+2], x3 = verb[a*4+3];
  float mean = (x0+x1+x2+x3) * 0.25f;
  float d0 = x0-mean, d1 = x1-mean, d2 = x2-mean, d3 = x3-mean;
  float var = (d0*d0 + d1*d1 + d2*d2 + d3*d3) * 0.25f;
  float rs = 1.0f / sqrtf(var + 1e-5f);
  float h[4] = { d0*rs*ln_w[0]+ln_b[0], d1*rs*ln_w[1]+ln_b[1],
                 d2*rs*ln_w[2]+ln_b[2], d3*rs*ln_w[3]+ln_b[3] };
  float t[4], u[4];
  for (int j = 0; j < 4; ++j) {
    float s1 = 0.f, s2 = 0.f;
    for (int i2 = 0; i2 < 4; ++i2) {
      s1 += h[i2] * mw1[i2*4 + j];
      s2 += h[i2] * rw1[i2*4 + j];
    }
    t[j] = (s1 > 0.f) ? s1 : 0.01f*s1;
    u[j] = (s2 > 0.f) ? s2 : 0.01f*s2;
  }
  float ml = 0.f;
  for (int j = 0; j < 4; ++j) ml += t[j] * mw2[j];
  scal[SC_MIXV+a] = 1.0f / (1.0f + expf(-ml));
  float best = -1e30f; int bi = 0;
  for (int rr = 0; rr < 8; ++rr) {
    float lg = 0.f;
    for (int j = 0; j < 4; ++j) lg += u[j] * rw2[j*8 + rr];
    if (lg > best) { best = lg; bi = rr; }
  }
  ((int*)scal)[SC_ROOM + a] = bi;
}

// ---------------- resonances GEMM via MFMA: LDS-free, barrier-free ---------
// grid (256, 2) x 512 threads (8 waves); K half per blockIdx.y; prefetch x4.
// [R14 configuration — R15's 256-thread split reverted]
__global__ __launch_bounds__(512) void k_gemm_mfma(
    const float* __restrict__ waves, const short* __restrict__ ctb,
    short* __restrict__ rp)
{
  const int t = threadIdx.x;
  const int w = t >> 6, lane = t & 63;
  const int ml = lane & 15, q = lane >> 4;
  const int col = blockIdx.x * 128 + w * 16 + ml;
  const int part = blockIdx.y;
  const int kb0 = part * 64;

  f32x4 acc[4] = {};

  const float* ws0 = waves + (size_t)(kb0*8 + 2*q) * 32768 + col;          // sine
  const float* ws1 = waves + (size_t)(1024 + kb0*8 + 2*q) * 32768 + col;   // saw
  const short* abase = ctb + (size_t)ml * 4096 + (size_t)kb0 * 32 + q * 8;

  #define LOADW(v, kbl) { size_t o = (size_t)(kbl) * (8*32768); \
    v[0] = ws0[o]; v[1] = ws0[o + 32768]; v[2] = ws1[o]; v[3] = ws1[o + 32768]; }

  #define DOKB(v, kbl) { \
    float sq0 = (v[0] > 0.f) ? 1.f : ((v[0] < 0.f) ? -1.f : v[0]); \
    float sq1 = (v[1] > 0.f) ? 1.f : ((v[1] < 0.f) ? -1.f : v[1]); \
    float tr0 = 2.f * fabsf(v[2]) - 1.f; \
    float tr1 = 2.f * fabsf(v[3]) - 1.f; \
    bf16x8 b; \
    b[0] = f2bf(v[0]); b[1] = f2bf(v[2]); b[2] = f2bf(sq0); b[3] = f2bf(tr0); \
    b[4] = f2bf(v[1]); b[5] = f2bf(v[3]); b[6] = f2bf(sq1); b[7] = f2bf(tr1); \
    const short* ap = abase + (size_t)(kbl) * 32; \
    acc[0] = __builtin_amdgcn_mfma_f32_16x16x32_bf16(*(const bf16x8*)(ap),                   b, acc[0], 0,0,0); \
    acc[1] = __builtin_amdgcn_mfma_f32_16x16x32_bf16(*(const bf16x8*)(ap + (size_t)16*4096), b, acc[1], 0,0,0); \
    acc[2] = __builtin_amdgcn_mfma_f32_16x16x32_bf16(*(const bf16x8*)(ap + (size_t)32*4096), b, acc[2], 0,0,0); \
    acc[3] = __builtin_amdgcn_mfma_f32_16x16x32_bf16(*(const bf16x8*)(ap + (size_t)48*4096), b, acc[3], 0,0,0); }

  float vA[4], vB[4], vC[4], vD[4];
  LOADW(vA, 0);
  LOADW(vB, 1);
  LOADW(vC, 2);
  LOADW(vD, 3);
  for (int kbl = 0; kbl < 64; kbl += 4) {
    DOKB(vA, kbl);
    if (kbl + 4 < 64) LOADW(vA, kbl + 4);
    DOKB(vB, kbl + 1);
    if (kbl + 5 < 64) LOADW(vB, kbl + 5);
    DOKB(vC, kbl + 2);
    if (kbl + 6 < 64) LOADW(vC, kbl + 6);
    DOKB(vD, kbl + 3);
    if (kbl + 7 < 64) LOADW(vD, kbl + 7);
  }
  #undef LOADW
  #undef DOKB

  #pragma unroll
  for (int mt = 0; mt < 4; ++mt) {
    #pragma unroll
    for (int rr = 0; rr < 4; ++rr) {
      rp[(size_t)(part*64 + mt*16 + q*4 + rr) * 32768 + col] = f2bf(acc[mt][rr]);
    }
  }
}

// ============================================================================
extern "C" void kernel_launch(void* const* d_in, const int* in_sizes, int n_in,
                              void* d_out, int out_size, void* d_ws, size_t ws_size,
                              hipStream_t stream)
{
  const float* mix   = (const float*)d_in[1];
  const float* dec   = (const float*)d_in[2];
  const float* fdec  = (const float*)d_in[3];
  const float* rc    = (const float*)d_in[4];
  const float* nf    = (const float*)d_in[5];
  const float* rf1   = (const float*)d_in[6];
  const float* rf2   = (const float*)d_in[7];
  const float* env   = (const float*)d_in[8];
  const float* amps  = (const float*)d_in[9];
  const float* verb  = (const float*)d_in[10];
  const float* noise = (const float*)d_in[11];
  const float* waves = (const float*)d_in[12];
  const float* lnw   = (const float*)d_in[13];
  const float* lnb   = (const float*)d_in[14];
  const float* mw1   = (const float*)d_in[15];
  const float* mw2   = (const float*)d_in[16];
  const float* rw1   = (const float*)d_in[17];
  const float* rw2   = (const float*)d_in[18];
  const float* rirs  = (const float*)d_in[19];
  float* out = (float*)d_out;
  float* w   = (float*)d_ws;

  if (ws_size < WS_FLOATS * 4ULL) return;

  float*    scal = w + OFF_SCAL;
  short*    ctb  = (short*)(w + OFF_CT);
  short*    rp   = (short*)(w + OFF_RP);     // bf16, dead before Ds
  unsigned* P    = (unsigned*)(w + OFF_P);   // bf16-packed, half-transformed
  unsigned* Ds   = (unsigned*)(w + OFF_DS);
  unsigned* W64  = (unsigned*)(w + OFF_W64);
  unsigned* RSs  = (unsigned*)(w + OFF_RSS);
  unsigned* NSs  = (unsigned*)(w + OFF_NSS); // in W64 region (early)
  unsigned* W2   = (unsigned*)(w + OFF_W2);  // in W64 region (early)
  float*    finU = w + OFF_FINU;
  unsigned* W1   = (unsigned*)(w + OFF_W1);
  short*    fnb  = (short*)(w + OFF_FN);     // fn bf16
  unsigned* FRP  = (unsigned*)(w + OFF_FRP); // fr1+i*fr2 packed
  unsigned* IRS  = (unsigned*)(w + OFF_IRS); // bf16-packed, half-transformed
  const int* room = ((const int*)(w + OFF_SCAL)) + SC_ROOM;

  // A repack + per-atom scalars (block 0)
  k_packA<<<1024, 256, 0, stream>>>(rc, ctb, mix, dec, fdec, nf, rf1, rf2, env,
                                    amps, verb, lnw, lnb, mw1, mw2, rw1, rw2,
                                    scal, out);
  k_gemm_mfma<<<dim3(256, 2), 512, 0, stream>>>(waves, ctb, rp);

  // merged RS (sum 2 bf16 GEMM partials) + NS chains: 3 dispatches
  k_fft_s128_first<<<dim3(8,128),256,0,stream>>>(RSs, NSs, rp, noise);
  k_fft_m128_both<<<dim3(16,128),256,0,stream>>>(RSs, NSs, W1, W2, scal);
  k_fft_s128_last<<<dim3(8,128),256,0,stream>>>(W1, W2, FRP, fnb);

  // merged Ds + P + IRS forward strided (all half-transformed, bf16)
  k_fft_s256_DsPI<<<dim3(16,136),256,0,stream>>>(Ds, P, IRS, FRP, fnb, rirs, scal);

  // conv mid: fft(Ds)*fft(P) -> inverse-contig -> W64
  k_fft_mid256dual<<<dim3(16,64),256,0,stream>>>(Ds, P, W64, nullptr);

  // FUSED: conv inverse -> finU + SS partials -> reverb forward -> Ds
  k_fft_out6fwd<<<dim3(16,64),256,0,stream>>>(W64, fnb, finU, scal, Ds);

  // reverb mid: fft(Ds half) * fft(IRS half[room]) -> inverse-contig -> W64
  // *** NO contig FFT between strided and mid (round-2 bug) ***
  k_fft_mid256dual<<<dim3(16,64),256,0,stream>>>(Ds, IRS, W64, room);

  // final inverse + inline norm (from PSS partials) + dry/wet mix
  k_fft_s256_out3<<<dim3(16,64),256,0,stream>>>(W64, finU, scal, out);
}

// Round 17
// 268.444 us; speedup vs baseline: 1.1188x; 1.0834x over previous
//
#include <hip/hip_runtime.h>

// ============================================================================
// Model_22016002360008 — synth forward pass.
//  GEMM: bf16 MFMA 16x16x32, FULLY ANALYTIC B (no waves read): rps table
//    (bit-exact fp32 replication of numpy) -> rad = rps*col (exact) ->
//    saw/tri via IEEE fp32 div+floor (op-for-op numpy), sq from DOUBLE
//    fractional phase (sign exact to ~1e-11), sine via __sinf (bf16 absorbs).
//    512-thr blocks, grid (256,2), K split x2 (partials summed in RS load).
//  FFT: complex four-step, N = N1*256, digit-permuted spectrum
//       addr = k2*N1 + k1, true bin k = k2 + 256*k1.
//  ALL complex spectra + GEMM partials stored PACKED BF16; fr1/fr2 packed as
//  one uint (FRP), fn bf16; finU fp32. FFT arithmetic fp32 in regs/LDS.
//  Length-256 transforms: REGISTER 16x16 FFT. 32K mid: radix-4 LDS Stockham.
//  Fusions: scalars+rps folded into packA; conv-inverse+finU+SS+reverb-fwd in
//  one kernel; fscale deferred to final pass; Ds+P+IRS forwards one dispatch.
//  !! mid's input must be STRIDED-ONLY (half-transformed) data — never run
//  !! a contig FFT before a mid kernel (round-2 bug, reverb path).
// ============================================================================

typedef __attribute__((ext_vector_type(8))) short bf16x8;
typedef __attribute__((ext_vector_type(4))) float f32x4;

constexpr int SC_OM0   = 0;
constexpr int SC_OM1   = 64;
constexpr int SC_NFMU  = 128;
constexpr int SC_NFSD  = 192;
constexpr int SC_RF1SD = 256;
constexpr int SC_RF2SD = 320;
constexpr int SC_ENVMU = 384;
constexpr int SC_ENVSD = 448;
constexpr int SC_AMPS  = 512;
constexpr int SC_MIXV  = 576;
constexpr int SC_ROOM  = 832;
constexpr int SC_PSS   = 1024;   // 64 x 16 partial sum-of-squares
constexpr int SC_DTAB  = 4096;
constexpr int SC_FTAB  = 12288;
constexpr int SC_RPS   = 20480;  // 1024-entry fp32 rps table

// ---------------- workspace layout (float offsets; bf16 buffers use less) ---
constexpr size_t OFF_SCAL = 0;
constexpr size_t OFF_CT   = 65536;
constexpr size_t OFF_P    = 327680;       // P half-transformed (bf16 packed)
constexpr size_t OFF_DS   = 8716288;      // Ds (bf16); rp (bf16) aliases
constexpr size_t OFF_RP   = OFF_DS;
constexpr size_t OFF_W64  = 17104896;     // conv/rev work; early: NSs + W2
constexpr size_t OFF_NSS  = OFF_W64;
constexpr size_t OFF_W2   = OFF_W64 + 4194304;
constexpr size_t OFF_RSS  = 25493504;     // RSs -> finU
constexpr size_t OFF_FINU = OFF_RSS;
constexpr size_t OFF_W1   = 29687808;
constexpr size_t OFF_FN   = 38076416;     // fn bf16 (shorts)
constexpr size_t OFF_FRP  = 40173568;     // fr1+i*fr2 packed (uints)
constexpr size_t OFF_IRS  = 44367872;
constexpr size_t WS_FLOATS= 45416448;

__device__ __forceinline__ float2 cmul(float2 a, float2 b) {
  return make_float2(a.x*b.x - a.y*b.y, a.x*b.y + a.y*b.x);
}

__device__ __forceinline__ short f2bf(float x) {
  unsigned u = __float_as_uint(x);
  u = (u + 0x7FFFu + ((u >> 16) & 1u)) >> 16;
  return (short)u;
}
__device__ __forceinline__ float bf2f(short s) {
  return __uint_as_float((unsigned)(unsigned short)s << 16);
}
__device__ __forceinline__ unsigned pk2(float2 v) {
  return (unsigned)(unsigned short)f2bf(v.x)
       | ((unsigned)(unsigned short)f2bf(v.y) << 16);
}
__device__ __forceinline__ float2 upk2(unsigned u) {
  return make_float2(__uint_as_float(u << 16),
                     __uint_as_float(u & 0xFFFF0000u));
}

// ---------------- 16-point DFT in registers (natural order in/out) ---------
__device__ __forceinline__ void dft16(float2 d[16], float ei)
{
  const float CA[4] = {1.0f, 0.92387953251128674f, 0.70710678118654752f, 0.38268343236508977f};
  const float SA[4] = {0.0f, 0.38268343236508977f, 0.70710678118654752f, 0.92387953251128674f};
  const float CB[4] = {1.0f, 0.70710678118654752f, 0.0f, -0.70710678118654752f};
  const float SB[4] = {0.0f, 0.70710678118654752f, 1.0f, 0.70710678118654752f};
  float2 e[16];
  #pragma unroll
  for (int q = 0; q < 4; ++q) {
    float2 x0 = d[q], x1 = d[q+4], x2 = d[q+8], x3 = d[q+12];
    float ca = CA[q], sa = ei*SA[q], cb = CB[q], sb = ei*SB[q];
    float2 sum1 = make_float2(x0.x+x2.x, x0.y+x2.y);
    float2 d1   = make_float2(x0.x-x2.x, x0.y-x2.y);
    float2 dif1 = make_float2(d1.x*ca - d1.y*sa, d1.x*sa + d1.y*ca);
    float2 sum2 = make_float2(x1.x+x3.x, x1.y+x3.y);
    float2 d2   = make_float2(x1.x-x3.x, x1.y-x3.y);
    float2 dt   = make_float2(d2.x*ca - d2.y*sa, d2.x*sa + d2.y*ca);
    float2 dif2 = make_float2(-ei*dt.y, ei*dt.x);
    float2 Dm   = make_float2(sum1.x-sum2.x, sum1.y-sum2.y);
    float2 Dm2  = make_float2(dif1.x-dif2.x, dif1.y-dif2.y);
    e[4*q+0] = make_float2(sum1.x+sum2.x, sum1.y+sum2.y);
    e[4*q+1] = make_float2(dif1.x+dif2.x, dif1.y+dif2.y);
    e[4*q+2] = make_float2(Dm.x*cb - Dm.y*sb, Dm.x*sb + Dm.y*cb);
    e[4*q+3] = make_float2(Dm2.x*cb - Dm2.y*sb, Dm2.x*sb + Dm2.y*cb);
  }
  #pragma unroll
  for (int q = 0; q < 4; ++q) {
    float2 x0 = e[q], x1 = e[q+4], x2 = e[q+8], x3 = e[q+12];
    float2 sum1 = make_float2(x0.x+x2.x, x0.y+x2.y);
    float2 dif1 = make_float2(x0.x-x2.x, x0.y-x2.y);
    float2 sum2 = make_float2(x1.x+x3.x, x1.y+x3.y);
    float2 d2   = make_float2(x1.x-x3.x, x1.y-x3.y);
    float2 dif2 = make_float2(-ei*d2.y, ei*d2.x);
    d[q]    = make_float2(sum1.x+sum2.x, sum1.y+sum2.y);
    d[q+4]  = make_float2(dif1.x+dif2.x, dif1.y+dif2.y);
    d[q+8]  = make_float2(sum1.x-sum2.x, sum1.y-sum2.y);
    d[q+12] = make_float2(dif1.x-dif2.x, dif1.y-dif2.y);
  }
}

__device__ __forceinline__ void twiddleB(float2 d[16], int u, float dir2pi)
{
  float sn1, cs1;
  __sincosf(dir2pi * ((float)u * (1.0f/256.0f)), &sn1, &cs1);
  float2 w1 = make_float2(cs1, sn1);
  float2 tw = w1;
  #pragma unroll
  for (int k = 1; k < 16; ++k) { d[k] = cmul(d[k], tw); tw = cmul(tw, w1); }
}

// ---------------- in-LDS RADIX-4 Stockham (LEN=128, 32K mid only) ----------
template<int LEN>
__device__ float2* lds_fft(float2* src, float2* dst,
                           const float2* __restrict__ T256,
                           float dsign, float ei)
{
  constexpr int QB  = LEN >> 2;
  constexpr int FPT = (16 * QB) >> 8;
  constexpr int NST = (LEN == 256) ? 4 : 3;
  int n = LEN, s = 1, ls = 0;
  int sh = (LEN == 256) ? 0 : 1;

  if (LEN == 128) {
    constexpr int HB = LEN >> 1;
    constexpr int BPT = (16 * HB) >> 8;
    __syncthreads();
    #pragma unroll
    for (int b = 0; b < BPT; ++b) {
      int g = threadIdx.x + (b << 8);
      int row = g / HB;
      int beta = g & (HB - 1);
      float2 tj = T256[beta << 1];
      float cs = tj.x, sn = dsign * tj.y;
      float2 av = src[row*LEN + (beta ^ row)];
      float2 bv = src[row*LEN + ((beta + HB) ^ row)];
      float2 sum = make_float2(av.x + bv.x, av.y + bv.y);
      float2 dif = make_float2(av.x - bv.x, av.y - bv.y);
      float2 tw  = make_float2(dif.x*cs - dif.y*sn, dif.x*sn + dif.y*cs);
      dst[row*LEN + ((2*beta)     ^ row)] = sum;
      dst[row*LEN + ((2*beta + 1) ^ row)] = tw;
    }
    float2* t = src; src = dst; dst = t;
    n = 64; s = 2; ls = 1; sh = 2;
  }

  for (int st = 0; st < NST; ++st) {
    __syncthreads();
    #pragma unroll
    for (int b = 0; b < FPT; ++b) {
      int g   = threadIdx.x + (b << 8);
      int row = g / QB;
      int q   = g & (QB - 1);
      int p1  = q >> ls;
      int blo = q & (s - 1);
      int base = row * LEN;
      float2 x0 = src[base + ( q         ^ row)];
      float2 x1 = src[base + ((q +   QB) ^ row)];
      float2 x2 = src[base + ((q + 2*QB) ^ row)];
      float2 x3 = src[base + ((q + 3*QB) ^ row)];
      float2 tA = T256[p1 << sh];
      float caA = tA.x, saA = dsign * tA.y;
      float2 tB = T256[p1 << (sh + 1)];
      float caB = tB.x, saB = dsign * tB.y;
      float2 sum1 = make_float2(x0.x + x2.x, x0.y + x2.y);
      float2 d1   = make_float2(x0.x - x2.x, x0.y - x2.y);
      float2 dif1 = make_float2(d1.x*caA - d1.y*saA, d1.x*saA + d1.y*caA);
      float2 sum2 = make_float2(x1.x + x3.x, x1.y + x3.y);
      float2 d2   = make_float2(x1.x - x3.x, x1.y - x3.y);
      float2 dt   = make_float2(d2.x*caA - d2.y*saA, d2.x*saA + d2.y*caA);
      float2 dif2 = make_float2(-ei * dt.y, ei * dt.x);
      float2 S  = make_float2(sum1.x + sum2.x, sum1.y + sum2.y);
      float2 Dm = make_float2(sum1.x - sum2.x, sum1.y - sum2.y);
      float2 D  = make_float2(Dm.x*caB - Dm.y*saB, Dm.x*saB + Dm.y*caB);
      float2 S2 = make_float2(dif1.x + dif2.x, dif1.y + dif2.y);
      float2 Dm2= make_float2(dif1.x - dif2.x, dif1.y - dif2.y);
      float2 D2 = make_float2(Dm2.x*caB - Dm2.y*saB, Dm2.x*saB + Dm2.y*caB);
      int w0 = (p1 << (ls + 2)) | blo;
      dst[base + ( w0          ^ row)] = S;
      dst[base + ((w0 +     s) ^ row)] = S2;
      dst[base + ((w0 + 2 * s) ^ row)] = D;
      dst[base + ((w0 + 3 * s) ^ row)] = D2;
    }
    float2* t = src; src = dst; dst = t;
    n >>= 2; s <<= 2; ls += 2; sh += 2;
  }
  __syncthreads();
  return src;
}

// ---------------- merged Ds + P + IRS forward strided (64K) ----------------
__global__ __launch_bounds__(256) void k_fft_s256_DsPI(
    unsigned* __restrict__ Ds, unsigned* __restrict__ P,
    unsigned* __restrict__ IRS,
    const unsigned* __restrict__ FRP, const short* __restrict__ fnb,
    const float* __restrict__ rirs, const float* __restrict__ scal)
{
  constexpr int N = 65536, NH = 32768;
  constexpr float FWD = -6.283185307179586f;
  __shared__ float2 X[16*16*17];
  __shared__ float2 T256[256];
  __shared__ float2 TN[256];
  const int mode = (blockIdx.y < 64) ? 0 : ((blockIdx.y < 128) ? 1 : 2);
  const int a = (mode == 0) ? blockIdx.y : ((mode == 1) ? blockIdx.y - 64 : blockIdx.y - 128);
  const int n1base = blockIdx.x << 4;
  const int r = threadIdx.x & 15;
  const int u = threadIdx.x >> 4;

  {
    float ang = FWD * ((float)threadIdx.x * (1.0f/256.0f));
    float sn, cs; __sincosf(ang, &sn, &cs);
    T256[threadIdx.x] = make_float2(cs, sn);
    float ang2 = FWD * ((float)threadIdx.x * (1.0f/(float)N));
    float sn2, cs2; __sincosf(ang2, &sn2, &cs2);
    TN[threadIdx.x] = make_float2(cs2, sn2);
  }

  float emu = 0.f, esd = 1.f, egp = 0.f;
  if (mode == 1) {
    emu = scal[SC_ENVMU + a];
    esd = scal[SC_ENVSD + a];
    egp = 0.3989422804014327f / esd;
  }

  float2 d[16];
  #pragma unroll
  for (int m = 0; m < 16; ++m) {
    int j = u + (m << 4);
    int n = n1base + r + 256 * j;
    float2 v = make_float2(0.0f, 0.0f);
    if (n < NH) {
      if (mode == 0) {
        float pos = ((float)n + 0.5f) * (1.0f/256.0f) - 0.5f;
        pos = fminf(fmaxf(pos, 0.0f), 127.0f);
        int i0 = (int)pos;
        float w = pos - (float)i0;
        int i1 = (i0 + 1 < 127) ? i0 + 1 : 127;
        const float* dt = scal + SC_DTAB + a*128;
        float de = dt[i0]*(1.0f-w) + dt[i1]*w;
        float2 fr = upk2(FRP[(size_t)a * NH + n]);
        v = make_float2(fr.x * de, fr.y * de);
      } else if (mode == 1) {
        float uu = (float)n * (1.0f / 32767.0f);
        float te = (uu - emu) / esd;
        float envv = __expf(-0.5f * te * te) * egp;
        v = make_float2(bf2f(fnb[(size_t)a * NH + n]) * envv, 0.0f);
      } else {
        v = make_float2(rirs[(size_t)a * NH + n], 0.0f);
      }
    }
    d[m] = v;
  }

  dft16(d, -1.0f);
  twiddleB(d, u, FWD);
  #pragma unroll
  for (int k = 0; k < 16; ++k) X[(u*16 + k)*17 + r] = d[k];
  __syncthreads();
  #pragma unroll
  for (int m = 0; m < 16; ++m) d[m] = X[(m*16 + u)*17 + r];
  dft16(d, -1.0f);

  unsigned* outp = (mode == 0) ? Ds : ((mode == 1) ? P : IRS);
  #pragma unroll
  for (int k1 = 0; k1 < 16; ++k1) {
    int j = u + (k1 << 4);
    int n = n1base + r + 256 * j;
    int aa = (n1base + r) * j;
    float2 tw = cmul(T256[(aa >> 8) & 255], TN[aa & 255]);
    outp[(size_t)a * N + n] = pk2(cmul(d[k1], tw));
  }
}

// ---------------- merged first strided (32K): RS (y<64) + NS (y>=64) -------
__global__ __launch_bounds__(256) void k_fft_s128_first(
    unsigned* __restrict__ RSs, unsigned* __restrict__ NSs,
    const short* __restrict__ rez, const float* __restrict__ noise)
{
  constexpr int N1 = 128, N = 32768;
  constexpr float FWD = -6.283185307179586f;
  __shared__ float2 X[16*16*17];
  __shared__ float2 T256[256];
  __shared__ float2 TN[128];
  const bool isRS = blockIdx.y < 64;
  const int a = isRS ? blockIdx.y : blockIdx.y - 64;
  const int n1base = blockIdx.x << 4;
  const int r = threadIdx.x & 15;
  const int u = threadIdx.x >> 4;

  {
    float ang = FWD * ((float)threadIdx.x * (1.0f/256.0f));
    float sn, cs; __sincosf(ang, &sn, &cs);
    T256[threadIdx.x] = make_float2(cs, sn);
    if (threadIdx.x < 128) {
      float ang2 = FWD * ((float)threadIdx.x * (1.0f/(float)N));
      float sn2, cs2; __sincosf(ang2, &sn2, &cs2);
      TN[threadIdx.x] = make_float2(cs2, sn2);
    }
  }

  float2 d[16];
  #pragma unroll
  for (int m = 0; m < 16; ++m) {
    int j = u + (m << 4);
    int n = n1base + r + N1 * j;
    float x = isRS ? (bf2f(rez[(size_t)a * N + n]) +
                      bf2f(rez[(size_t)(64 + a) * N + n]))
                   : noise[(size_t)a * N + n];
    d[m] = make_float2(x, 0.0f);
  }

  dft16(d, -1.0f);
  twiddleB(d, u, FWD);
  #pragma unroll
  for (int k = 0; k < 16; ++k) X[(u*16 + k)*17 + r] = d[k];
  __syncthreads();
  #pragma unroll
  for (int m = 0; m < 16; ++m) d[m] = X[(m*16 + u)*17 + r];
  dft16(d, -1.0f);

  unsigned* outp = isRS ? RSs : NSs;
  #pragma unroll
  for (int k1 = 0; k1 < 16; ++k1) {
    int j = u + (k1 << 4);
    int n = n1base + r + N1 * j;
    int aa = (n1base + r) * j;
    float2 tw = cmul(T256[(aa >> 7) & 255], TN[aa & 127]);
    outp[(size_t)a * N + n] = pk2(cmul(d[k1], tw));
  }
}

// ---------------- merged 32K mid: RS complex filter (y<64) / NS gauss ------
__global__ __launch_bounds__(256) void k_fft_m128_both(
    const unsigned* __restrict__ RSs, const unsigned* __restrict__ NSs,
    unsigned* __restrict__ W1, unsigned* __restrict__ W2,
    const float* __restrict__ scal)
{
  constexpr int N1 = 128;
  constexpr int N = N1 * 256;
  constexpr int ITERS = (16 * N1) >> 8;
  constexpr int LOG2N1 = 7;
  constexpr float FWD = -6.283185307179586f;
  constexpr float IVD = +6.283185307179586f;
  __shared__ float2 A[16 * N1];
  __shared__ float2 B[16 * N1];
  __shared__ float2 T256[256];
  __shared__ float2 TN[N1];
  const bool isRS = blockIdx.y < 64;
  const int a = isRS ? blockIdx.y : blockIdx.y - 64;
  const int colbase = blockIdx.x << 4;

  {
    float ang = FWD * ((float)threadIdx.x * (1.0f/256.0f));
    float sn, cs; __sincosf(ang, &sn, &cs);
    T256[threadIdx.x] = make_float2(cs, sn);
    if (threadIdx.x < N1) {
      float ang2 = IVD * ((float)threadIdx.x * (1.0f/(float)N));
      float sn2, cs2; __sincosf(ang2, &sn2, &cs2);
      TN[threadIdx.x] = make_float2(cs2, sn2);
    }
  }

  float mu = 0.f, isd1 = 0.f, g1 = 0.f, isd2 = 0.f, g2 = 0.f;
  if (isRS) {
    float s1 = scal[SC_RF1SD + a], s2 = scal[SC_RF2SD + a];
    isd1 = 1.0f/s1; g1 = 0.3989422804014327f/s1;
    isd2 = 1.0f/s2; g2 = 0.3989422804014327f/s2;
  } else {
    float sd = scal[SC_NFSD + a]; mu = scal[SC_NFMU + a];
    isd1 = 1.0f/sd; g1 = 0.3989422804014327f/sd;
  }
  const unsigned* zin = (isRS ? RSs : NSs) + (size_t)a * N;
  unsigned* out = (isRS ? W1 : W2) + (size_t)a * N;

  #pragma unroll
  for (int it = 0; it < ITERS; ++it) {
    int flat = threadIdx.x + (it << 8);
    int c = flat / N1, j = flat & (N1 - 1);
    A[c*N1 + (j ^ c)] = upk2(zin[(size_t)(colbase + c) * N1 + j]);
  }
  float2* cur = lds_fft<N1>(A, B, T256, 1.0f, -1.0f);
  float2* alt = (cur == A) ? B : A;

  #pragma unroll
  for (int it = 0; it < ITERS; ++it) {
    int flat = threadIdx.x + (it << 8);
    int c = flat / N1, j = flat & (N1 - 1);
    int idx = c*N1 + (j ^ c);
    float2 v = cur[idx];
    int k  = (colbase + c) + (j << 8);          // true bin
    int kk = (k <= N - k) ? k : N - k;          // hermitian mirror
    if (isRS) {
      float fr = (float)kk * (2.0f/(float)N);
      float t1 = fr * isd1, t2 = fr * isd2;
      float ga = __expf(-0.5f * t1 * t1) * g1;   // G1 (real)
      float gb = __expf(-0.5f * t2 * t2) * g2;   // G2 (imag)
      v = make_float2(v.x*ga - v.y*gb, v.x*gb + v.y*ga);
    } else {
      float t = ((float)kk * (2.0f/(float)N) - mu) * isd1;
      float g = __expf(-0.5f * t * t) * g1;
      v.x *= g; v.y *= g;
    }
    cur[idx] = v;
  }

  float2* r2 = lds_fft<N1>(cur, alt, T256, -1.0f, 1.0f);

  #pragma unroll
  for (int it = 0; it < ITERS; ++it) {
    int flat = threadIdx.x + (it << 8);
    int c = flat / N1, j = flat & (N1 - 1);
    float2 v = r2[c*N1 + (j ^ c)];
    int aa = j * (colbase + c);
    float2 t1 = T256[(aa >> LOG2N1) & 255];
    t1.y = -t1.y;
    float2 tw = cmul(t1, TN[aa & (N1 - 1)]);
    out[(size_t)(colbase + c) * N1 + j] = pk2(cmul(v, tw));
  }
}

// ---------------- merged final strided (32K inverse) -----------------------
__global__ __launch_bounds__(256) void k_fft_s128_last(
    const unsigned* __restrict__ W1, const unsigned* __restrict__ W2,
    unsigned* __restrict__ FRP, short* __restrict__ fnb)
{
  constexpr int N1 = 128, N = 32768;
  constexpr float IVD = +6.283185307179586f;
  constexpr float S32 = 1.0f / 32768.0f;
  __shared__ float2 X[16*16*17];
  const bool isRS = blockIdx.y < 64;
  const int a = isRS ? blockIdx.y : blockIdx.y - 64;
  const int n1base = blockIdx.x << 4;
  const int r = threadIdx.x & 15;
  const int u = threadIdx.x >> 4;

  const unsigned* cb = (isRS ? W1 : W2) + (size_t)a * N;
  float2 d[16];
  #pragma unroll
  for (int m = 0; m < 16; ++m) {
    int j = u + (m << 4);
    d[m] = upk2(cb[n1base + r + N1 * j]);
  }
  dft16(d, 1.0f);
  twiddleB(d, u, IVD);
  #pragma unroll
  for (int k = 0; k < 16; ++k) X[(u*16 + k)*17 + r] = d[k];
  __syncthreads();
  #pragma unroll
  for (int m = 0; m < 16; ++m) d[m] = X[(m*16 + u)*17 + r];
  dft16(d, 1.0f);

  #pragma unroll
  for (int k1 = 0; k1 < 16; ++k1) {
    int j = u + (k1 << 4);
    int n = n1base + r + N1 * j;
    if (isRS) {
      FRP[(size_t)a * N + n] = pk2(make_float2(d[k1].x * S32, d[k1].y * S32));
    } else {
      fnb[(size_t)a * N + n] = f2bf(d[k1].x * S32);
    }
  }
}

// ---------------- fused middle, 64K (register FFT, dual-operand) -----------
__global__ __launch_bounds__(256) void k_fft_mid256dual(
    const unsigned* __restrict__ zin, const unsigned* __restrict__ zin2half,
    unsigned* __restrict__ out1, const int* __restrict__ roomArr)
{
  constexpr int N = 65536;
  constexpr float FWD = -6.283185307179586f;
  constexpr float IVD = +6.283185307179586f;
  __shared__ float2 X[16*16*17];
  __shared__ float2 T256[256];
  __shared__ float2 TN[256];
  const int a = blockIdx.y;
  const int colbase = blockIdx.x << 4;
  const int u  = threadIdx.x & 15;
  const int rc = threadIdx.x >> 4;

  {
    float ang = FWD * ((float)threadIdx.x * (1.0f/256.0f));
    float sn, cs; __sincosf(ang, &sn, &cs);
    T256[threadIdx.x] = make_float2(cs, sn);
    float ang2 = IVD * ((float)threadIdx.x * (1.0f/(float)N));
    float sn2, cs2; __sincosf(ang2, &sn2, &cs2);
    TN[threadIdx.x] = make_float2(cs2, sn2);
  }
  __syncthreads();

  const unsigned* z2 = zin2half + (size_t)(roomArr ? roomArr[a] : a) * N;
  const size_t rowG = (size_t)a * N + (size_t)(colbase + rc) * 256;
  const size_t rowZ2 = (size_t)(colbase + rc) * 256;

  float2 d[16];
  #pragma unroll
  for (int m = 0; m < 16; ++m) d[m] = upk2(zin[rowG + u + (m << 4)]);
  dft16(d, -1.0f);
  twiddleB(d, u, FWD);
  #pragma unroll
  for (int k = 0; k < 16; ++k) X[(rc*16 + k)*17 + u] = d[k];
  #pragma unroll
  for (int m = 0; m < 16; ++m) d[m] = X[(rc*16 + u)*17 + m];
  dft16(d, -1.0f);

  float2 stash[16];
  #pragma unroll
  for (int k = 0; k < 16; ++k) stash[k] = d[k];
  #pragma unroll
  for (int m = 0; m < 16; ++m) d[m] = upk2(z2[rowZ2 + u + (m << 4)]);
  dft16(d, -1.0f);
  twiddleB(d, u, FWD);
  #pragma unroll
  for (int k = 0; k < 16; ++k) X[(rc*16 + k)*17 + u] = d[k];
  #pragma unroll
  for (int m = 0; m < 16; ++m) d[m] = X[(rc*16 + u)*17 + m];
  dft16(d, -1.0f);
  #pragma unroll
  for (int k = 0; k < 16; ++k) d[k] = cmul(stash[k], d[k]);

  dft16(d, 1.0f);
  twiddleB(d, u, IVD);
  #pragma unroll
  for (int k = 0; k < 16; ++k) X[(rc*16 + k)*17 + u] = d[k];
  #pragma unroll
  for (int m = 0; m < 16; ++m) d[m] = X[(rc*16 + u)*17 + m];
  dft16(d, 1.0f);

  #pragma unroll
  for (int k1 = 0; k1 < 16; ++k1) {
    int j = u + (k1 << 4);
    int aa = j * (colbase + rc);
    float2 t1 = T256[(aa >> 8) & 255];
    t1.y = -t1.y;
    float2 tw = cmul(t1, TN[aa & 255]);
    out1[rowG + j] = pk2(cmul(d[k1], tw));
  }
}

// ---------------- FUSED: conv inverse -> finU + SS -> reverb forward -------
__global__ __launch_bounds__(256) void k_fft_out6fwd(
    const unsigned* __restrict__ W64in, const short* __restrict__ fnb,
    float* __restrict__ finU, float* __restrict__ scal,
    unsigned* __restrict__ DsOut)
{
  constexpr int N = 65536, NH = 32768;
  constexpr float FWD = -6.283185307179586f;
  constexpr float IVD = +6.283185307179586f;
  constexpr float S64 = 1.0f / 65536.0f;
  __shared__ float2 X[16*16*17];
  __shared__ float2 T256[256];   // FWD (for output twiddle)
  __shared__ float2 TN[256];     // FWD
  __shared__ float red[256];
  const int a = blockIdx.y;
  const int n1base = blockIdx.x << 4;
  const int r = threadIdx.x & 15;
  const int u = threadIdx.x >> 4;

  {
    float ang = FWD * ((float)threadIdx.x * (1.0f/256.0f));
    float sn, cs; __sincosf(ang, &sn, &cs);
    T256[threadIdx.x] = make_float2(cs, sn);
    float ang2 = FWD * ((float)threadIdx.x * (1.0f/(float)N));
    float sn2, cs2; __sincosf(ang2, &sn2, &cs2);
    TN[threadIdx.x] = make_float2(cs2, sn2);
  }

  const float emu = scal[SC_ENVMU + a];
  const float esd = scal[SC_ENVSD + a];
  const float egp = 0.3989422804014327f / esd;
  const float om0 = scal[SC_OM0 + a], om1 = scal[SC_OM1 + a];
  const float* ft = scal + SC_FTAB + a*128;

  // ---- inverse strided of conv spectrum ----
  float2 d[16];
  #pragma unroll
  for (int m = 0; m < 16; ++m) {
    int j = u + (m << 4);
    d[m] = upk2(W64in[(size_t)a * N + n1base + r + 256 * j]);
  }
  dft16(d, 1.0f);
  twiddleB(d, u, IVD);
  #pragma unroll
  for (int k = 0; k < 16; ++k) X[(u*16 + k)*17 + r] = d[k];
  __syncthreads();
  #pragma unroll
  for (int m = 0; m < 16; ++m) d[m] = X[(m*16 + u)*17 + r];
  dft16(d, 1.0f);

  // ---- finU (n < NH <=> k1 < 8) + partial sum of squares ----
  float fv[8];
  float ss = 0.0f;
  #pragma unroll
  for (int k1 = 0; k1 < 8; ++k1) {
    int n = n1base + r + 256 * (u + (k1 << 4));
    float resv  = d[k1].x * S64;
    float res2v = d[k1].y * S64;
    float uu = (float)n * (1.0f / 32767.0f);
    float te = (uu - emu) / esd;
    float envv = __expf(-0.5f * te * te) * egp;
    float pnv = bf2f(fnb[(size_t)a * NH + n]) * envv;
    float pos = ((float)n + 0.5f) * (1.0f/256.0f) - 0.5f;
    pos = fminf(fmaxf(pos, 0.0f), 127.0f);
    int i0 = (int)pos;
    float w = pos - (float)i0;
    int i1 = (i0 + 1 < 127) ? i0 + 1 : 127;
    float fc = ft[i0]*(1.0f-w) + ft[i1]*w;
    float f = pnv*om0 + (fc*resv + (1.0f-fc)*res2v)*om1;
    finU[(size_t)a * NH + n] = f;
    fv[k1] = f;
    ss += f * f;
  }
  red[threadIdx.x] = ss;
  __syncthreads();           // also guarantees all X reads above are done
  for (int s = 128; s > 0; s >>= 1) {
    if (threadIdx.x < s) red[threadIdx.x] += red[threadIdx.x + s];
    __syncthreads();
  }
  if (threadIdx.x == 0) scal[SC_PSS + a*16 + blockIdx.x] = red[0];

  // ---- forward strided of padded finU (same layout) ----
  #pragma unroll
  for (int m = 0; m < 16; ++m)
    d[m] = (m < 8) ? make_float2(fv[m], 0.0f) : make_float2(0.0f, 0.0f);
  dft16(d, -1.0f);
  twiddleB(d, u, FWD);
  #pragma unroll
  for (int k = 0; k < 16; ++k) X[(u*16 + k)*17 + r] = d[k];
  __syncthreads();
  #pragma unroll
  for (int m = 0; m < 16; ++m) d[m] = X[(m*16 + u)*17 + r];
  dft16(d, -1.0f);

  #pragma unroll
  for (int k1 = 0; k1 < 16; ++k1) {
    int j = u + (k1 << 4);
    int n = n1base + r + 256 * j;
    int aa = (n1base + r) * j;
    float2 tw = cmul(T256[(aa >> 8) & 255], TN[aa & 255]);
    DsOut[(size_t)a * N + n] = pk2(cmul(d[k1], tw));
  }
}

// ---------------- final inverse strided + inline norm + dry/wet mix --------
__global__ __launch_bounds__(256) void k_fft_s256_out3(
    const unsigned* __restrict__ W64in, const float* __restrict__ finU,
    const float* __restrict__ scal, float* __restrict__ out)
{
  constexpr int N = 65536, NH = 32768;
  constexpr float IVD = +6.283185307179586f;
  constexpr float S64 = 1.0f / 65536.0f;
  __shared__ float2 X[16*16*17];
  const int a = blockIdx.y;
  const int n1base = blockIdx.x << 4;
  const int r = threadIdx.x & 15;
  const int u = threadIdx.x >> 4;

  float ss = 0.0f;
  #pragma unroll
  for (int i = 0; i < 16; ++i) ss += scal[SC_PSS + a*16 + i];
  float fscale = scal[SC_AMPS + a] / (sqrtf(ss) + 1e-8f);
  float mixv = scal[SC_MIXV + a];
  float w1 = fscale * (1.0f - mixv);
  float w0 = fscale * mixv;

  float2 d[16];
  #pragma unroll
  for (int m = 0; m < 16; ++m) {
    int j = u + (m << 4);
    d[m] = upk2(W64in[(size_t)a * N + n1base + r + 256 * j]);
  }
  dft16(d, 1.0f);
  twiddleB(d, u, IVD);
  #pragma unroll
  for (int k = 0; k < 16; ++k) X[(u*16 + k)*17 + r] = d[k];
  __syncthreads();
  #pragma unroll
  for (int m = 0; m < 16; ++m) d[m] = X[(m*16 + u)*17 + r];
  dft16(d, 1.0f);

  #pragma unroll
  for (int k1 = 0; k1 < 8; ++k1) {
    int n = n1base + r + 256 * (u + (k1 << 4));
    out[(size_t)a * NH + n] =
        d[k1].x * S64 * w1 + finU[(size_t)a * NH + n] * w0;
  }
}

// ---------------- A repack + per-atom scalars + rps table -------------------
// blocks 0..3: rps[idx] (bit-exact fp32 replication of numpy make_waves);
// block 0 lanes<64: per-atom scalars/MLPs/tables.
__global__ void k_packA(const float* __restrict__ rc, short* __restrict__ ctb,
    const float* __restrict__ mix, const float* __restrict__ decays,
    const float* __restrict__ fdec, const float* __restrict__ nf,
    const float* __restrict__ rf1, const float* __restrict__ rf2,
    const float* __restrict__ env, const float* __restrict__ amplitudes,
    const float* __restrict__ verb, const float* __restrict__ ln_w,
    const float* __restrict__ ln_b, const float* __restrict__ mw1,
    const float* __restrict__ mw2, const float* __restrict__ rw1,
    const float* __restrict__ rw2, float* __restrict__ scal,
    float* __restrict__ dout)
{
  int o = blockIdx.x * 256 + threadIdx.x;   // o = m*4096 + k
  {
    int m = o >> 12, k = o & 4095;
    int s = k >> 2, f = k & 3;
    float v = fmaxf(rc[m*4096 + f*1024 + s], 0.0f);
    ctb[o] = f2bf(v);
  }
  if (blockIdx.x < 4) {
    int idx = blockIdx.x * 256 + threadIdx.x;   // 0..1023
    // numpy linspace: step = 85/1023; midi = i*step + 21; midi[1023] = 106
    double step = 85.0 / 1023.0;
    double midi = (double)idx * step + 21.0;
    if (idx == 1023) midi = 106.0;
    double f0 = 440.0 * exp2((midi - 69.0) * (1.0 / 12.0));
    scal[SC_RPS + idx] = (float)((f0 / 11025.0) * 3.141592653589793);
  }
  if (blockIdx.x != 0 || threadIdx.x >= 64) return;
  int a = threadIdx.x;
  float m0 = mix[a*2+0], m1 = mix[a*2+1];
  float mx = fmaxf(m0, m1);
  float e0 = expf(m0 - mx), e1 = expf(m1 - mx);
  float inv = 1.0f / (e0 + e1);
  scal[SC_OM0+a] = e0 * inv;
  scal[SC_OM1+a] = e1 * inv;
  scal[SC_NFMU+a] = nf[a*2+0];
  scal[SC_NFSD+a] = fabsf(nf[a*2+1]) + 1e-12f;
  scal[SC_RF1SD+a] = fabsf(rf1[a*2+1]) + 1e-12f;
  scal[SC_RF2SD+a] = fabsf(rf2[a*2+1]) + 1e-12f;
  scal[SC_ENVMU+a] = env[a*2+0];
  scal[SC_ENVSD+a] = fabsf(env[a*2+1] + 1e-12f) * 0.1f;
  float amp = fabsf(amplitudes[a]);
  scal[SC_AMPS+a] = amp;
  dout[2097152 + a] = amp;                       // output 1: amps
  float d  = 0.02f + (1.0f/(1.0f+expf(-decays[a]))) * (0.98f * 0.95f);
  float fd = 0.02f + (1.0f/(1.0f+expf(-fdec[a])))   * (0.98f * 0.95f);
  float pd = 1.0f, pf = 1.0f;
  for (int f = 0; f < 128; ++f) {
    pd *= d; pf *= fd;
    scal[SC_DTAB + a*128 + f] = pd;
    scal[SC_FTAB + a*128 + f] = pf;
  }
  float x0 = verb[a*4+0], x1 = verb[a*4+1], x2 = verb[a*4+2], x3 = verb[a*4+3];
  float mean = (x0+x1+x2+x3) * 0.25f;
  float d0 = x0-mean, d1 = x1-mean, d2 = x2-mean, d3 = x3-mean;
  float var = (d0*d0 + d1*d1 + d2*d2 + d3*d3) * 0.25f;
  float rs = 1.0f / sqrtf(var + 1e-5f);
  float h[4] = { d0*rs*ln_w[0]+ln_b[0], d1*rs*ln_w[1]+ln_b[1],
                 d2*rs*ln_w[2]+ln_b[2], d3*rs*ln_w[3]+ln_b[3] };
  float t[4], u[4];
  for (int j = 0; j < 4; ++j) {
    float s1 = 0.f, s2 = 0.f;
    for (int i2 = 0; i2 < 4; ++i2) {
      s1 += h[i2] * mw1[i2*4 + j];
      s2 += h[i2] * rw1[i2*4 + j];
    }
    t[j] = (s1 > 0.f) ? s1 : 0.01f*s1;
    u[j] = (s2 > 0.f) ? s2 : 0.01f*s2;
  }
  float ml = 0.f;
  for (int j = 0; j < 4; ++j) ml += t[j] * mw2[j];
  scal[SC_MIXV+a] = 1.0f / (1.0f + expf(-ml));
  float best = -1e30f; int bi = 0;
  for (int rr = 0; rr < 8; ++rr) {
    float lg = 0.f;
    for (int j = 0; j < 4; ++j) lg += u[j] * rw2[j*8 + rr];
    if (lg > best) { best = lg; bi = rr; }
  }
  ((int*)scal)[SC_ROOM + a] = bi;
}

// ---------------- resonances GEMM: ANALYTIC waves, MFMA, no loads ----------
// grid (256, 2) x 512 threads (8 waves); K half per blockIdx.y.
// B fragment computed in-register from rps table:
//   rad = rps[s]*col (fp32, == numpy); saw via IEEE fp32 div+floor (exact);
//   tri = 2|saw|-1 (exact); sq from DOUBLE frac(rad/2pi) < 0.5 (sign exact);
//   sine = __sinf(2pi*frac) (<=2e-7 abs err, absorbed by bf16 quantization).
__global__ __launch_bounds__(512) void k_gemm_mfma(
    const float* __restrict__ scal, const short* __restrict__ ctb,
    short* __restrict__ rp)
{
  const int t = threadIdx.x;
  const int w = t >> 6, lane = t & 63;
  const int ml = lane & 15, q = lane >> 4;
  const int col = blockIdx.x * 128 + w * 16 + ml;
  const int part = blockIdx.y;

  const float colf = (float)col;
  const float TWO_PI_F = 6.28318530717958647692f;
  const double INV_2PI = 0.15915494309189533577;

  f32x4 acc[4] = {};
  const short* abase = ctb + (size_t)ml * 4096 + (size_t)part * 2048 + q * 8;
  const float* rtab = scal + SC_RPS + part * 512;

  #define WAVE4(rps, b, off) { \
    float rad = (rps) * colf; \
    double dt = (double)rad * INV_2PI; \
    double frd = dt - floor(dt); \
    float sine = __sinf((float)frd * TWO_PI_F); \
    float sq = (rad == 0.0f) ? 0.0f : ((frd < 0.5) ? 1.0f : -1.0f); \
    float tt = rad / TWO_PI_F; \
    float saw = 2.0f * (tt - floorf(tt + 0.5f)); \
    float tri = 2.0f * fabsf(saw) - 1.0f; \
    b[off+0] = f2bf(sine); b[off+1] = f2bf(saw); \
    b[off+2] = f2bf(sq);   b[off+3] = f2bf(tri); }

  for (int kbl = 0; kbl < 64; ++kbl) {
    int sl = kbl * 8 + 2 * q;
    float rps0 = rtab[sl], rps1 = rtab[sl + 1];
    bf16x8 b;
    WAVE4(rps0, b, 0);
    WAVE4(rps1, b, 4);
    const short* ap = abase + (size_t)kbl * 32;
    acc[0] = __builtin_amdgcn_mfma_f32_16x16x32_bf16(*(const bf16x8*)(ap),                   b, acc[0], 0,0,0);
    acc[1] = __builtin_amdgcn_mfma_f32_16x16x32_bf16(*(const bf16x8*)(ap + (size_t)16*4096), b, acc[1], 0,0,0);
    acc[2] = __builtin_amdgcn_mfma_f32_16x16x32_bf16(*(const bf16x8*)(ap + (size_t)32*4096), b, acc[2], 0,0,0);
    acc[3] = __builtin_amdgcn_mfma_f32_16x16x32_bf16(*(const bf16x8*)(ap + (size_t)48*4096), b, acc[3], 0,0,0);
  }
  #undef WAVE4

  #pragma unroll
  for (int mt = 0; mt < 4; ++mt) {
    #pragma unroll
    for (int rr = 0; rr < 4; ++rr) {
      rp[(size_t)(part*64 + mt*16 + q*4 + rr) * 32768 + col] = f2bf(acc[mt][rr]);
    }
  }
}

// ============================================================================
extern "C" void kernel_launch(void* const* d_in, const int* in_sizes, int n_in,
                              void* d_out, int out_size, void* d_ws, size_t ws_size,
                              hipStream_t stream)
{
  const float* mix   = (const float*)d_in[1];
  const float* dec   = (const float*)d_in[2];
  const float* fdec  = (const float*)d_in[3];
  const float* rc    = (const float*)d_in[4];
  const float* nf    = (const float*)d_in[5];
  const float* rf1   = (const float*)d_in[6];
  const float* rf2   = (const float*)d_in[7];
  const float* env   = (const float*)d_in[8];
  const float* amps  = (const float*)d_in[9];
  const float* verb  = (const float*)d_in[10];
  const float* noise = (const float*)d_in[11];
  const float* lnw   = (const float*)d_in[13];
  const float* lnb   = (const float*)d_in[14];
  const float* mw1   = (const float*)d_in[15];
  const float* mw2   = (const float*)d_in[16];
  const float* rw1   = (const float*)d_in[17];
  const float* rw2   = (const float*)d_in[18];
  const float* rirs  = (const float*)d_in[19];
  float* out = (float*)d_out;
  float* w   = (float*)d_ws;

  if (ws_size < WS_FLOATS * 4ULL) return;

  float*    scal = w + OFF_SCAL;
  short*    ctb  = (short*)(w + OFF_CT);
  short*    rp   = (short*)(w + OFF_RP);     // bf16, dead before Ds
  unsigned* P    = (unsigned*)(w + OFF_P);   // bf16-packed, half-transformed
  unsigned* Ds   = (unsigned*)(w + OFF_DS);
  unsigned* W64  = (unsigned*)(w + OFF_W64);
  unsigned* RSs  = (unsigned*)(w + OFF_RSS);
  unsigned* NSs  = (unsigned*)(w + OFF_NSS); // in W64 region (early)
  unsigned* W2   = (unsigned*)(w + OFF_W2);  // in W64 region (early)
  float*    finU = w + OFF_FINU;
  unsigned* W1   = (unsigned*)(w + OFF_W1);
  short*    fnb  = (short*)(w + OFF_FN);     // fn bf16
  unsigned* FRP  = (unsigned*)(w + OFF_FRP); // fr1+i*fr2 packed
  unsigned* IRS  = (unsigned*)(w + OFF_IRS); // bf16-packed, half-transformed
  const int* room = ((const int*)(w + OFF_SCAL)) + SC_ROOM;

  // A repack + per-atom scalars + rps table
  k_packA<<<1024, 256, 0, stream>>>(rc, ctb, mix, dec, fdec, nf, rf1, rf2, env,
                                    amps, verb, lnw, lnb, mw1, mw2, rw1, rw2,
                                    scal, out);
  // analytic GEMM (no waves read)
  k_gemm_mfma<<<dim3(256, 2), 512, 0, stream>>>(scal, ctb, rp);

  // merged RS (sum 2 bf16 GEMM partials) + NS chains: 3 dispatches
  k_fft_s128_first<<<dim3(8,128),256,0,stream>>>(RSs, NSs, rp, noise);
  k_fft_m128_both<<<dim3(16,128),256,0,stream>>>(RSs, NSs, W1, W2, scal);
  k_fft_s128_last<<<dim3(8,128),256,0,stream>>>(W1, W2, FRP, fnb);

  // merged Ds + P + IRS forward strided (all half-transformed, bf16)
  k_fft_s256_DsPI<<<dim3(16,136),256,0,stream>>>(Ds, P, IRS, FRP, fnb, rirs, scal);

  // conv mid: fft(Ds)*fft(P) -> inverse-contig -> W64
  k_fft_mid256dual<<<dim3(16,64),256,0,stream>>>(Ds, P, W64, nullptr);

  // FUSED: conv inverse -> finU + SS partials -> reverb forward -> Ds
  k_fft_out6fwd<<<dim3(16,64),256,0,stream>>>(W64, fnb, finU, scal, Ds);

  // reverb mid: fft(Ds half) * fft(IRS half[room]) -> inverse-contig -> W64
  // *** NO contig FFT between strided and mid (round-2 bug) ***
  k_fft_mid256dual<<<dim3(16,64),256,0,stream>>>(Ds, IRS, W64, room);

  // final inverse + inline norm (from PSS partials) + dry/wet mix
  k_fft_s256_out3<<<dim3(16,64),256,0,stream>>>(W64, finU, scal, out);
}

// Round 18
// 260.793 us; speedup vs baseline: 1.1516x; 1.0293x over previous
//
#include <hip/hip_runtime.h>

// ============================================================================
// Model_22016002360008 — synth forward pass.
//  GEMM: bf16 MFMA 16x16x32, FULLY ANALYTIC B (no waves read).
//  FFT: complex four-step, N = N1*256, digit-permuted spectrum
//       addr = k2*N1 + k1, true bin k = k2 + 256*k1.
//  ALL spectra bf16-packed; fr1/fr2 packed (FRP), fn bf16; finU fp32.
//  ALL transforms now REGISTER-based: length-256 = 16x16 (dft16+transpose+
//  dft16); 32K mid = 16x8 four-step (dft8 -> tw -> dft16 -> filter ->
//  inv dft16 [same reg layout] -> tw -> inv dft8), 3 barriers.
//  Fusions: scalars+rps in packA; conv-inverse+finU+SS+reverb-fwd in one
//  kernel; fscale deferred; Ds+P+IRS forwards one dispatch.
//  !! mid's input must be STRIDED-ONLY (half-transformed) data — never run
//  !! a contig FFT before a mid kernel (round-2 bug, reverb path).
// ============================================================================

typedef __attribute__((ext_vector_type(8))) short bf16x8;
typedef __attribute__((ext_vector_type(4))) float f32x4;

constexpr int SC_OM0   = 0;
constexpr int SC_OM1   = 64;
constexpr int SC_NFMU  = 128;
constexpr int SC_NFSD  = 192;
constexpr int SC_RF1SD = 256;
constexpr int SC_RF2SD = 320;
constexpr int SC_ENVMU = 384;
constexpr int SC_ENVSD = 448;
constexpr int SC_AMPS  = 512;
constexpr int SC_MIXV  = 576;
constexpr int SC_ROOM  = 832;
constexpr int SC_PSS   = 1024;   // 64 x 16 partial sum-of-squares
constexpr int SC_DTAB  = 4096;
constexpr int SC_FTAB  = 12288;
constexpr int SC_RPS   = 20480;  // 1024-entry fp32 rps table

constexpr size_t OFF_SCAL = 0;
constexpr size_t OFF_CT   = 65536;
constexpr size_t OFF_P    = 327680;
constexpr size_t OFF_DS   = 8716288;
constexpr size_t OFF_RP   = OFF_DS;
constexpr size_t OFF_W64  = 17104896;
constexpr size_t OFF_NSS  = OFF_W64;
constexpr size_t OFF_W2   = OFF_W64 + 4194304;
constexpr size_t OFF_RSS  = 25493504;
constexpr size_t OFF_FINU = OFF_RSS;
constexpr size_t OFF_W1   = 29687808;
constexpr size_t OFF_FN   = 38076416;
constexpr size_t OFF_FRP  = 40173568;
constexpr size_t OFF_IRS  = 44367872;
constexpr size_t WS_FLOATS= 45416448;

__device__ __forceinline__ float2 cmul(float2 a, float2 b) {
  return make_float2(a.x*b.x - a.y*b.y, a.x*b.y + a.y*b.x);
}

__device__ __forceinline__ short f2bf(float x) {
  unsigned u = __float_as_uint(x);
  u = (u + 0x7FFFu + ((u >> 16) & 1u)) >> 16;
  return (short)u;
}
__device__ __forceinline__ float bf2f(short s) {
  return __uint_as_float((unsigned)(unsigned short)s << 16);
}
__device__ __forceinline__ unsigned pk2(float2 v) {
  return (unsigned)(unsigned short)f2bf(v.x)
       | ((unsigned)(unsigned short)f2bf(v.y) << 16);
}
__device__ __forceinline__ float2 upk2(unsigned u) {
  return make_float2(__uint_as_float(u << 16),
                     __uint_as_float(u & 0xFFFF0000u));
}

// ---------------- 16-point DFT in registers (natural order in/out) ---------
__device__ __forceinline__ void dft16(float2 d[16], float ei)
{
  const float CA[4] = {1.0f, 0.92387953251128674f, 0.70710678118654752f, 0.38268343236508977f};
  const float SA[4] = {0.0f, 0.38268343236508977f, 0.70710678118654752f, 0.92387953251128674f};
  const float CB[4] = {1.0f, 0.70710678118654752f, 0.0f, -0.70710678118654752f};
  const float SB[4] = {0.0f, 0.70710678118654752f, 1.0f, 0.70710678118654752f};
  float2 e[16];
  #pragma unroll
  for (int q = 0; q < 4; ++q) {
    float2 x0 = d[q], x1 = d[q+4], x2 = d[q+8], x3 = d[q+12];
    float ca = CA[q], sa = ei*SA[q], cb = CB[q], sb = ei*SB[q];
    float2 sum1 = make_float2(x0.x+x2.x, x0.y+x2.y);
    float2 d1   = make_float2(x0.x-x2.x, x0.y-x2.y);
    float2 dif1 = make_float2(d1.x*ca - d1.y*sa, d1.x*sa + d1.y*ca);
    float2 sum2 = make_float2(x1.x+x3.x, x1.y+x3.y);
    float2 d2   = make_float2(x1.x-x3.x, x1.y-x3.y);
    float2 dt   = make_float2(d2.x*ca - d2.y*sa, d2.x*sa + d2.y*ca);
    float2 dif2 = make_float2(-ei*dt.y, ei*dt.x);
    float2 Dm   = make_float2(sum1.x-sum2.x, sum1.y-sum2.y);
    float2 Dm2  = make_float2(dif1.x-dif2.x, dif1.y-dif2.y);
    e[4*q+0] = make_float2(sum1.x+sum2.x, sum1.y+sum2.y);
    e[4*q+1] = make_float2(dif1.x+dif2.x, dif1.y+dif2.y);
    e[4*q+2] = make_float2(Dm.x*cb - Dm.y*sb, Dm.x*sb + Dm.y*cb);
    e[4*q+3] = make_float2(Dm2.x*cb - Dm2.y*sb, Dm2.x*sb + Dm2.y*cb);
  }
  #pragma unroll
  for (int q = 0; q < 4; ++q) {
    float2 x0 = e[q], x1 = e[q+4], x2 = e[q+8], x3 = e[q+12];
    float2 sum1 = make_float2(x0.x+x2.x, x0.y+x2.y);
    float2 dif1 = make_float2(x0.x-x2.x, x0.y-x2.y);
    float2 sum2 = make_float2(x1.x+x3.x, x1.y+x3.y);
    float2 d2   = make_float2(x1.x-x3.x, x1.y-x3.y);
    float2 dif2 = make_float2(-ei*d2.y, ei*d2.x);
    d[q]    = make_float2(sum1.x+sum2.x, sum1.y+sum2.y);
    d[q+4]  = make_float2(dif1.x+dif2.x, dif1.y+dif2.y);
    d[q+8]  = make_float2(sum1.x-sum2.x, sum1.y-sum2.y);
    d[q+12] = make_float2(dif1.x-dif2.x, dif1.y-dif2.y);
  }
}

// ---------------- 8-point DFT in registers (natural order in/out) ----------
// dft4(evens) + dft4(odds) + combine; verified on DC & impulse vs DFT defn.
__device__ __forceinline__ void dft8(float2 d[8], float ei)
{
  const float RS = 0.70710678118654752f;
  float2 E[4], O[4];
  {
    float2 s02 = make_float2(d[0].x+d[4].x, d[0].y+d[4].y);
    float2 m02 = make_float2(d[0].x-d[4].x, d[0].y-d[4].y);
    float2 s13 = make_float2(d[2].x+d[6].x, d[2].y+d[6].y);
    float2 m13 = make_float2(d[2].x-d[6].x, d[2].y-d[6].y);
    float2 im13 = make_float2(-ei*m13.y, ei*m13.x);
    E[0] = make_float2(s02.x+s13.x, s02.y+s13.y);
    E[1] = make_float2(m02.x+im13.x, m02.y+im13.y);
    E[2] = make_float2(s02.x-s13.x, s02.y-s13.y);
    E[3] = make_float2(m02.x-im13.x, m02.y-im13.y);
  }
  {
    float2 s02 = make_float2(d[1].x+d[5].x, d[1].y+d[5].y);
    float2 m02 = make_float2(d[1].x-d[5].x, d[1].y-d[5].y);
    float2 s13 = make_float2(d[3].x+d[7].x, d[3].y+d[7].y);
    float2 m13 = make_float2(d[3].x-d[7].x, d[3].y-d[7].y);
    float2 im13 = make_float2(-ei*m13.y, ei*m13.x);
    O[0] = make_float2(s02.x+s13.x, s02.y+s13.y);
    O[1] = make_float2(m02.x+im13.x, m02.y+im13.y);
    O[2] = make_float2(s02.x-s13.x, s02.y-s13.y);
    O[3] = make_float2(m02.x-im13.x, m02.y-im13.y);
  }
  float2 w1 = make_float2(RS, ei*RS);
  float2 w2 = make_float2(0.0f, ei);
  float2 w3 = make_float2(-RS, ei*RS);
  float2 t0 = O[0];
  float2 t1 = cmul(w1, O[1]);
  float2 t2 = cmul(w2, O[2]);
  float2 t3 = cmul(w3, O[3]);
  d[0] = make_float2(E[0].x+t0.x, E[0].y+t0.y);
  d[1] = make_float2(E[1].x+t1.x, E[1].y+t1.y);
  d[2] = make_float2(E[2].x+t2.x, E[2].y+t2.y);
  d[3] = make_float2(E[3].x+t3.x, E[3].y+t3.y);
  d[4] = make_float2(E[0].x-t0.x, E[0].y-t0.y);
  d[5] = make_float2(E[1].x-t1.x, E[1].y-t1.y);
  d[6] = make_float2(E[2].x-t2.x, E[2].y-t2.y);
  d[7] = make_float2(E[3].x-t3.x, E[3].y-t3.y);
}

__device__ __forceinline__ void twiddleB(float2 d[16], int u, float dir2pi)
{
  float sn1, cs1;
  __sincosf(dir2pi * ((float)u * (1.0f/256.0f)), &sn1, &cs1);
  float2 w1 = make_float2(cs1, sn1);
  float2 tw = w1;
  #pragma unroll
  for (int k = 1; k < 16; ++k) { d[k] = cmul(d[k], tw); tw = cmul(tw, w1); }
}

// ---------------- merged Ds + P + IRS forward strided (64K) ----------------
__global__ __launch_bounds__(256) void k_fft_s256_DsPI(
    unsigned* __restrict__ Ds, unsigned* __restrict__ P,
    unsigned* __restrict__ IRS,
    const unsigned* __restrict__ FRP, const short* __restrict__ fnb,
    const float* __restrict__ rirs, const float* __restrict__ scal)
{
  constexpr int N = 65536, NH = 32768;
  constexpr float FWD = -6.283185307179586f;
  __shared__ float2 X[16*16*17];
  __shared__ float2 T256[256];
  __shared__ float2 TN[256];
  const int mode = (blockIdx.y < 64) ? 0 : ((blockIdx.y < 128) ? 1 : 2);
  const int a = (mode == 0) ? blockIdx.y : ((mode == 1) ? blockIdx.y - 64 : blockIdx.y - 128);
  const int n1base = blockIdx.x << 4;
  const int r = threadIdx.x & 15;
  const int u = threadIdx.x >> 4;

  {
    float ang = FWD * ((float)threadIdx.x * (1.0f/256.0f));
    float sn, cs; __sincosf(ang, &sn, &cs);
    T256[threadIdx.x] = make_float2(cs, sn);
    float ang2 = FWD * ((float)threadIdx.x * (1.0f/(float)N));
    float sn2, cs2; __sincosf(ang2, &sn2, &cs2);
    TN[threadIdx.x] = make_float2(cs2, sn2);
  }

  float emu = 0.f, esd = 1.f, egp = 0.f;
  if (mode == 1) {
    emu = scal[SC_ENVMU + a];
    esd = scal[SC_ENVSD + a];
    egp = 0.3989422804014327f / esd;
  }

  float2 d[16];
  #pragma unroll
  for (int m = 0; m < 16; ++m) {
    int j = u + (m << 4);
    int n = n1base + r + 256 * j;
    float2 v = make_float2(0.0f, 0.0f);
    if (n < NH) {
      if (mode == 0) {
        float pos = ((float)n + 0.5f) * (1.0f/256.0f) - 0.5f;
        pos = fminf(fmaxf(pos, 0.0f), 127.0f);
        int i0 = (int)pos;
        float w = pos - (float)i0;
        int i1 = (i0 + 1 < 127) ? i0 + 1 : 127;
        const float* dt = scal + SC_DTAB + a*128;
        float de = dt[i0]*(1.0f-w) + dt[i1]*w;
        float2 fr = upk2(FRP[(size_t)a * NH + n]);
        v = make_float2(fr.x * de, fr.y * de);
      } else if (mode == 1) {
        float uu = (float)n * (1.0f / 32767.0f);
        float te = (uu - emu) / esd;
        float envv = __expf(-0.5f * te * te) * egp;
        v = make_float2(bf2f(fnb[(size_t)a * NH + n]) * envv, 0.0f);
      } else {
        v = make_float2(rirs[(size_t)a * NH + n], 0.0f);
      }
    }
    d[m] = v;
  }

  dft16(d, -1.0f);
  twiddleB(d, u, FWD);
  #pragma unroll
  for (int k = 0; k < 16; ++k) X[(u*16 + k)*17 + r] = d[k];
  __syncthreads();
  #pragma unroll
  for (int m = 0; m < 16; ++m) d[m] = X[(m*16 + u)*17 + r];
  dft16(d, -1.0f);

  unsigned* outp = (mode == 0) ? Ds : ((mode == 1) ? P : IRS);
  #pragma unroll
  for (int k1 = 0; k1 < 16; ++k1) {
    int j = u + (k1 << 4);
    int n = n1base + r + 256 * j;
    int aa = (n1base + r) * j;
    float2 tw = cmul(T256[(aa >> 8) & 255], TN[aa & 255]);
    outp[(size_t)a * N + n] = pk2(cmul(d[k1], tw));
  }
}

// ---------------- merged first strided (32K): RS (y<64) + NS (y>=64) -------
__global__ __launch_bounds__(256) void k_fft_s128_first(
    unsigned* __restrict__ RSs, unsigned* __restrict__ NSs,
    const short* __restrict__ rez, const float* __restrict__ noise)
{
  constexpr int N1 = 128, N = 32768;
  constexpr float FWD = -6.283185307179586f;
  __shared__ float2 X[16*16*17];
  __shared__ float2 T256[256];
  __shared__ float2 TN[128];
  const bool isRS = blockIdx.y < 64;
  const int a = isRS ? blockIdx.y : blockIdx.y - 64;
  const int n1base = blockIdx.x << 4;
  const int r = threadIdx.x & 15;
  const int u = threadIdx.x >> 4;

  {
    float ang = FWD * ((float)threadIdx.x * (1.0f/256.0f));
    float sn, cs; __sincosf(ang, &sn, &cs);
    T256[threadIdx.x] = make_float2(cs, sn);
    if (threadIdx.x < 128) {
      float ang2 = FWD * ((float)threadIdx.x * (1.0f/(float)N));
      float sn2, cs2; __sincosf(ang2, &sn2, &cs2);
      TN[threadIdx.x] = make_float2(cs2, sn2);
    }
  }

  float2 d[16];
  #pragma unroll
  for (int m = 0; m < 16; ++m) {
    int j = u + (m << 4);
    int n = n1base + r + N1 * j;
    float x = isRS ? (bf2f(rez[(size_t)a * N + n]) +
                      bf2f(rez[(size_t)(64 + a) * N + n]))
                   : noise[(size_t)a * N + n];
    d[m] = make_float2(x, 0.0f);
  }

  dft16(d, -1.0f);
  twiddleB(d, u, FWD);
  #pragma unroll
  for (int k = 0; k < 16; ++k) X[(u*16 + k)*17 + r] = d[k];
  __syncthreads();
  #pragma unroll
  for (int m = 0; m < 16; ++m) d[m] = X[(m*16 + u)*17 + r];
  dft16(d, -1.0f);

  unsigned* outp = isRS ? RSs : NSs;
  #pragma unroll
  for (int k1 = 0; k1 < 16; ++k1) {
    int j = u + (k1 << 4);
    int n = n1base + r + N1 * j;
    int aa = (n1base + r) * j;
    float2 tw = cmul(T256[(aa >> 7) & 255], TN[aa & 127]);
    outp[(size_t)a * N + n] = pk2(cmul(d[k1], tw));
  }
}

// ---------------- 32K mid, REGISTER 16x8 four-step --------------------------
// 128 = 16*8: n = n1 + 16*n2, spectral j = k2 + 8*k1.
// fwd: dft8 over n2 -> tw w128^{-k2 n1} -> [LDS transpose] -> dft16 over n1.
// filter in register (thread holds j = k2+8k1 over k1). inverse: dft16 over
// k1 (layout already matches) -> tw conj -> [transpose] -> dft8 -> out + tw.
// Tile: 32 cols x 128. Grid (8, 128). 3 barriers.
__global__ __launch_bounds__(256) void k_fft_m128_both(
    const unsigned* __restrict__ RSs, const unsigned* __restrict__ NSs,
    unsigned* __restrict__ W1, unsigned* __restrict__ W2,
    const float* __restrict__ scal)
{
  constexpr int N = 32768;
  constexpr float FWD = -6.283185307179586f;
  constexpr float IVD = +6.283185307179586f;
  __shared__ float2 L[32*145];       // c*145 + n1*9 + k2
  __shared__ float2 T256[256];       // FWD direction
  __shared__ float2 TN[128];         // IVD direction (outer post-twiddle)
  const bool isRS = blockIdx.y < 64;
  const int a = isRS ? blockIdx.y : blockIdx.y - 64;
  const int colbase = blockIdx.x << 5;   // 32 cols per block
  const int t = threadIdx.x;

  {
    float ang = FWD * ((float)t * (1.0f/256.0f));
    float sn, cs; __sincosf(ang, &sn, &cs);
    T256[t] = make_float2(cs, sn);
    if (t < 128) {
      float ang2 = IVD * ((float)t * (1.0f/(float)N));
      float sn2, cs2; __sincosf(ang2, &sn2, &cs2);
      TN[t] = make_float2(cs2, sn2);
    }
  }

  float mu = 0.f, isd1 = 0.f, g1 = 0.f, isd2 = 0.f, g2 = 0.f;
  if (isRS) {
    float s1 = scal[SC_RF1SD + a], s2 = scal[SC_RF2SD + a];
    isd1 = 1.0f/s1; g1 = 0.3989422804014327f/s1;
    isd2 = 1.0f/s2; g2 = 0.3989422804014327f/s2;
  } else {
    float sd = scal[SC_NFSD + a]; mu = scal[SC_NFMU + a];
    isd1 = 1.0f/sd; g1 = 0.3989422804014327f/sd;
  }
  const unsigned* zin = (isRS ? RSs : NSs) + (size_t)a * N;
  unsigned* outp = (isRS ? W1 : W2) + (size_t)a * N;

  __syncthreads();   // tables visible

  // ---- step A: 2x { dft8 over n2; tw w128^{-k2*n1}; write L } ----
  #pragma unroll
  for (int pp = 0; pp < 2; ++pp) {
    int p = t + (pp << 8);
    int c = p >> 4, n1 = p & 15;
    float2 d8[8];
    #pragma unroll
    for (int n2 = 0; n2 < 8; ++n2)
      d8[n2] = upk2(zin[(size_t)(colbase + c) * 128 + n1 + (n2 << 4)]);
    dft8(d8, -1.0f);
    #pragma unroll
    for (int k2 = 0; k2 < 8; ++k2) {
      float2 v = cmul(d8[k2], T256[(k2 * n1) << 1]);   // angle k2*n1/128 (FWD)
      L[c*145 + n1*9 + k2] = v;
    }
  }
  __syncthreads();

  // ---- step C: dft16 over n1; filter; inv dft16; tw conj; write back ----
  {
    int c = t >> 3, k2 = t & 7;
    float2 d[16];
    #pragma unroll
    for (int n1 = 0; n1 < 16; ++n1) d[n1] = L[c*145 + n1*9 + k2];
    dft16(d, -1.0f);                   // d[k1] = X[j = k2 + 8*k1]
    int col = colbase + c;
    #pragma unroll
    for (int k1 = 0; k1 < 16; ++k1) {
      int j = k2 + (k1 << 3);
      int k = col + (j << 8);          // true bin
      int kk = (k <= N - k) ? k : N - k;
      float2 v = d[k1];
      if (isRS) {
        float fr = (float)kk * (2.0f/(float)N);
        float t1 = fr * isd1, t2 = fr * isd2;
        float ga = __expf(-0.5f * t1 * t1) * g1;   // G1 (real)
        float gb = __expf(-0.5f * t2 * t2) * g2;   // G2 (imag)
        v = make_float2(v.x*ga - v.y*gb, v.x*gb + v.y*ga);
      } else {
        float tt = ((float)kk * (2.0f/(float)N) - mu) * isd1;
        float g = __expf(-0.5f * tt * tt) * g1;
        v.x *= g; v.y *= g;
      }
      d[k1] = v;
    }
    dft16(d, 1.0f);                    // inverse over k1 -> over n1
    #pragma unroll
    for (int n1 = 0; n1 < 16; ++n1) {
      float2 tw = T256[(k2 * n1) << 1];
      tw.y = -tw.y;                    // conj -> inverse direction
      L[c*145 + n1*9 + k2] = cmul(d[n1], tw);   // same slots (thread-local)
    }
  }
  __syncthreads();

  // ---- step E: 2x { read over k2; inv dft8 -> n2; outer tw; write } ----
  #pragma unroll
  for (int pp = 0; pp < 2; ++pp) {
    int p = t + (pp << 8);
    int c = p >> 4, n1 = p & 15;
    float2 d8[8];
    #pragma unroll
    for (int k2 = 0; k2 < 8; ++k2) d8[k2] = L[c*145 + n1*9 + k2];
    dft8(d8, 1.0f);
    int col = colbase + c;
    #pragma unroll
    for (int n2 = 0; n2 < 8; ++n2) {
      int n = n1 + (n2 << 4);
      int aa = n * col;                // < 32768
      float2 t1 = T256[(aa >> 7) & 255];
      t1.y = -t1.y;                    // conj -> IVD direction
      float2 tw = cmul(t1, TN[aa & 127]);
      outp[(size_t)col * 128 + n] = pk2(cmul(d8[n2], tw));
    }
  }
}

// ---------------- merged final strided (32K inverse) -----------------------
__global__ __launch_bounds__(256) void k_fft_s128_last(
    const unsigned* __restrict__ W1, const unsigned* __restrict__ W2,
    unsigned* __restrict__ FRP, short* __restrict__ fnb)
{
  constexpr int N1 = 128, N = 32768;
  constexpr float IVD = +6.283185307179586f;
  constexpr float S32 = 1.0f / 32768.0f;
  __shared__ float2 X[16*16*17];
  const bool isRS = blockIdx.y < 64;
  const int a = isRS ? blockIdx.y : blockIdx.y - 64;
  const int n1base = blockIdx.x << 4;
  const int r = threadIdx.x & 15;
  const int u = threadIdx.x >> 4;

  const unsigned* cb = (isRS ? W1 : W2) + (size_t)a * N;
  float2 d[16];
  #pragma unroll
  for (int m = 0; m < 16; ++m) {
    int j = u + (m << 4);
    d[m] = upk2(cb[n1base + r + N1 * j]);
  }
  dft16(d, 1.0f);
  twiddleB(d, u, IVD);
  #pragma unroll
  for (int k = 0; k < 16; ++k) X[(u*16 + k)*17 + r] = d[k];
  __syncthreads();
  #pragma unroll
  for (int m = 0; m < 16; ++m) d[m] = X[(m*16 + u)*17 + r];
  dft16(d, 1.0f);

  #pragma unroll
  for (int k1 = 0; k1 < 16; ++k1) {
    int j = u + (k1 << 4);
    int n = n1base + r + N1 * j;
    if (isRS) {
      FRP[(size_t)a * N + n] = pk2(make_float2(d[k1].x * S32, d[k1].y * S32));
    } else {
      fnb[(size_t)a * N + n] = f2bf(d[k1].x * S32);
    }
  }
}

// ---------------- fused middle, 64K (register FFT, dual-operand) -----------
__global__ __launch_bounds__(256) void k_fft_mid256dual(
    const unsigned* __restrict__ zin, const unsigned* __restrict__ zin2half,
    unsigned* __restrict__ out1, const int* __restrict__ roomArr)
{
  constexpr int N = 65536;
  constexpr float FWD = -6.283185307179586f;
  constexpr float IVD = +6.283185307179586f;
  __shared__ float2 X[16*16*17];
  __shared__ float2 T256[256];
  __shared__ float2 TN[256];
  const int a = blockIdx.y;
  const int colbase = blockIdx.x << 4;
  const int u  = threadIdx.x & 15;
  const int rc = threadIdx.x >> 4;

  {
    float ang = FWD * ((float)threadIdx.x * (1.0f/256.0f));
    float sn, cs; __sincosf(ang, &sn, &cs);
    T256[threadIdx.x] = make_float2(cs, sn);
    float ang2 = IVD * ((float)threadIdx.x * (1.0f/(float)N));
    float sn2, cs2; __sincosf(ang2, &sn2, &cs2);
    TN[threadIdx.x] = make_float2(cs2, sn2);
  }
  __syncthreads();

  const unsigned* z2 = zin2half + (size_t)(roomArr ? roomArr[a] : a) * N;
  const size_t rowG = (size_t)a * N + (size_t)(colbase + rc) * 256;
  const size_t rowZ2 = (size_t)(colbase + rc) * 256;

  float2 d[16];
  #pragma unroll
  for (int m = 0; m < 16; ++m) d[m] = upk2(zin[rowG + u + (m << 4)]);
  dft16(d, -1.0f);
  twiddleB(d, u, FWD);
  #pragma unroll
  for (int k = 0; k < 16; ++k) X[(rc*16 + k)*17 + u] = d[k];
  #pragma unroll
  for (int m = 0; m < 16; ++m) d[m] = X[(rc*16 + u)*17 + m];
  dft16(d, -1.0f);

  float2 stash[16];
  #pragma unroll
  for (int k = 0; k < 16; ++k) stash[k] = d[k];
  #pragma unroll
  for (int m = 0; m < 16; ++m) d[m] = upk2(z2[rowZ2 + u + (m << 4)]);
  dft16(d, -1.0f);
  twiddleB(d, u, FWD);
  #pragma unroll
  for (int k = 0; k < 16; ++k) X[(rc*16 + k)*17 + u] = d[k];
  #pragma unroll
  for (int m = 0; m < 16; ++m) d[m] = X[(rc*16 + u)*17 + m];
  dft16(d, -1.0f);
  #pragma unroll
  for (int k = 0; k < 16; ++k) d[k] = cmul(stash[k], d[k]);

  dft16(d, 1.0f);
  twiddleB(d, u, IVD);
  #pragma unroll
  for (int k = 0; k < 16; ++k) X[(rc*16 + k)*17 + u] = d[k];
  #pragma unroll
  for (int m = 0; m < 16; ++m) d[m] = X[(rc*16 + u)*17 + m];
  dft16(d, 1.0f);

  #pragma unroll
  for (int k1 = 0; k1 < 16; ++k1) {
    int j = u + (k1 << 4);
    int aa = j * (colbase + rc);
    float2 t1 = T256[(aa >> 8) & 255];
    t1.y = -t1.y;
    float2 tw = cmul(t1, TN[aa & 255]);
    out1[rowG + j] = pk2(cmul(d[k1], tw));
  }
}

// ---------------- FUSED: conv inverse -> finU + SS -> reverb forward -------
__global__ __launch_bounds__(256) void k_fft_out6fwd(
    const unsigned* __restrict__ W64in, const short* __restrict__ fnb,
    float* __restrict__ finU, float* __restrict__ scal,
    unsigned* __restrict__ DsOut)
{
  constexpr int N = 65536, NH = 32768;
  constexpr float FWD = -6.283185307179586f;
  constexpr float IVD = +6.283185307179586f;
  constexpr float S64 = 1.0f / 65536.0f;
  __shared__ float2 X[16*16*17];
  __shared__ float2 T256[256];   // FWD (for output twiddle)
  __shared__ float2 TN[256];     // FWD
  __shared__ float red[256];
  const int a = blockIdx.y;
  const int n1base = blockIdx.x << 4;
  const int r = threadIdx.x & 15;
  const int u = threadIdx.x >> 4;

  {
    float ang = FWD * ((float)threadIdx.x * (1.0f/256.0f));
    float sn, cs; __sincosf(ang, &sn, &cs);
    T256[threadIdx.x] = make_float2(cs, sn);
    float ang2 = FWD * ((float)threadIdx.x * (1.0f/(float)N));
    float sn2, cs2; __sincosf(ang2, &sn2, &cs2);
    TN[threadIdx.x] = make_float2(cs2, sn2);
  }

  const float emu = scal[SC_ENVMU + a];
  const float esd = scal[SC_ENVSD + a];
  const float egp = 0.3989422804014327f / esd;
  const float om0 = scal[SC_OM0 + a], om1 = scal[SC_OM1 + a];
  const float* ft = scal + SC_FTAB + a*128;

  float2 d[16];
  #pragma unroll
  for (int m = 0; m < 16; ++m) {
    int j = u + (m << 4);
    d[m] = upk2(W64in[(size_t)a * N + n1base + r + 256 * j]);
  }
  dft16(d, 1.0f);
  twiddleB(d, u, IVD);
  #pragma unroll
  for (int k = 0; k < 16; ++k) X[(u*16 + k)*17 + r] = d[k];
  __syncthreads();
  #pragma unroll
  for (int m = 0; m < 16; ++m) d[m] = X[(m*16 + u)*17 + r];
  dft16(d, 1.0f);

  float fv[8];
  float ss = 0.0f;
  #pragma unroll
  for (int k1 = 0; k1 < 8; ++k1) {
    int n = n1base + r + 256 * (u + (k1 << 4));
    float resv  = d[k1].x * S64;
    float res2v = d[k1].y * S64;
    float uu = (float)n * (1.0f / 32767.0f);
    float te = (uu - emu) / esd;
    float envv = __expf(-0.5f * te * te) * egp;
    float pnv = bf2f(fnb[(size_t)a * NH + n]) * envv;
    float pos = ((float)n + 0.5f) * (1.0f/256.0f) - 0.5f;
    pos = fminf(fmaxf(pos, 0.0f), 127.0f);
    int i0 = (int)pos;
    float w = pos - (float)i0;
    int i1 = (i0 + 1 < 127) ? i0 + 1 : 127;
    float fc = ft[i0]*(1.0f-w) + ft[i1]*w;
    float f = pnv*om0 + (fc*resv + (1.0f-fc)*res2v)*om1;
    finU[(size_t)a * NH + n] = f;
    fv[k1] = f;
    ss += f * f;
  }
  red[threadIdx.x] = ss;
  __syncthreads();
  for (int s = 128; s > 0; s >>= 1) {
    if (threadIdx.x < s) red[threadIdx.x] += red[threadIdx.x + s];
    __syncthreads();
  }
  if (threadIdx.x == 0) scal[SC_PSS + a*16 + blockIdx.x] = red[0];

  #pragma unroll
  for (int m = 0; m < 16; ++m)
    d[m] = (m < 8) ? make_float2(fv[m], 0.0f) : make_float2(0.0f, 0.0f);
  dft16(d, -1.0f);
  twiddleB(d, u, FWD);
  #pragma unroll
  for (int k = 0; k < 16; ++k) X[(u*16 + k)*17 + r] = d[k];
  __syncthreads();
  #pragma unroll
  for (int m = 0; m < 16; ++m) d[m] = X[(m*16 + u)*17 + r];
  dft16(d, -1.0f);

  #pragma unroll
  for (int k1 = 0; k1 < 16; ++k1) {
    int j = u + (k1 << 4);
    int n = n1base + r + 256 * j;
    int aa = (n1base + r) * j;
    float2 tw = cmul(T256[(aa >> 8) & 255], TN[aa & 255]);
    DsOut[(size_t)a * N + n] = pk2(cmul(d[k1], tw));
  }
}

// ---------------- final inverse strided + inline norm + dry/wet mix --------
__global__ __launch_bounds__(256) void k_fft_s256_out3(
    const unsigned* __restrict__ W64in, const float* __restrict__ finU,
    const float* __restrict__ scal, float* __restrict__ out)
{
  constexpr int N = 65536, NH = 32768;
  constexpr float IVD = +6.283185307179586f;
  constexpr float S64 = 1.0f / 65536.0f;
  __shared__ float2 X[16*16*17];
  const int a = blockIdx.y;
  const int n1base = blockIdx.x << 4;
  const int r = threadIdx.x & 15;
  const int u = threadIdx.x >> 4;

  float ss = 0.0f;
  #pragma unroll
  for (int i = 0; i < 16; ++i) ss += scal[SC_PSS + a*16 + i];
  float fscale = scal[SC_AMPS + a] / (sqrtf(ss) + 1e-8f);
  float mixv = scal[SC_MIXV + a];
  float w1 = fscale * (1.0f - mixv);
  float w0 = fscale * mixv;

  float2 d[16];
  #pragma unroll
  for (int m = 0; m < 16; ++m) {
    int j = u + (m << 4);
    d[m] = upk2(W64in[(size_t)a * N + n1base + r + 256 * j]);
  }
  dft16(d, 1.0f);
  twiddleB(d, u, IVD);
  #pragma unroll
  for (int k = 0; k < 16; ++k) X[(u*16 + k)*17 + r] = d[k];
  __syncthreads();
  #pragma unroll
  for (int m = 0; m < 16; ++m) d[m] = X[(m*16 + u)*17 + r];
  dft16(d, 1.0f);

  #pragma unroll
  for (int k1 = 0; k1 < 8; ++k1) {
    int n = n1base + r + 256 * (u + (k1 << 4));
    out[(size_t)a * NH + n] =
        d[k1].x * S64 * w1 + finU[(size_t)a * NH + n] * w0;
  }
}

// ---------------- A repack + per-atom scalars + rps table -------------------
__global__ void k_packA(const float* __restrict__ rc, short* __restrict__ ctb,
    const float* __restrict__ mix, const float* __restrict__ decays,
    const float* __restrict__ fdec, const float* __restrict__ nf,
    const float* __restrict__ rf1, const float* __restrict__ rf2,
    const float* __restrict__ env, const float* __restrict__ amplitudes,
    const float* __restrict__ verb, const float* __restrict__ ln_w,
    const float* __restrict__ ln_b, const float* __restrict__ mw1,
    const float* __restrict__ mw2, const float* __restrict__ rw1,
    const float* __restrict__ rw2, float* __restrict__ scal,
    float* __restrict__ dout)
{
  int o = blockIdx.x * 256 + threadIdx.x;   // o = m*4096 + k
  {
    int m = o >> 12, k = o & 4095;
    int s = k >> 2, f = k & 3;
    float v = fmaxf(rc[m*4096 + f*1024 + s], 0.0f);
    ctb[o] = f2bf(v);
  }
  if (blockIdx.x < 4) {
    int idx = blockIdx.x * 256 + threadIdx.x;   // 0..1023
    double step = 85.0 / 1023.0;
    double midi = (double)idx * step + 21.0;
    if (idx == 1023) midi = 106.0;
    double f0 = 440.0 * exp2((midi - 69.0) * (1.0 / 12.0));
    scal[SC_RPS + idx] = (float)((f0 / 11025.0) * 3.141592653589793);
  }
  if (blockIdx.x != 0 || threadIdx.x >= 64) return;
  int a = threadIdx.x;
  float m0 = mix[a*2+0], m1 = mix[a*2+1];
  float mx = fmaxf(m0, m1);
  float e0 = expf(m0 - mx), e1 = expf(m1 - mx);
  float inv = 1.0f / (e0 + e1);
  scal[SC_OM0+a] = e0 * inv;
  scal[SC_OM1+a] = e1 * inv;
  scal[SC_NFMU+a] = nf[a*2+0];
  scal[SC_NFSD+a] = fabsf(nf[a*2+1]) + 1e-12f;
  scal[SC_RF1SD+a] = fabsf(rf1[a*2+1]) + 1e-12f;
  scal[SC_RF2SD+a] = fabsf(rf2[a*2+1]) + 1e-12f;
  scal[SC_ENVMU+a] = env[a*2+0];
  scal[SC_ENVSD+a] = fabsf(env[a*2+1] + 1e-12f) * 0.1f;
  float amp = fabsf(amplitudes[a]);
  scal[SC_AMPS+a] = amp;
  dout[2097152 + a] = amp;                       // output 1: amps
  float d  = 0.02f + (1.0f/(1.0f+expf(-decays[a]))) * (0.98f * 0.95f);
  float fd = 0.02f + (1.0f/(1.0f+expf(-fdec[a])))   * (0.98f * 0.95f);
  float pd = 1.0f, pf = 1.0f;
  for (int f = 0; f < 128; ++f) {
    pd *= d; pf *= fd;
    scal[SC_DTAB + a*128 + f] = pd;
    scal[SC_FTAB + a*128 + f] = pf;
  }
  float x0 = verb[a*4+0], x1 = verb[a*4+1], x2 = verb[a*4+2], x3 = verb[a*4+3];
  float mean = (x0+x1+x2+x3) * 0.25f;
  float d0 = x0-mean, d1 = x1-mean, d2 = x2-mean, d3 = x3-mean;
  float var = (d0*d0 + d1*d1 + d2*d2 + d3*d3) * 0.25f;
  float rs = 1.0f / sqrtf(var + 1e-5f);
  float h[4] = { d0*rs*ln_w[0]+ln_b[0], d1*rs*ln_w[1]+ln_b[1],
                 d2*rs*ln_w[2]+ln_b[2], d3*rs*ln_w[3]+ln_b[3] };
  float t[4], u[4];
  for (int j = 0; j < 4; ++j) {
    float s1 = 0.f, s2 = 0.f;
    for (int i2 = 0; i2 < 4; ++i2) {
      s1 += h[i2] * mw1[i2*4 + j];
      s2 += h[i2] * rw1[i2*4 + j];
    }
    t[j] = (s1 > 0.f) ? s1 : 0.01f*s1;
    u[j] = (s2 > 0.f) ? s2 : 0.01f*s2;
  }
  float ml = 0.f;
  for (int j = 0; j < 4; ++j) ml += t[j] * mw2[j];
  scal[SC_MIXV+a] = 1.0f / (1.0f + expf(-ml));
  float best = -1e30f; int bi = 0;
  for (int rr = 0; rr < 8; ++rr) {
    float lg = 0.f;
    for (int j = 0; j < 4; ++j) lg += u[j] * rw2[j*8 + rr];
    if (lg > best) { best = lg; bi = rr; }
  }
  ((int*)scal)[SC_ROOM + a] = bi;
}

// ---------------- resonances GEMM: ANALYTIC waves, MFMA, no loads ----------
__global__ __launch_bounds__(512) void k_gemm_mfma(
    const float* __restrict__ scal, const short* __restrict__ ctb,
    short* __restrict__ rp)
{
  const int t = threadIdx.x;
  const int w = t >> 6, lane = t & 63;
  const int ml = lane & 15, q = lane >> 4;
  const int col = blockIdx.x * 128 + w * 16 + ml;
  const int part = blockIdx.y;

  const float colf = (float)col;
  const float TWO_PI_F = 6.28318530717958647692f;
  const double INV_2PI = 0.15915494309189533577;

  f32x4 acc[4] = {};
  const short* abase = ctb + (size_t)ml * 4096 + (size_t)part * 2048 + q * 8;
  const float* rtab = scal + SC_RPS + part * 512;

  #define WAVE4(rps, b, off) { \
    float rad = (rps) * colf; \
    double dt = (double)rad * INV_2PI; \
    double frd = dt - floor(dt); \
    float sine = __sinf((float)frd * TWO_PI_F); \
    float sq = (rad == 0.0f) ? 0.0f : ((frd < 0.5) ? 1.0f : -1.0f); \
    float tt = rad / TWO_PI_F; \
    float saw = 2.0f * (tt - floorf(tt + 0.5f)); \
    float tri = 2.0f * fabsf(saw) - 1.0f; \
    b[off+0] = f2bf(sine); b[off+1] = f2bf(saw); \
    b[off+2] = f2bf(sq);   b[off+3] = f2bf(tri); }

  for (int kbl = 0; kbl < 64; ++kbl) {
    int sl = kbl * 8 + 2 * q;
    float rps0 = rtab[sl], rps1 = rtab[sl + 1];
    bf16x8 b;
    WAVE4(rps0, b, 0);
    WAVE4(rps1, b, 4);
    const short* ap = abase + (size_t)kbl * 32;
    acc[0] = __builtin_amdgcn_mfma_f32_16x16x32_bf16(*(const bf16x8*)(ap),                   b, acc[0], 0,0,0);
    acc[1] = __builtin_amdgcn_mfma_f32_16x16x32_bf16(*(const bf16x8*)(ap + (size_t)16*4096), b, acc[1], 0,0,0);
    acc[2] = __builtin_amdgcn_mfma_f32_16x16x32_bf16(*(const bf16x8*)(ap + (size_t)32*4096), b, acc[2], 0,0,0);
    acc[3] = __builtin_amdgcn_mfma_f32_16x16x32_bf16(*(const bf16x8*)(ap + (size_t)48*4096), b, acc[3], 0,0,0);
  }
  #undef WAVE4

  #pragma unroll
  for (int mt = 0; mt < 4; ++mt) {
    #pragma unroll
    for (int rr = 0; rr < 4; ++rr) {
      rp[(size_t)(part*64 + mt*16 + q*4 + rr) * 32768 + col] = f2bf(acc[mt][rr]);
    }
  }
}

// ============================================================================
extern "C" void kernel_launch(void* const* d_in, const int* in_sizes, int n_in,
                              void* d_out, int out_size, void* d_ws, size_t ws_size,
                              hipStream_t stream)
{
  const float* mix   = (const float*)d_in[1];
  const float* dec   = (const float*)d_in[2];
  const float* fdec  = (const float*)d_in[3];
  const float* rc    = (const float*)d_in[4];
  const float* nf    = (const float*)d_in[5];
  const float* rf1   = (const float*)d_in[6];
  const float* rf2   = (const float*)d_in[7];
  const float* env   = (const float*)d_in[8];
  const float* amps  = (const float*)d_in[9];
  const float* verb  = (const float*)d_in[10];
  const float* noise = (const float*)d_in[11];
  const float* lnw   = (const float*)d_in[13];
  const float* lnb   = (const float*)d_in[14];
  const float* mw1   = (const float*)d_in[15];
  const float* mw2   = (const float*)d_in[16];
  const float* rw1   = (const float*)d_in[17];
  const float* rw2   = (const float*)d_in[18];
  const float* rirs  = (const float*)d_in[19];
  float* out = (float*)d_out;
  float* w   = (float*)d_ws;

  if (ws_size < WS_FLOATS * 4ULL) return;

  float*    scal = w + OFF_SCAL;
  short*    ctb  = (short*)(w + OFF_CT);
  short*    rp   = (short*)(w + OFF_RP);
  unsigned* P    = (unsigned*)(w + OFF_P);
  unsigned* Ds   = (unsigned*)(w + OFF_DS);
  unsigned* W64  = (unsigned*)(w + OFF_W64);
  unsigned* RSs  = (unsigned*)(w + OFF_RSS);
  unsigned* NSs  = (unsigned*)(w + OFF_NSS);
  unsigned* W2   = (unsigned*)(w + OFF_W2);
  float*    finU = w + OFF_FINU;
  unsigned* W1   = (unsigned*)(w + OFF_W1);
  short*    fnb  = (short*)(w + OFF_FN);
  unsigned* FRP  = (unsigned*)(w + OFF_FRP);
  unsigned* IRS  = (unsigned*)(w + OFF_IRS);
  const int* room = ((const int*)(w + OFF_SCAL)) + SC_ROOM;

  k_packA<<<1024, 256, 0, stream>>>(rc, ctb, mix, dec, fdec, nf, rf1, rf2, env,
                                    amps, verb, lnw, lnb, mw1, mw2, rw1, rw2,
                                    scal, out);
  k_gemm_mfma<<<dim3(256, 2), 512, 0, stream>>>(scal, ctb, rp);

  // merged RS + NS chains: 3 dispatches (32K mid now register 16x8)
  k_fft_s128_first<<<dim3(8,128),256,0,stream>>>(RSs, NSs, rp, noise);
  k_fft_m128_both<<<dim3(8,128),256,0,stream>>>(RSs, NSs, W1, W2, scal);
  k_fft_s128_last<<<dim3(8,128),256,0,stream>>>(W1, W2, FRP, fnb);

  // merged Ds + P + IRS forward strided (all half-transformed, bf16)
  k_fft_s256_DsPI<<<dim3(16,136),256,0,stream>>>(Ds, P, IRS, FRP, fnb, rirs, scal);

  // conv mid: fft(Ds)*fft(P) -> inverse-contig -> W64
  k_fft_mid256dual<<<dim3(16,64),256,0,stream>>>(Ds, P, W64, nullptr);

  // FUSED: conv inverse -> finU + SS partials -> reverb forward -> Ds
  k_fft_out6fwd<<<dim3(16,64),256,0,stream>>>(W64, fnb, finU, scal, Ds);

  // reverb mid: fft(Ds half) * fft(IRS half[room]) -> inverse-contig -> W64
  // *** NO contig FFT between strided and mid (round-2 bug) ***
  k_fft_mid256dual<<<dim3(16,64),256,0,stream>>>(Ds, IRS, W64, room);

  // final inverse + inline norm (from PSS partials) + dry/wet mix
  k_fft_s256_out3<<<dim3(16,64),256,0,stream>>>(W64, finU, scal, out);
}

// Round 19
// 256.856 us; speedup vs baseline: 1.1692x; 1.0153x over previous
//
#include <hip/hip_runtime.h>

// ============================================================================
// Model_22016002360008 — synth forward pass.
//  GEMM: bf16 MFMA 16x16x32, FULLY ANALYTIC B (no waves read).
//  FFT: complex four-step, N = N1*256, digit-permuted spectrum
//       addr = k2*N1 + k1, true bin k = k2 + 256*k1.
//  ALL spectra bf16-packed; fr1/fr2 packed (FRP), fn bf16; finU fp32.
//  ALL transforms REGISTER-based; step-B twiddle is a T256[u*k] table lookup
//  (twiddleT) — no sincos, no serial cmul chain. IRS full spectra
//  precomputed once (k_fft_irs_contig, in place); reverb mid is a direct
//  spectrum product (FM4).
//  !! mid's input must be STRIDED-ONLY (half-transformed) data — never run
//  !! a contig FFT before a mid kernel (round-2 bug, reverb path).
// ============================================================================

typedef __attribute__((ext_vector_type(8))) short bf16x8;
typedef __attribute__((ext_vector_type(4))) float f32x4;

constexpr int SC_OM0   = 0;
constexpr int SC_OM1   = 64;
constexpr int SC_NFMU  = 128;
constexpr int SC_NFSD  = 192;
constexpr int SC_RF1SD = 256;
constexpr int SC_RF2SD = 320;
constexpr int SC_ENVMU = 384;
constexpr int SC_ENVSD = 448;
constexpr int SC_AMPS  = 512;
constexpr int SC_MIXV  = 576;
constexpr int SC_ROOM  = 832;
constexpr int SC_PSS   = 1024;   // 64 x 16 partial sum-of-squares
constexpr int SC_DTAB  = 4096;
constexpr int SC_FTAB  = 12288;
constexpr int SC_RPS   = 20480;  // 1024-entry fp32 rps table

constexpr size_t OFF_SCAL = 0;
constexpr size_t OFF_CT   = 65536;
constexpr size_t OFF_P    = 327680;
constexpr size_t OFF_DS   = 8716288;
constexpr size_t OFF_RP   = OFF_DS;
constexpr size_t OFF_W64  = 17104896;
constexpr size_t OFF_NSS  = OFF_W64;
constexpr size_t OFF_W2   = OFF_W64 + 4194304;
constexpr size_t OFF_RSS  = 25493504;
constexpr size_t OFF_FINU = OFF_RSS;
constexpr size_t OFF_W1   = 29687808;
constexpr size_t OFF_FN   = 38076416;
constexpr size_t OFF_FRP  = 40173568;
constexpr size_t OFF_IRS  = 44367872;
constexpr size_t WS_FLOATS= 45416448;

__device__ __forceinline__ float2 cmul(float2 a, float2 b) {
  return make_float2(a.x*b.x - a.y*b.y, a.x*b.y + a.y*b.x);
}

__device__ __forceinline__ short f2bf(float x) {
  unsigned u = __float_as_uint(x);
  u = (u + 0x7FFFu + ((u >> 16) & 1u)) >> 16;
  return (short)u;
}
__device__ __forceinline__ float bf2f(short s) {
  return __uint_as_float((unsigned)(unsigned short)s << 16);
}
__device__ __forceinline__ unsigned pk2(float2 v) {
  return (unsigned)(unsigned short)f2bf(v.x)
       | ((unsigned)(unsigned short)f2bf(v.y) << 16);
}
__device__ __forceinline__ float2 upk2(unsigned u) {
  return make_float2(__uint_as_float(u << 16),
                     __uint_as_float(u & 0xFFFF0000u));
}

// ---------------- 16-point DFT in registers (natural order in/out) ---------
__device__ __forceinline__ void dft16(float2 d[16], float ei)
{
  const float CA[4] = {1.0f, 0.92387953251128674f, 0.70710678118654752f, 0.38268343236508977f};
  const float SA[4] = {0.0f, 0.38268343236508977f, 0.70710678118654752f, 0.92387953251128674f};
  const float CB[4] = {1.0f, 0.70710678118654752f, 0.0f, -0.70710678118654752f};
  const float SB[4] = {0.0f, 0.70710678118654752f, 1.0f, 0.70710678118654752f};
  float2 e[16];
  #pragma unroll
  for (int q = 0; q < 4; ++q) {
    float2 x0 = d[q], x1 = d[q+4], x2 = d[q+8], x3 = d[q+12];
    float ca = CA[q], sa = ei*SA[q], cb = CB[q], sb = ei*SB[q];
    float2 sum1 = make_float2(x0.x+x2.x, x0.y+x2.y);
    float2 d1   = make_float2(x0.x-x2.x, x0.y-x2.y);
    float2 dif1 = make_float2(d1.x*ca - d1.y*sa, d1.x*sa + d1.y*ca);
    float2 sum2 = make_float2(x1.x+x3.x, x1.y+x3.y);
    float2 d2   = make_float2(x1.x-x3.x, x1.y-x3.y);
    float2 dt   = make_float2(d2.x*ca - d2.y*sa, d2.x*sa + d2.y*ca);
    float2 dif2 = make_float2(-ei*dt.y, ei*dt.x);
    float2 Dm   = make_float2(sum1.x-sum2.x, sum1.y-sum2.y);
    float2 Dm2  = make_float2(dif1.x-dif2.x, dif1.y-dif2.y);
    e[4*q+0] = make_float2(sum1.x+sum2.x, sum1.y+sum2.y);
    e[4*q+1] = make_float2(dif1.x+dif2.x, dif1.y+dif2.y);
    e[4*q+2] = make_float2(Dm.x*cb - Dm.y*sb, Dm.x*sb + Dm.y*cb);
    e[4*q+3] = make_float2(Dm2.x*cb - Dm2.y*sb, Dm2.x*sb + Dm2.y*cb);
  }
  #pragma unroll
  for (int q = 0; q < 4; ++q) {
    float2 x0 = e[q], x1 = e[q+4], x2 = e[q+8], x3 = e[q+12];
    float2 sum1 = make_float2(x0.x+x2.x, x0.y+x2.y);
    float2 dif1 = make_float2(x0.x-x2.x, x0.y-x2.y);
    float2 sum2 = make_float2(x1.x+x3.x, x1.y+x3.y);
    float2 d2   = make_float2(x1.x-x3.x, x1.y-x3.y);
    float2 dif2 = make_float2(-ei*d2.y, ei*d2.x);
    d[q]    = make_float2(sum1.x+sum2.x, sum1.y+sum2.y);
    d[q+4]  = make_float2(dif1.x+dif2.x, dif1.y+dif2.y);
    d[q+8]  = make_float2(sum1.x-sum2.x, sum1.y-sum2.y);
    d[q+12] = make_float2(dif1.x-dif2.x, dif1.y-dif2.y);
  }
}

// ---------------- 8-point DFT in registers (natural order in/out) ----------
__device__ __forceinline__ void dft8(float2 d[8], float ei)
{
  const float RS = 0.70710678118654752f;
  float2 E[4], O[4];
  {
    float2 s02 = make_float2(d[0].x+d[4].x, d[0].y+d[4].y);
    float2 m02 = make_float2(d[0].x-d[4].x, d[0].y-d[4].y);
    float2 s13 = make_float2(d[2].x+d[6].x, d[2].y+d[6].y);
    float2 m13 = make_float2(d[2].x-d[6].x, d[2].y-d[6].y);
    float2 im13 = make_float2(-ei*m13.y, ei*m13.x);
    E[0] = make_float2(s02.x+s13.x, s02.y+s13.y);
    E[1] = make_float2(m02.x+im13.x, m02.y+im13.y);
    E[2] = make_float2(s02.x-s13.x, s02.y-s13.y);
    E[3] = make_float2(m02.x-im13.x, m02.y-im13.y);
  }
  {
    float2 s02 = make_float2(d[1].x+d[5].x, d[1].y+d[5].y);
    float2 m02 = make_float2(d[1].x-d[5].x, d[1].y-d[5].y);
    float2 s13 = make_float2(d[3].x+d[7].x, d[3].y+d[7].y);
    float2 m13 = make_float2(d[3].x-d[7].x, d[3].y-d[7].y);
    float2 im13 = make_float2(-ei*m13.y, ei*m13.x);
    O[0] = make_float2(s02.x+s13.x, s02.y+s13.y);
    O[1] = make_float2(m02.x+im13.x, m02.y+im13.y);
    O[2] = make_float2(s02.x-s13.x, s02.y-s13.y);
    O[3] = make_float2(m02.x-im13.x, m02.y-im13.y);
  }
  float2 w1 = make_float2(RS, ei*RS);
  float2 w2 = make_float2(0.0f, ei);
  float2 w3 = make_float2(-RS, ei*RS);
  float2 t0 = O[0];
  float2 t1 = cmul(w1, O[1]);
  float2 t2 = cmul(w2, O[2]);
  float2 t3 = cmul(w3, O[3]);
  d[0] = make_float2(E[0].x+t0.x, E[0].y+t0.y);
  d[1] = make_float2(E[1].x+t1.x, E[1].y+t1.y);
  d[2] = make_float2(E[2].x+t2.x, E[2].y+t2.y);
  d[3] = make_float2(E[3].x+t3.x, E[3].y+t3.y);
  d[4] = make_float2(E[0].x-t0.x, E[0].y-t0.y);
  d[5] = make_float2(E[1].x-t1.x, E[1].y-t1.y);
  d[6] = make_float2(E[2].x-t2.x, E[2].y-t2.y);
  d[7] = make_float2(E[3].x-t3.x, E[3].y-t3.y);
}

// step-B twiddle via table: d[k] *= (T256[u*k].x, dsign*T256[u*k].y).
// u*k <= 225 < 256, no wrap. No sincos, no serial chain.
__device__ __forceinline__ void twiddleT(float2 d[16], int u,
                                         const float2* __restrict__ T256,
                                         float dsign)
{
  #pragma unroll
  for (int k = 1; k < 16; ++k) {
    float2 tw = T256[u*k];
    tw.y *= dsign;
    d[k] = cmul(d[k], tw);
  }
}

// ---------------- merged Ds + P + IRS forward strided (64K) ----------------
__global__ __launch_bounds__(256) void k_fft_s256_DsPI(
    unsigned* __restrict__ Ds, unsigned* __restrict__ P,
    unsigned* __restrict__ IRS,
    const unsigned* __restrict__ FRP, const short* __restrict__ fnb,
    const float* __restrict__ rirs, const float* __restrict__ scal)
{
  constexpr int N = 65536, NH = 32768;
  constexpr float FWD = -6.283185307179586f;
  __shared__ float2 X[16*16*17];
  __shared__ float2 T256[256];
  __shared__ float2 TN[256];
  const int mode = (blockIdx.y < 64) ? 0 : ((blockIdx.y < 128) ? 1 : 2);
  const int a = (mode == 0) ? blockIdx.y : ((mode == 1) ? blockIdx.y - 64 : blockIdx.y - 128);
  const int n1base = blockIdx.x << 4;
  const int r = threadIdx.x & 15;
  const int u = threadIdx.x >> 4;

  {
    float ang = FWD * ((float)threadIdx.x * (1.0f/256.0f));
    float sn, cs; __sincosf(ang, &sn, &cs);
    T256[threadIdx.x] = make_float2(cs, sn);
    float ang2 = FWD * ((float)threadIdx.x * (1.0f/(float)N));
    float sn2, cs2; __sincosf(ang2, &sn2, &cs2);
    TN[threadIdx.x] = make_float2(cs2, sn2);
  }
  __syncthreads();

  float emu = 0.f, esd = 1.f, egp = 0.f;
  if (mode == 1) {
    emu = scal[SC_ENVMU + a];
    esd = scal[SC_ENVSD + a];
    egp = 0.3989422804014327f / esd;
  }

  float2 d[16];
  #pragma unroll
  for (int m = 0; m < 16; ++m) {
    int j = u + (m << 4);
    int n = n1base + r + 256 * j;
    float2 v = make_float2(0.0f, 0.0f);
    if (n < NH) {
      if (mode == 0) {
        float pos = ((float)n + 0.5f) * (1.0f/256.0f) - 0.5f;
        pos = fminf(fmaxf(pos, 0.0f), 127.0f);
        int i0 = (int)pos;
        float w = pos - (float)i0;
        int i1 = (i0 + 1 < 127) ? i0 + 1 : 127;
        const float* dt = scal + SC_DTAB + a*128;
        float de = dt[i0]*(1.0f-w) + dt[i1]*w;
        float2 fr = upk2(FRP[(size_t)a * NH + n]);
        v = make_float2(fr.x * de, fr.y * de);
      } else if (mode == 1) {
        float uu = (float)n * (1.0f / 32767.0f);
        float te = (uu - emu) / esd;
        float envv = __expf(-0.5f * te * te) * egp;
        v = make_float2(bf2f(fnb[(size_t)a * NH + n]) * envv, 0.0f);
      } else {
        v = make_float2(rirs[(size_t)a * NH + n], 0.0f);
      }
    }
    d[m] = v;
  }

  dft16(d, -1.0f);
  twiddleT(d, u, T256, 1.0f);
  #pragma unroll
  for (int k = 0; k < 16; ++k) X[(u*16 + k)*17 + r] = d[k];
  __syncthreads();
  #pragma unroll
  for (int m = 0; m < 16; ++m) d[m] = X[(m*16 + u)*17 + r];
  dft16(d, -1.0f);

  unsigned* outp = (mode == 0) ? Ds : ((mode == 1) ? P : IRS);
  #pragma unroll
  for (int k1 = 0; k1 < 16; ++k1) {
    int j = u + (k1 << 4);
    int n = n1base + r + 256 * j;
    int aa = (n1base + r) * j;
    float2 tw = cmul(T256[(aa >> 8) & 255], TN[aa & 255]);
    outp[(size_t)a * N + n] = pk2(cmul(d[k1], tw));
  }
}

// ---------------- IRS: complete to full spectrum (contig pass, in place) ----
__global__ __launch_bounds__(256) void k_fft_irs_contig(unsigned* __restrict__ IRS)
{
  constexpr int N = 65536;
  constexpr float FWD = -6.283185307179586f;
  __shared__ float2 X[16*16*17];
  __shared__ float2 T256[256];
  const int a = blockIdx.y;               // room
  const int colbase = blockIdx.x << 4;
  const int u  = threadIdx.x & 15;
  const int rc = threadIdx.x >> 4;

  {
    float ang = FWD * ((float)threadIdx.x * (1.0f/256.0f));
    float sn, cs; __sincosf(ang, &sn, &cs);
    T256[threadIdx.x] = make_float2(cs, sn);
  }
  __syncthreads();

  const size_t rowG = (size_t)a * N + (size_t)(colbase + rc) * 256;
  float2 d[16];
  #pragma unroll
  for (int m = 0; m < 16; ++m) d[m] = upk2(IRS[rowG + u + (m << 4)]);
  dft16(d, -1.0f);
  twiddleT(d, u, T256, 1.0f);
  #pragma unroll
  for (int k = 0; k < 16; ++k) X[(rc*16 + k)*17 + u] = d[k];
  #pragma unroll
  for (int m = 0; m < 16; ++m) d[m] = X[(rc*16 + u)*17 + m];
  dft16(d, -1.0f);
  #pragma unroll
  for (int k1 = 0; k1 < 16; ++k1)
    IRS[rowG + u + (k1 << 4)] = pk2(d[k1]);   // same addrs this thread read
}

// ---------------- merged first strided (32K): RS (y<64) + NS (y>=64) -------
__global__ __launch_bounds__(256) void k_fft_s128_first(
    unsigned* __restrict__ RSs, unsigned* __restrict__ NSs,
    const short* __restrict__ rez, const float* __restrict__ noise)
{
  constexpr int N1 = 128, N = 32768;
  constexpr float FWD = -6.283185307179586f;
  __shared__ float2 X[16*16*17];
  __shared__ float2 T256[256];
  __shared__ float2 TN[128];
  const bool isRS = blockIdx.y < 64;
  const int a = isRS ? blockIdx.y : blockIdx.y - 64;
  const int n1base = blockIdx.x << 4;
  const int r = threadIdx.x & 15;
  const int u = threadIdx.x >> 4;

  {
    float ang = FWD * ((float)threadIdx.x * (1.0f/256.0f));
    float sn, cs; __sincosf(ang, &sn, &cs);
    T256[threadIdx.x] = make_float2(cs, sn);
    if (threadIdx.x < 128) {
      float ang2 = FWD * ((float)threadIdx.x * (1.0f/(float)N));
      float sn2, cs2; __sincosf(ang2, &sn2, &cs2);
      TN[threadIdx.x] = make_float2(cs2, sn2);
    }
  }
  __syncthreads();

  float2 d[16];
  #pragma unroll
  for (int m = 0; m < 16; ++m) {
    int j = u + (m << 4);
    int n = n1base + r + N1 * j;
    float x = isRS ? (bf2f(rez[(size_t)a * N + n]) +
                      bf2f(rez[(size_t)(64 + a) * N + n]))
                   : noise[(size_t)a * N + n];
    d[m] = make_float2(x, 0.0f);
  }

  dft16(d, -1.0f);
  twiddleT(d, u, T256, 1.0f);
  #pragma unroll
  for (int k = 0; k < 16; ++k) X[(u*16 + k)*17 + r] = d[k];
  __syncthreads();
  #pragma unroll
  for (int m = 0; m < 16; ++m) d[m] = X[(m*16 + u)*17 + r];
  dft16(d, -1.0f);

  unsigned* outp = isRS ? RSs : NSs;
  #pragma unroll
  for (int k1 = 0; k1 < 16; ++k1) {
    int j = u + (k1 << 4);
    int n = n1base + r + N1 * j;
    int aa = (n1base + r) * j;
    float2 tw = cmul(T256[(aa >> 7) & 255], TN[aa & 127]);
    outp[(size_t)a * N + n] = pk2(cmul(d[k1], tw));
  }
}

// ---------------- 32K mid, REGISTER 16x8 four-step --------------------------
__global__ __launch_bounds__(256) void k_fft_m128_both(
    const unsigned* __restrict__ RSs, const unsigned* __restrict__ NSs,
    unsigned* __restrict__ W1, unsigned* __restrict__ W2,
    const float* __restrict__ scal)
{
  constexpr int N = 32768;
  constexpr float FWD = -6.283185307179586f;
  constexpr float IVD = +6.283185307179586f;
  __shared__ float2 L[32*145];       // c*145 + n1*9 + k2
  __shared__ float2 T256[256];       // FWD direction
  __shared__ float2 TN[128];         // IVD direction (outer post-twiddle)
  const bool isRS = blockIdx.y < 64;
  const int a = isRS ? blockIdx.y : blockIdx.y - 64;
  const int colbase = blockIdx.x << 5;   // 32 cols per block
  const int t = threadIdx.x;

  {
    float ang = FWD * ((float)t * (1.0f/256.0f));
    float sn, cs; __sincosf(ang, &sn, &cs);
    T256[t] = make_float2(cs, sn);
    if (t < 128) {
      float ang2 = IVD * ((float)t * (1.0f/(float)N));
      float sn2, cs2; __sincosf(ang2, &sn2, &cs2);
      TN[t] = make_float2(cs2, sn2);
    }
  }

  float mu = 0.f, isd1 = 0.f, g1 = 0.f, isd2 = 0.f, g2 = 0.f;
  if (isRS) {
    float s1 = scal[SC_RF1SD + a], s2 = scal[SC_RF2SD + a];
    isd1 = 1.0f/s1; g1 = 0.3989422804014327f/s1;
    isd2 = 1.0f/s2; g2 = 0.3989422804014327f/s2;
  } else {
    float sd = scal[SC_NFSD + a]; mu = scal[SC_NFMU + a];
    isd1 = 1.0f/sd; g1 = 0.3989422804014327f/sd;
  }
  const unsigned* zin = (isRS ? RSs : NSs) + (size_t)a * N;
  unsigned* outp = (isRS ? W1 : W2) + (size_t)a * N;

  __syncthreads();   // tables visible

  #pragma unroll
  for (int pp = 0; pp < 2; ++pp) {
    int p = t + (pp << 8);
    int c = p >> 4, n1 = p & 15;
    float2 d8[8];
    #pragma unroll
    for (int n2 = 0; n2 < 8; ++n2)
      d8[n2] = upk2(zin[(size_t)(colbase + c) * 128 + n1 + (n2 << 4)]);
    dft8(d8, -1.0f);
    #pragma unroll
    for (int k2 = 0; k2 < 8; ++k2) {
      float2 v = cmul(d8[k2], T256[(k2 * n1) << 1]);   // angle k2*n1/128 (FWD)
      L[c*145 + n1*9 + k2] = v;
    }
  }
  __syncthreads();

  {
    int c = t >> 3, k2 = t & 7;
    float2 d[16];
    #pragma unroll
    for (int n1 = 0; n1 < 16; ++n1) d[n1] = L[c*145 + n1*9 + k2];
    dft16(d, -1.0f);                   // d[k1] = X[j = k2 + 8*k1]
    int col = colbase + c;
    #pragma unroll
    for (int k1 = 0; k1 < 16; ++k1) {
      int j = k2 + (k1 << 3);
      int k = col + (j << 8);          // true bin
      int kk = (k <= N - k) ? k : N - k;
      float2 v = d[k1];
      if (isRS) {
        float fr = (float)kk * (2.0f/(float)N);
        float t1 = fr * isd1, t2 = fr * isd2;
        float ga = __expf(-0.5f * t1 * t1) * g1;   // G1 (real)
        float gb = __expf(-0.5f * t2 * t2) * g2;   // G2 (imag)
        v = make_float2(v.x*ga - v.y*gb, v.x*gb + v.y*ga);
      } else {
        float tt = ((float)kk * (2.0f/(float)N) - mu) * isd1;
        float g = __expf(-0.5f * tt * tt) * g1;
        v.x *= g; v.y *= g;
      }
      d[k1] = v;
    }
    dft16(d, 1.0f);                    // inverse over k1 -> over n1
    #pragma unroll
    for (int n1 = 0; n1 < 16; ++n1) {
      float2 tw = T256[(k2 * n1) << 1];
      tw.y = -tw.y;                    // conj -> inverse direction
      L[c*145 + n1*9 + k2] = cmul(d[n1], tw);
    }
  }
  __syncthreads();

  #pragma unroll
  for (int pp = 0; pp < 2; ++pp) {
    int p = t + (pp << 8);
    int c = p >> 4, n1 = p & 15;
    float2 d8[8];
    #pragma unroll
    for (int k2 = 0; k2 < 8; ++k2) d8[k2] = L[c*145 + n1*9 + k2];
    dft8(d8, 1.0f);
    int col = colbase + c;
    #pragma unroll
    for (int n2 = 0; n2 < 8; ++n2) {
      int n = n1 + (n2 << 4);
      int aa = n * col;                // < 32768
      float2 t1 = T256[(aa >> 7) & 255];
      t1.y = -t1.y;                    // conj -> IVD direction
      float2 tw = cmul(t1, TN[aa & 127]);
      outp[(size_t)col * 128 + n] = pk2(cmul(d8[n2], tw));
    }
  }
}

// ---------------- merged final strided (32K inverse) -----------------------
__global__ __launch_bounds__(256) void k_fft_s128_last(
    const unsigned* __restrict__ W1, const unsigned* __restrict__ W2,
    unsigned* __restrict__ FRP, short* __restrict__ fnb)
{
  constexpr int N1 = 128, N = 32768;
  constexpr float IVD = +6.283185307179586f;
  constexpr float S32 = 1.0f / 32768.0f;
  __shared__ float2 X[16*16*17];
  __shared__ float2 T256[256];       // IVD direction
  const bool isRS = blockIdx.y < 64;
  const int a = isRS ? blockIdx.y : blockIdx.y - 64;
  const int n1base = blockIdx.x << 4;
  const int r = threadIdx.x & 15;
  const int u = threadIdx.x >> 4;

  {
    float ang = IVD * ((float)threadIdx.x * (1.0f/256.0f));
    float sn, cs; __sincosf(ang, &sn, &cs);
    T256[threadIdx.x] = make_float2(cs, sn);
  }
  __syncthreads();

  const unsigned* cb = (isRS ? W1 : W2) + (size_t)a * N;
  float2 d[16];
  #pragma unroll
  for (int m = 0; m < 16; ++m) {
    int j = u + (m << 4);
    d[m] = upk2(cb[n1base + r + N1 * j]);
  }
  dft16(d, 1.0f);
  twiddleT(d, u, T256, 1.0f);
  #pragma unroll
  for (int k = 0; k < 16; ++k) X[(u*16 + k)*17 + r] = d[k];
  __syncthreads();
  #pragma unroll
  for (int m = 0; m < 16; ++m) d[m] = X[(m*16 + u)*17 + r];
  dft16(d, 1.0f);

  #pragma unroll
  for (int k1 = 0; k1 < 16; ++k1) {
    int j = u + (k1 << 4);
    int n = n1base + r + N1 * j;
    if (isRS) {
      FRP[(size_t)a * N + n] = pk2(make_float2(d[k1].x * S32, d[k1].y * S32));
    } else {
      fnb[(size_t)a * N + n] = f2bf(d[k1].x * S32);
    }
  }
}

// ---------------- fused middle, 64K (register FFT) -------------------------
// FM=5: z2 HALF-transformed (contig FFT run here). FM=4: z2 FULL spectrum.
template<int FM>
__global__ __launch_bounds__(256) void k_fft_mid256dual(
    const unsigned* __restrict__ zin, const unsigned* __restrict__ zin2,
    unsigned* __restrict__ out1, const int* __restrict__ roomArr)
{
  constexpr int N = 65536;
  constexpr float FWD = -6.283185307179586f;
  constexpr float IVD = +6.283185307179586f;
  __shared__ float2 X[16*16*17];
  __shared__ float2 T256[256];
  __shared__ float2 TN[256];
  const int a = blockIdx.y;
  const int colbase = blockIdx.x << 4;
  const int u  = threadIdx.x & 15;
  const int rc = threadIdx.x >> 4;

  {
    float ang = FWD * ((float)threadIdx.x * (1.0f/256.0f));
    float sn, cs; __sincosf(ang, &sn, &cs);
    T256[threadIdx.x] = make_float2(cs, sn);
    float ang2 = IVD * ((float)threadIdx.x * (1.0f/(float)N));
    float sn2, cs2; __sincosf(ang2, &sn2, &cs2);
    TN[threadIdx.x] = make_float2(cs2, sn2);
  }
  __syncthreads();

  const unsigned* z2 = zin2 + (size_t)(roomArr ? roomArr[a] : a) * N;
  const size_t rowG = (size_t)a * N + (size_t)(colbase + rc) * 256;
  const size_t rowZ2 = (size_t)(colbase + rc) * 256;

  float2 d[16];
  #pragma unroll
  for (int m = 0; m < 16; ++m) d[m] = upk2(zin[rowG + u + (m << 4)]);
  dft16(d, -1.0f);
  twiddleT(d, u, T256, 1.0f);
  #pragma unroll
  for (int k = 0; k < 16; ++k) X[(rc*16 + k)*17 + u] = d[k];
  #pragma unroll
  for (int m = 0; m < 16; ++m) d[m] = X[(rc*16 + u)*17 + m];
  dft16(d, -1.0f);

  if (FM == 5) {
    float2 stash[16];
    #pragma unroll
    for (int k = 0; k < 16; ++k) stash[k] = d[k];
    #pragma unroll
    for (int m = 0; m < 16; ++m) d[m] = upk2(z2[rowZ2 + u + (m << 4)]);
    dft16(d, -1.0f);
    twiddleT(d, u, T256, 1.0f);
    #pragma unroll
    for (int k = 0; k < 16; ++k) X[(rc*16 + k)*17 + u] = d[k];
    #pragma unroll
    for (int m = 0; m < 16; ++m) d[m] = X[(rc*16 + u)*17 + m];
    dft16(d, -1.0f);
    #pragma unroll
    for (int k = 0; k < 16; ++k) d[k] = cmul(stash[k], d[k]);
  } else {
    #pragma unroll
    for (int k = 0; k < 16; ++k)
      d[k] = cmul(d[k], upk2(z2[rowZ2 + u + (k << 4)]));
  }

  dft16(d, 1.0f);
  twiddleT(d, u, T256, -1.0f);
  #pragma unroll
  for (int k = 0; k < 16; ++k) X[(rc*16 + k)*17 + u] = d[k];
  #pragma unroll
  for (int m = 0; m < 16; ++m) d[m] = X[(rc*16 + u)*17 + m];
  dft16(d, 1.0f);

  #pragma unroll
  for (int k1 = 0; k1 < 16; ++k1) {
    int j = u + (k1 << 4);
    int aa = j * (colbase + rc);
    float2 t1 = T256[(aa >> 8) & 255];
    t1.y = -t1.y;
    float2 tw = cmul(t1, TN[aa & 255]);
    out1[rowG + j] = pk2(cmul(d[k1], tw));
  }
}

// ---------------- FUSED: conv inverse -> finU + SS -> reverb forward -------
__global__ __launch_bounds__(256) void k_fft_out6fwd(
    const unsigned* __restrict__ W64in, const short* __restrict__ fnb,
    float* __restrict__ finU, float* __restrict__ scal,
    unsigned* __restrict__ DsOut)
{
  constexpr int N = 65536, NH = 32768;
  constexpr float FWD = -6.283185307179586f;
  constexpr float IVD = +6.283185307179586f;
  constexpr float S64 = 1.0f / 65536.0f;
  __shared__ float2 X[16*16*17];
  __shared__ float2 T256[256];   // FWD
  __shared__ float2 TN[256];     // FWD
  __shared__ float red[256];
  const int a = blockIdx.y;
  const int n1base = blockIdx.x << 4;
  const int r = threadIdx.x & 15;
  const int u = threadIdx.x >> 4;

  {
    float ang = FWD * ((float)threadIdx.x * (1.0f/256.0f));
    float sn, cs; __sincosf(ang, &sn, &cs);
    T256[threadIdx.x] = make_float2(cs, sn);
    float ang2 = FWD * ((float)threadIdx.x * (1.0f/(float)N));
    float sn2, cs2; __sincosf(ang2, &sn2, &cs2);
    TN[threadIdx.x] = make_float2(cs2, sn2);
  }
  __syncthreads();

  const float emu = scal[SC_ENVMU + a];
  const float esd = scal[SC_ENVSD + a];
  const float egp = 0.3989422804014327f / esd;
  const float om0 = scal[SC_OM0 + a], om1 = scal[SC_OM1 + a];
  const float* ft = scal + SC_FTAB + a*128;

  float2 d[16];
  #pragma unroll
  for (int m = 0; m < 16; ++m) {
    int j = u + (m << 4);
    d[m] = upk2(W64in[(size_t)a * N + n1base + r + 256 * j]);
  }
  dft16(d, 1.0f);
  twiddleT(d, u, T256, -1.0f);     // IVD via conj of FWD table
  #pragma unroll
  for (int k = 0; k < 16; ++k) X[(u*16 + k)*17 + r] = d[k];
  __syncthreads();
  #pragma unroll
  for (int m = 0; m < 16; ++m) d[m] = X[(m*16 + u)*17 + r];
  dft16(d, 1.0f);

  float fv[8];
  float ss = 0.0f;
  #pragma unroll
  for (int k1 = 0; k1 < 8; ++k1) {
    int n = n1base + r + 256 * (u + (k1 << 4));
    float resv  = d[k1].x * S64;
    float res2v = d[k1].y * S64;
    float uu = (float)n * (1.0f / 32767.0f);
    float te = (uu - emu) / esd;
    float envv = __expf(-0.5f * te * te) * egp;
    float pnv = bf2f(fnb[(size_t)a * NH + n]) * envv;
    float pos = ((float)n + 0.5f) * (1.0f/256.0f) - 0.5f;
    pos = fminf(fmaxf(pos, 0.0f), 127.0f);
    int i0 = (int)pos;
    float w = pos - (float)i0;
    int i1 = (i0 + 1 < 127) ? i0 + 1 : 127;
    float fc = ft[i0]*(1.0f-w) + ft[i1]*w;
    float f = pnv*om0 + (fc*resv + (1.0f-fc)*res2v)*om1;
    finU[(size_t)a * NH + n] = f;
    fv[k1] = f;
    ss += f * f;
  }
  red[threadIdx.x] = ss;
  __syncthreads();
  for (int s = 128; s > 0; s >>= 1) {
    if (threadIdx.x < s) red[threadIdx.x] += red[threadIdx.x + s];
    __syncthreads();
  }
  if (threadIdx.x == 0) scal[SC_PSS + a*16 + blockIdx.x] = red[0];

  #pragma unroll
  for (int m = 0; m < 16; ++m)
    d[m] = (m < 8) ? make_float2(fv[m], 0.0f) : make_float2(0.0f, 0.0f);
  dft16(d, -1.0f);
  twiddleT(d, u, T256, 1.0f);
  #pragma unroll
  for (int k = 0; k < 16; ++k) X[(u*16 + k)*17 + r] = d[k];
  __syncthreads();
  #pragma unroll
  for (int m = 0; m < 16; ++m) d[m] = X[(m*16 + u)*17 + r];
  dft16(d, -1.0f);

  #pragma unroll
  for (int k1 = 0; k1 < 16; ++k1) {
    int j = u + (k1 << 4);
    int n = n1base + r + 256 * j;
    int aa = (n1base + r) * j;
    float2 tw = cmul(T256[(aa >> 8) & 255], TN[aa & 255]);
    DsOut[(size_t)a * N + n] = pk2(cmul(d[k1], tw));
  }
}

// ---------------- final inverse strided + inline norm + dry/wet mix --------
__global__ __launch_bounds__(256) void k_fft_s256_out3(
    const unsigned* __restrict__ W64in, const float* __restrict__ finU,
    const float* __restrict__ scal, float* __restrict__ out)
{
  constexpr int N = 65536, NH = 32768;
  constexpr float IVD = +6.283185307179586f;
  constexpr float S64 = 1.0f / 65536.0f;
  __shared__ float2 X[16*16*17];
  __shared__ float2 T256[256];       // IVD direction
  const int a = blockIdx.y;
  const int n1base = blockIdx.x << 4;
  const int r = threadIdx.x & 15;
  const int u = threadIdx.x >> 4;

  {
    float ang = IVD * ((float)threadIdx.x * (1.0f/256.0f));
    float sn, cs; __sincosf(ang, &sn, &cs);
    T256[threadIdx.x] = make_float2(cs, sn);
  }
  __syncthreads();

  float ss = 0.0f;
  #pragma unroll
  for (int i = 0; i < 16; ++i) ss += scal[SC_PSS + a*16 + i];
  float fscale = scal[SC_AMPS + a] / (sqrtf(ss) + 1e-8f);
  float mixv = scal[SC_MIXV + a];
  float w1 = fscale * (1.0f - mixv);
  float w0 = fscale * mixv;

  float2 d[16];
  #pragma unroll
  for (int m = 0; m < 16; ++m) {
    int j = u + (m << 4);
    d[m] = upk2(W64in[(size_t)a * N + n1base + r + 256 * j]);
  }
  dft16(d, 1.0f);
  twiddleT(d, u, T256, 1.0f);
  #pragma unroll
  for (int k = 0; k < 16; ++k) X[(u*16 + k)*17 + r] = d[k];
  __syncthreads();
  #pragma unroll
  for (int m = 0; m < 16; ++m) d[m] = X[(m*16 + u)*17 + r];
  dft16(d, 1.0f);

  #pragma unroll
  for (int k1 = 0; k1 < 8; ++k1) {
    int n = n1base + r + 256 * (u + (k1 << 4));
    out[(size_t)a * NH + n] =
        d[k1].x * S64 * w1 + finU[(size_t)a * NH + n] * w0;
  }
}

// ---------------- A repack + per-atom scalars + rps table -------------------
__global__ void k_packA(const float* __restrict__ rc, short* __restrict__ ctb,
    const float* __restrict__ mix, const float* __restrict__ decays,
    const float* __restrict__ fdec, const float* __restrict__ nf,
    const float* __restrict__ rf1, const float* __restrict__ rf2,
    const float* __restrict__ env, const float* __restrict__ amplitudes,
    const float* __restrict__ verb, const float* __restrict__ ln_w,
    const float* __restrict__ ln_b, const float* __restrict__ mw1,
    const float* __restrict__ mw2, const float* __restrict__ rw1,
    const float* __restrict__ rw2, float* __restrict__ scal,
    float* __restrict__ dout)
{
  int o = blockIdx.x * 256 + threadIdx.x;   // o = m*4096 + k
  {
    int m = o >> 12, k = o & 4095;
    int s = k >> 2, f = k & 3;
    float v = fmaxf(rc[m*4096 + f*1024 + s], 0.0f);
    ctb[o] = f2bf(v);
  }
  if (blockIdx.x < 4) {
    int idx = blockIdx.x * 256 + threadIdx.x;   // 0..1023
    double step = 85.0 / 1023.0;
    double midi = (double)idx * step + 21.0;
    if (idx == 1023) midi = 106.0;
    double f0 = 440.0 * exp2((midi - 69.0) * (1.0 / 12.0));
    scal[SC_RPS + idx] = (float)((f0 / 11025.0) * 3.141592653589793);
  }
  if (blockIdx.x != 0 || threadIdx.x >= 64) return;
  int a = threadIdx.x;
  float m0 = mix[a*2+0], m1 = mix[a*2+1];
  float mx = fmaxf(m0, m1);
  float e0 = expf(m0 - mx), e1 = expf(m1 - mx);
  float inv = 1.0f / (e0 + e1);
  scal[SC_OM0+a] = e0 * inv;
  scal[SC_OM1+a] = e1 * inv;
  scal[SC_NFMU+a] = nf[a*2+0];
  scal[SC_NFSD+a] = fabsf(nf[a*2+1]) + 1e-12f;
  scal[SC_RF1SD+a] = fabsf(rf1[a*2+1]) + 1e-12f;
  scal[SC_RF2SD+a] = fabsf(rf2[a*2+1]) + 1e-12f;
  scal[SC_ENVMU+a] = env[a*2+0];
  scal[SC_ENVSD+a] = fabsf(env[a*2+1] + 1e-12f) * 0.1f;
  float amp = fabsf(amplitudes[a]);
  scal[SC_AMPS+a] = amp;
  dout[2097152 + a] = amp;                       // output 1: amps
  float d  = 0.02f + (1.0f/(1.0f+expf(-decays[a]))) * (0.98f * 0.95f);
  float fd = 0.02f + (1.0f/(1.0f+expf(-fdec[a])))   * (0.98f * 0.95f);
  float pd = 1.0f, pf = 1.0f;
  for (int f = 0; f < 128; ++f) {
    pd *= d; pf *= fd;
    scal[SC_DTAB + a*128 + f] = pd;
    scal[SC_FTAB + a*128 + f] = pf;
  }
  float x0 = verb[a*4+0], x1 = verb[a*4+1], x2 = verb[a*4+2], x3 = verb[a*4+3];
  float mean = (x0+x1+x2+x3) * 0.25f;
  float d0 = x0-mean, d1 = x1-mean, d2 = x2-mean, d3 = x3-mean;
  float var = (d0*d0 + d1*d1 + d2*d2 + d3*d3) * 0.25f;
  float rs = 1.0f / sqrtf(var + 1e-5f);
  float h[4] = { d0*rs*ln_w[0]+ln_b[0], d1*rs*ln_w[1]+ln_b[1],
                 d2*rs*ln_w[2]+ln_b[2], d3*rs*ln_w[3]+ln_b[3] };
  float t[4], u[4];
  for (int j = 0; j < 4; ++j) {
    float s1 = 0.f, s2 = 0.f;
    for (int i2 = 0; i2 < 4; ++i2) {
      s1 += h[i2] * mw1[i2*4 + j];
      s2 += h[i2] * rw1[i2*4 + j];
    }
    t[j] = (s1 > 0.f) ? s1 : 0.01f*s1;
    u[j] = (s2 > 0.f) ? s2 : 0.01f*s2;
  }
  float ml = 0.f;
  for (int j = 0; j < 4; ++j) ml += t[j] * mw2[j];
  scal[SC_MIXV+a] = 1.0f / (1.0f + expf(-ml));
  float best = -1e30f; int bi = 0;
  for (int rr = 0; rr < 8; ++rr) {
    float lg = 0.f;
    for (int j = 0; j < 4; ++j) lg += u[j] * rw2[j*8 + rr];
    if (lg > best) { best = lg; bi = rr; }
  }
  ((int*)scal)[SC_ROOM + a] = bi;
}

// ---------------- resonances GEMM: ANALYTIC waves, MFMA, no loads ----------
__global__ __launch_bounds__(512) void k_gemm_mfma(
    const float* __restrict__ scal, const short* __restrict__ ctb,
    short* __restrict__ rp)
{
  const int t = threadIdx.x;
  const int w = t >> 6, lane = t & 63;
  const int ml = lane & 15, q = lane >> 4;
  const int col = blockIdx.x * 128 + w * 16 + ml;
  const int part = blockIdx.y;

  const float colf = (float)col;
  const float TWO_PI_F = 6.28318530717958647692f;
  const double INV_2PI = 0.15915494309189533577;

  f32x4 acc[4] = {};
  const short* abase = ctb + (size_t)ml * 4096 + (size_t)part * 2048 + q * 8;
  const float* rtab = scal + SC_RPS + part * 512;

  #define WAVE4(rps, b, off) { \
    float rad = (rps) * colf; \
    double dt = (double)rad * INV_2PI; \
    double frd = dt - floor(dt); \
    float sine = __sinf((float)frd * TWO_PI_F); \
    float sq = (rad == 0.0f) ? 0.0f : ((frd < 0.5) ? 1.0f : -1.0f); \
    float tt = rad / TWO_PI_F; \
    float saw = 2.0f * (tt - floorf(tt + 0.5f)); \
    float tri = 2.0f * fabsf(saw) - 1.0f; \
    b[off+0] = f2bf(sine); b[off+1] = f2bf(saw); \
    b[off+2] = f2bf(sq);   b[off+3] = f2bf(tri); }

  for (int kbl = 0; kbl < 64; ++kbl) {
    int sl = kbl * 8 + 2 * q;
    float rps0 = rtab[sl], rps1 = rtab[sl + 1];
    bf16x8 b;
    WAVE4(rps0, b, 0);
    WAVE4(rps1, b, 4);
    const short* ap = abase + (size_t)kbl * 32;
    acc[0] = __builtin_amdgcn_mfma_f32_16x16x32_bf16(*(const bf16x8*)(ap),                   b, acc[0], 0,0,0);
    acc[1] = __builtin_amdgcn_mfma_f32_16x16x32_bf16(*(const bf16x8*)(ap + (size_t)16*4096), b, acc[1], 0,0,0);
    acc[2] = __builtin_amdgcn_mfma_f32_16x16x32_bf16(*(const bf16x8*)(ap + (size_t)32*4096), b, acc[2], 0,0,0);
    acc[3] = __builtin_amdgcn_mfma_f32_16x16x32_bf16(*(const bf16x8*)(ap + (size_t)48*4096), b, acc[3], 0,0,0);
  }
  #undef WAVE4

  #pragma unroll
  for (int mt = 0; mt < 4; ++mt) {
    #pragma unroll
    for (int rr = 0; rr < 4; ++rr) {
      rp[(size_t)(part*64 + mt*16 + q*4 + rr) * 32768 + col] = f2bf(acc[mt][rr]);
    }
  }
}

// ============================================================================
extern "C" void kernel_launch(void* const* d_in, const int* in_sizes, int n_in,
                              void* d_out, int out_size, void* d_ws, size_t ws_size,
                              hipStream_t stream)
{
  const float* mix   = (const float*)d_in[1];
  const float* dec   = (const float*)d_in[2];
  const float* fdec  = (const float*)d_in[3];
  const float* rc    = (const float*)d_in[4];
  const float* nf    = (const float*)d_in[5];
  const float* rf1   = (const float*)d_in[6];
  const float* rf2   = (const float*)d_in[7];
  const float* env   = (const float*)d_in[8];
  const float* amps  = (const float*)d_in[9];
  const float* verb  = (const float*)d_in[10];
  const float* noise = (const float*)d_in[11];
  const float* lnw   = (const float*)d_in[13];
  const float* lnb   = (const float*)d_in[14];
  const float* mw1   = (const float*)d_in[15];
  const float* mw2   = (const float*)d_in[16];
  const float* rw1   = (const float*)d_in[17];
  const float* rw2   = (const float*)d_in[18];
  const float* rirs  = (const float*)d_in[19];
  float* out = (float*)d_out;
  float* w   = (float*)d_ws;

  if (ws_size < WS_FLOATS * 4ULL) return;

  float*    scal = w + OFF_SCAL;
  short*    ctb  = (short*)(w + OFF_CT);
  short*    rp   = (short*)(w + OFF_RP);
  unsigned* P    = (unsigned*)(w + OFF_P);
  unsigned* Ds   = (unsigned*)(w + OFF_DS);
  unsigned* W64  = (unsigned*)(w + OFF_W64);
  unsigned* RSs  = (unsigned*)(w + OFF_RSS);
  unsigned* NSs  = (unsigned*)(w + OFF_NSS);
  unsigned* W2   = (unsigned*)(w + OFF_W2);
  float*    finU = w + OFF_FINU;
  unsigned* W1   = (unsigned*)(w + OFF_W1);
  short*    fnb  = (short*)(w + OFF_FN);
  unsigned* FRP  = (unsigned*)(w + OFF_FRP);
  unsigned* IRS  = (unsigned*)(w + OFF_IRS);
  const int* room = ((const int*)(w + OFF_SCAL)) + SC_ROOM;

  k_packA<<<1024, 256, 0, stream>>>(rc, ctb, mix, dec, fdec, nf, rf1, rf2, env,
                                    amps, verb, lnw, lnb, mw1, mw2, rw1, rw2,
                                    scal, out);
  k_gemm_mfma<<<dim3(256, 2), 512, 0, stream>>>(scal, ctb, rp);

  // merged RS + NS chains: 3 dispatches
  k_fft_s128_first<<<dim3(8,128),256,0,stream>>>(RSs, NSs, rp, noise);
  k_fft_m128_both<<<dim3(8,128),256,0,stream>>>(RSs, NSs, W1, W2, scal);
  k_fft_s128_last<<<dim3(8,128),256,0,stream>>>(W1, W2, FRP, fnb);

  // merged Ds + P + IRS forward strided (all half-transformed, bf16)
  k_fft_s256_DsPI<<<dim3(16,136),256,0,stream>>>(Ds, P, IRS, FRP, fnb, rirs, scal);
  // complete IRS to full spectra (8 rooms, in place; tiny)
  k_fft_irs_contig<<<dim3(16,8),256,0,stream>>>(IRS);

  // conv mid: fft(Ds)*fft(P) -> inverse-contig -> W64
  k_fft_mid256dual<5><<<dim3(16,64),256,0,stream>>>(Ds, P, W64, nullptr);

  // FUSED: conv inverse -> finU + SS partials -> reverb forward -> Ds
  k_fft_out6fwd<<<dim3(16,64),256,0,stream>>>(W64, fnb, finU, scal, Ds);

  // reverb mid: fft(Ds half) * IRS_full[room] -> inverse-contig -> W64
  // *** NO contig FFT between strided and mid for Ds (round-2 bug) ***
  k_fft_mid256dual<4><<<dim3(16,64),256,0,stream>>>(Ds, IRS, W64, room);

  // final inverse + inline norm (from PSS partials) + dry/wet mix
  k_fft_s256_out3<<<dim3(16,64),256,0,stream>>>(W64, finU, scal, out);
}